// Round 5
// baseline (399.739 us; speedup 1.0000x reference)
//
#include <hip/hip_runtime.h>

// Problem dims
#define NT 8192      // N*H*W tokens
#define DM 256
#define HH 64
#define WW 64

typedef unsigned short u16;
typedef __attribute__((ext_vector_type(8))) short short8;  // 8 x bf16 mfma frag
typedef __attribute__((ext_vector_type(4))) float f4;

__device__ __forceinline__ float bf2f(u16 u){
  union { unsigned int i; float f; } v; v.i = ((unsigned int)u) << 16; return v.f;
}
__device__ __forceinline__ u16 f2bf(float f){
  union { float f; unsigned int i; } v; v.f = f;
  unsigned int r = (v.i + 0x7fffu + ((v.i >> 16) & 1u)) >> 16;
  return (u16)r;
}
// async global->LDS 16B (direct DMA, no VGPR round trip)
__device__ __forceinline__ void gld16(const void* g, void* l){
  __builtin_amdgcn_global_load_lds(
      (const __attribute__((address_space(1))) unsigned int*)g,
      (__attribute__((address_space(3))) unsigned int*)l, 16, 0, 0);
}

// ---------------------------------------------------------------------------
// fp32 -> dual bf16 planes (x = hi + lo, |err| <= 2^-17 rel)
// ---------------------------------------------------------------------------
__global__ __launch_bounds__(256) void split_k(const float* __restrict__ src,
                                               u16* __restrict__ dh,
                                               u16* __restrict__ dl){
  int i = blockIdx.x * 256 + threadIdx.x;
  f4 v = ((const f4*)src)[i];
  ushort4 h, l;
  h.x = f2bf(v.x); l.x = f2bf(v.x - bf2f(h.x));
  h.y = f2bf(v.y); l.y = f2bf(v.y - bf2f(h.y));
  h.z = f2bf(v.z); l.z = f2bf(v.z - bf2f(h.z));
  h.w = f2bf(v.w); l.w = f2bf(v.w - bf2f(h.w));
  ((ushort4*)dh)[i] = h;
  ((ushort4*)dl)[i] = l;
}

// ---------------------------------------------------------------------------
// Transpose fp32 [R,C] -> bf16 hi/lo planes [C,R]
// ---------------------------------------------------------------------------
__global__ __launch_bounds__(256) void transpose3_k(const float* __restrict__ src,
                                                    u16* __restrict__ dh,
                                                    u16* __restrict__ dl,
                                                    int R, int C){
  __shared__ float t[32][33];
  int tx = threadIdx.x & 31, ty = threadIdx.x >> 5;
  int c0 = blockIdx.x * 32, r0 = blockIdx.y * 32;
  for (int i = ty; i < 32; i += 8) t[i][tx] = src[(size_t)(r0 + i) * C + c0 + tx];
  __syncthreads();
  for (int i = ty; i < 32; i += 8){
    float x = t[tx][i];
    u16 h = f2bf(x);
    size_t idx = (size_t)(c0 + i) * R + r0 + tx;
    dh[idx] = h;
    dl[idx] = f2bf(x - bf2f(h));
  }
}

// ---------------------------------------------------------------------------
// Fold W_kvp/b_kvp through Wk (or Wv): out = [Wkk0(256), Wkk1(256), bias2(256)]
// ---------------------------------------------------------------------------
__global__ __launch_bounds__(256) void prepkv_k(const float* __restrict__ Wkvp,
                                                const float* __restrict__ bkvp,
                                                const float* __restrict__ Wx,
                                                const float* __restrict__ bx,
                                                float* __restrict__ outc){
  int e = threadIdx.x;
  float a0 = 0.f, a1 = 0.f, ab = 0.f;
  for (int d = 0; d < 256; d++){
    float w = Wx[d * 256 + e];
    a0 += Wkvp[d] * w;
    a1 += Wkvp[256 + d] * w;
    ab += bkvp[d] * w;
  }
  outc[e] = a0; outc[256 + e] = a1; outc[512 + e] = ab + bx[e];
}

// ---------------------------------------------------------------------------
// Offsets: off = 60*sigmoid(hs @ W_off + b_off) - 30 ; loc = clip(ref+off,0,63)
// ---------------------------------------------------------------------------
__global__ __launch_bounds__(256) void offsets_k(const float* __restrict__ hs,
                                                 const float* __restrict__ Woff,
                                                 const float* __restrict__ boff,
                                                 float* __restrict__ off,
                                                 float* __restrict__ loc){
  __shared__ float hsl[8][256];
  __shared__ float wl[256 * 32];
  const int tid = threadIdx.x;
  const int t0 = blockIdx.x * 8;
  for (int i = tid; i < 8192; i += 256) wl[i] = Woff[i];
  for (int i = tid; i < 2048; i += 256) hsl[i >> 8][i & 255] = hs[(size_t)t0 * 256 + i];
  __syncthreads();
  const int g = tid >> 5, o = tid & 31;
  float acc = 0.f;
  #pragma unroll 8
  for (int d = 0; d < 256; d++) acc += hsl[g][d] * wl[d * 32 + o];
  acc += boff[o];
  float sg = 1.f / (1.f + expf(-acc));
  float of = 60.f * sg - 30.f;
  int tok = t0 + g;
  int hh = (tok >> 6) & 63, ww = tok & 63;
  float base = (o & 1) ? (float)ww : (float)hh;
  float l = fminf(fmaxf(base + of, 0.f), 63.f);
  off[tok * 32 + o] = of;
  loc[tok * 32 + o] = l;
}

// ---------------------------------------------------------------------------
// Split-precision MFMA GEMM, m97-style: C = A(hi/lo planes) * Bt(hi/lo)^T.
// BM=128, BK=32, BN in {64,128}. 4 waves, wave = (BM/2)x(BN/2) subtile.
// product = Ah*Bh + Ah*Bl + Al*Bh  (~2^-17 rel). global_load_lds staging.
// EPI 0: fp32 +bias -> C0.   EPI 1: gelu(tanh) -> hi/lo planes C0/C1.
// EPI 2: bf16 packed-KV layout (row*512 + (d>>2)*8 + part*4 + (d&3)) -> C0.
// ---------------------------------------------------------------------------
template<int BN, int EPI>
__global__ __launch_bounds__(256) void gemm_k(const u16* __restrict__ Agh,
                                              const u16* __restrict__ Agl,
                                              const u16* __restrict__ Bgh,
                                              const u16* __restrict__ Bgl,
                                              const float* __restrict__ bias,
                                              void* __restrict__ C0,
                                              void* __restrict__ C1,
                                              int M, int N, int K){
  constexpr int NF = BN / 32;                  // n-frags per wave (2 or 4)
  __shared__ __align__(16) u16 Ah[4][128][8];
  __shared__ __align__(16) u16 Al[4][128][8];
  __shared__ __align__(16) u16 Bh[4][BN][8];
  __shared__ __align__(16) u16 Bl[4][BN][8];
  const int m0 = blockIdx.x << 7, n0 = blockIdx.y * BN;
  const int tid = threadIdx.x;
  const int lane = tid & 63, wave = tid >> 6;
  const int quad = lane >> 4, l15 = lane & 15;
  const int wm = (wave >> 1) << 6;
  const int wn = (wave & 1) * (BN >> 1);
  // A staging: 512 slots of 16B; slot s: qd=s>>7, r=s&127; thread does s=tid, tid+256
  const int ar = tid & 127, aq = tid >> 7;
  const u16* gAh = Agh + (size_t)(m0 + ar) * K + aq * 8;
  const u16* gAl = Agl + (size_t)(m0 + ar) * K + aq * 8;
  // B staging
  const int br = (BN == 128) ? (tid & 127) : (tid & 63);
  const int bq = (BN == 128) ? (tid >> 7) : (tid >> 6);
  const u16* gBh = Bgh + (size_t)(n0 + br) * K + bq * 8;
  const u16* gBl = Bgl + (size_t)(n0 + br) * K + bq * 8;
  f4 acc[4][NF] = {};
  for (int k0 = 0; k0 < K; k0 += 32){
    __syncthreads();
    gld16(gAh + k0,      &Ah[aq][ar][0]);
    gld16(gAh + k0 + 16, &Ah[aq + 2][ar][0]);
    gld16(gAl + k0,      &Al[aq][ar][0]);
    gld16(gAl + k0 + 16, &Al[aq + 2][ar][0]);
    if (BN == 128){
      gld16(gBh + k0,      &Bh[bq][br][0]);
      gld16(gBh + k0 + 16, &Bh[bq + 2][br][0]);
      gld16(gBl + k0,      &Bl[bq][br][0]);
      gld16(gBl + k0 + 16, &Bl[bq + 2][br][0]);
    } else {
      gld16(gBh + k0, &Bh[bq][br][0]);
      gld16(gBl + k0, &Bl[bq][br][0]);
    }
    asm volatile("s_waitcnt vmcnt(0)" ::: "memory");
    __syncthreads();
    short8 ahf[4], alf[4], bhf[NF], blf[NF];
    #pragma unroll
    for (int i = 0; i < 4; i++){
      ahf[i] = *(const short8*)(&Ah[quad][wm + i * 16 + l15][0]);
      alf[i] = *(const short8*)(&Al[quad][wm + i * 16 + l15][0]);
    }
    #pragma unroll
    for (int i = 0; i < NF; i++){
      bhf[i] = *(const short8*)(&Bh[quad][wn + i * 16 + l15][0]);
      blf[i] = *(const short8*)(&Bl[quad][wn + i * 16 + l15][0]);
    }
    #pragma unroll
    for (int mi = 0; mi < 4; mi++)
    #pragma unroll
    for (int ni = 0; ni < NF; ni++){
      acc[mi][ni] = __builtin_amdgcn_mfma_f32_16x16x32_bf16(alf[mi], bhf[ni], acc[mi][ni], 0, 0, 0);
      acc[mi][ni] = __builtin_amdgcn_mfma_f32_16x16x32_bf16(ahf[mi], blf[ni], acc[mi][ni], 0, 0, 0);
      acc[mi][ni] = __builtin_amdgcn_mfma_f32_16x16x32_bf16(ahf[mi], bhf[ni], acc[mi][ni], 0, 0, 0);
    }
  }
  #pragma unroll
  for (int mi = 0; mi < 4; mi++)
  #pragma unroll
  for (int ni = 0; ni < NF; ni++){
    int col = n0 + wn + ni * 16 + l15;
    float bval = bias ? bias[col] : 0.f;
    int rowb = m0 + wm + mi * 16 + quad * 4;
    #pragma unroll
    for (int rg = 0; rg < 4; rg++){
      float v = acc[mi][ni][rg] + bval;
      int row = rowb + rg;
      if (EPI == 0){
        ((float*)C0)[(size_t)row * N + col] = v;
      } else if (EPI == 1){
        float t = v + 0.044715f * v * v * v;
        float g = 0.5f * v * (1.f + tanhf(0.7978845608f * t));
        size_t idx = (size_t)row * N + col;
        u16 h = f2bf(g);
        ((u16*)C0)[idx] = h;
        ((u16*)C1)[idx] = f2bf(g - bf2f(h));
      } else {   // packed KV bf16: part 0 = K dims, part 1 = V dims
        int part = col >> 8, d = col & 255;
        int pc = ((d >> 2) << 3) + (part << 2) + (d & 3);
        ((u16*)C0)[(size_t)row * 512 + pc] = f2bf(v);
      }
    }
  }
}

// ---------------------------------------------------------------------------
// Attention, single pass (online softmax). One wave per token; lane owns dims
// [4*lane,4*lane+4). EKV packed bf16: one 16B load per corner = k4|v4.
// Output: hi/lo bf16 planes (A-operand of out-proj).
// ---------------------------------------------------------------------------
__device__ __forceinline__ void unpack8(int4 p, f4& k4, f4& v4){
  k4.x = bf2f((u16)(p.x & 0xffff)); k4.y = bf2f((u16)((unsigned)p.x >> 16));
  k4.z = bf2f((u16)(p.y & 0xffff)); k4.w = bf2f((u16)((unsigned)p.y >> 16));
  v4.x = bf2f((u16)(p.z & 0xffff)); v4.y = bf2f((u16)((unsigned)p.z >> 16));
  v4.z = bf2f((u16)(p.w & 0xffff)); v4.w = bf2f((u16)((unsigned)p.w >> 16));
}

__global__ __launch_bounds__(256) void attn_k(const float* __restrict__ q,
                                              const u16* __restrict__ EKV,
                                              const float* __restrict__ offb,
                                              const float* __restrict__ locb,
                                              const float* __restrict__ kvc,
                                              u16* __restrict__ ah,
                                              u16* __restrict__ al){
  const int tid = threadIdx.x;
  const int wave = tid >> 6, lane = tid & 63;
  const int tok = blockIdx.x * 4 + wave;
  const int base = (tok >> 12) << 12;   // n*4096
  const int4* E = (const int4*)EKV;     // 16B per (row,lane)
  const f4* kvc4 = (const f4*)kvc;
  f4 qv  = *((const f4*)q + (size_t)tok * 64 + lane);
  f4 wk0 = kvc4[lane], wk1 = kvc4[64 + lane], bkv = kvc4[128 + lane];
  f4 wv0 = kvc4[192 + lane], wv1 = kvc4[256 + lane], bvv = kvc4[320 + lane];
  float m = -1e30f, l = 0.f;
  f4 acc = {0.f, 0.f, 0.f, 0.f};
  #pragma unroll
  for (int s = 0; s < 16; s++){
    float y = locb[tok * 32 + s * 2], x = locb[tok * 32 + s * 2 + 1];
    float o0 = offb[tok * 32 + s * 2], o1 = offb[tok * 32 + s * 2 + 1];
    float yf = floorf(y), xf = floorf(x);
    int y0 = (int)yf, x0 = (int)xf;
    int y1 = min(y0 + 1, 63), x1 = min(x0 + 1, 63);
    float wy = y - yf, wx = x - xf;
    int4 p00 = E[(size_t)(base + y0 * 64 + x0) * 64 + lane];
    int4 p01 = E[(size_t)(base + y0 * 64 + x1) * 64 + lane];
    int4 p10 = E[(size_t)(base + y1 * 64 + x0) * 64 + lane];
    int4 p11 = E[(size_t)(base + y1 * 64 + x1) * 64 + lane];
    f4 k00, v00, k01, v01, k10, v10, k11, v11;
    unpack8(p00, k00, v00); unpack8(p01, k01, v01);
    unpack8(p10, k10, v10); unpack8(p11, k11, v11);
    float w00 = (1.f - wy) * (1.f - wx), w01 = (1.f - wy) * wx;
    float w10 = wy * (1.f - wx), w11 = wy * wx;
    f4 kk = w00 * k00 + w01 * k01 + w10 * k10 + w11 * k11;
    f4 vv = w00 * v00 + w01 * v01 + w10 * v10 + w11 * v11;
    kk += o0 * wk0 + o1 * wk1 + bkv;
    vv += o0 * wv0 + o1 * wv1 + bvv;
    float p = qv.x * kk.x + qv.y * kk.y + qv.z * kk.z + qv.w * kk.w;
    p += __shfl_xor(p, 1); p += __shfl_xor(p, 2);
    p += __shfl_xor(p, 4); p += __shfl_xor(p, 8);
    p *= 0.125f;   // /sqrt(64)
    float mn = fmaxf(m, p);
    float cor = __expf(m - mn);
    float wgt = __expf(p - mn);
    l = l * cor + wgt;
    acc = acc * cor + wgt * vv;
    m = mn;
  }
  float inv = 1.f / l;
  f4 o = acc * inv;
  ushort4 h, lo;
  h.x = f2bf(o.x); lo.x = f2bf(o.x - bf2f(h.x));
  h.y = f2bf(o.y); lo.y = f2bf(o.y - bf2f(h.y));
  h.z = f2bf(o.z); lo.z = f2bf(o.z - bf2f(h.z));
  h.w = f2bf(o.w); lo.w = f2bf(o.w - bf2f(h.w));
  *(ushort4*)(ah + (size_t)tok * 256 + lane * 4) = h;
  *(ushort4*)(al + (size_t)tok * 256 + lane * 4) = lo;
}

// ---------------------------------------------------------------------------
// LayerNorm(a + b) * scale + bias. One wave per token.
// INP: 0 -> a0 fp32; 1 -> a0/a1 hi/lo planes.  OUTP: 0 -> fp32; 1 -> planes.
// ---------------------------------------------------------------------------
template<int INP, int OUTP>
__global__ __launch_bounds__(256) void ln_k(const void* __restrict__ a0,
                                            const void* __restrict__ a1,
                                            const float* __restrict__ b,
                                            const float* __restrict__ sc,
                                            const float* __restrict__ bi,
                                            void* __restrict__ o0,
                                            void* __restrict__ o1){
  const int tid = threadIdx.x;
  const int wave = tid >> 6, lane = tid & 63;
  const int tok = blockIdx.x * 4 + wave;
  float x0, x1, x2, x3;
  if (INP){
    ushort4 h = ((const ushort4*)a0)[(size_t)tok * 64 + lane];
    ushort4 lo = ((const ushort4*)a1)[(size_t)tok * 64 + lane];
    x0 = bf2f(h.x) + bf2f(lo.x); x1 = bf2f(h.y) + bf2f(lo.y);
    x2 = bf2f(h.z) + bf2f(lo.z); x3 = bf2f(h.w) + bf2f(lo.w);
  } else {
    f4 av = ((const f4*)a0)[(size_t)tok * 64 + lane];
    x0 = av.x; x1 = av.y; x2 = av.z; x3 = av.w;
  }
  f4 bv = ((const f4*)b)[(size_t)tok * 64 + lane];
  x0 += bv.x; x1 += bv.y; x2 += bv.z; x3 += bv.w;
  float sm = x0 + x1 + x2 + x3;
  float sq = x0 * x0 + x1 * x1 + x2 * x2 + x3 * x3;
  #pragma unroll
  for (int mm = 1; mm < 64; mm <<= 1){ sm += __shfl_xor(sm, mm); sq += __shfl_xor(sq, mm); }
  float mean = sm * (1.f / 256.f);
  float var = sq * (1.f / 256.f) - mean * mean;
  float rs = rsqrtf(var + 1e-6f);
  f4 sv = ((const f4*)sc)[lane];
  f4 bb = ((const f4*)bi)[lane];
  float y0 = (x0 - mean) * rs * sv.x + bb.x;
  float y1 = (x1 - mean) * rs * sv.y + bb.y;
  float y2 = (x2 - mean) * rs * sv.z + bb.z;
  float y3 = (x3 - mean) * rs * sv.w + bb.w;
  if (OUTP){
    ushort4 h, lo;
    h.x = f2bf(y0); lo.x = f2bf(y0 - bf2f(h.x));
    h.y = f2bf(y1); lo.y = f2bf(y1 - bf2f(h.y));
    h.z = f2bf(y2); lo.z = f2bf(y2 - bf2f(h.z));
    h.w = f2bf(y3); lo.w = f2bf(y3 - bf2f(h.w));
    ((ushort4*)o0)[(size_t)tok * 64 + lane] = h;
    ((ushort4*)o1)[(size_t)tok * 64 + lane] = lo;
  } else {
    f4 ov = {y0, y1, y2, y3};
    ((f4*)o0)[(size_t)tok * 64 + lane] = ov;
  }
}

// ---------------------------------------------------------------------------
extern "C" void kernel_launch(void* const* d_in, const int* in_sizes, int n_in,
                              void* d_out, int out_size, void* d_ws, size_t ws_size,
                              hipStream_t stream){
  const float* hs   = (const float*)d_in[0];
  const float* emb  = (const float*)d_in[1];
  const float* Woff = (const float*)d_in[2];
  const float* boff = (const float*)d_in[3];
  const float* Wkvp = (const float*)d_in[4];
  const float* bkvp = (const float*)d_in[5];
  const float* Wq   = (const float*)d_in[6];
  const float* bq   = (const float*)d_in[7];
  const float* Wk   = (const float*)d_in[8];
  const float* bk   = (const float*)d_in[9];
  const float* Wv   = (const float*)d_in[10];
  const float* bv   = (const float*)d_in[11];
  const float* Wo   = (const float*)d_in[12];
  const float* bo   = (const float*)d_in[13];
  const float* ln1s = (const float*)d_in[14];
  const float* ln1b = (const float*)d_in[15];
  const float* ln2s = (const float*)d_in[16];
  const float* ln2b = (const float*)d_in[17];
  const float* W1   = (const float*)d_in[18];
  const float* b1   = (const float*)d_in[19];
  const float* W2   = (const float*)d_in[20];
  const float* b2   = (const float*)d_in[21];

  char* w = (char*)d_ws;
  auto alloc = [&](size_t bytes){ char* p = w; w += (bytes + 255) & ~(size_t)255; return p; };
  // weight planes (live all)
  u16* WqTh = (u16*)alloc(65536 * 2);  u16* WqTl = (u16*)alloc(65536 * 2);
  u16* kvWh = (u16*)alloc(131072 * 2); u16* kvWl = (u16*)alloc(131072 * 2);  // [512,256]
  u16* WoTh = (u16*)alloc(65536 * 2);  u16* WoTl = (u16*)alloc(65536 * 2);
  u16* W1Th = (u16*)alloc(262144 * 2); u16* W1Tl = (u16*)alloc(262144 * 2);
  u16* W2Th = (u16*)alloc(262144 * 2); u16* W2Tl = (u16*)alloc(262144 * 2);
  float* kvc = (float*)alloc(1536 * 4);
  // slot1 (8.4 MB): hs planes (steps 1-4) / attn planes (6-7) / xb planes (8-end)
  char* slot1 = alloc((size_t)NT * 256 * 4);
  u16* hsph = (u16*)slot1;          u16* hspl = hsph + (size_t)NT * 256;
  u16* attnh = hsph;                u16* attnl = hspl;
  u16* xbh = hsph;                  u16* xbl = hspl;
  // slot2 (8.4 MB): emb planes (2-5) / aout fp32 (7-8)
  char* slot2 = alloc((size_t)NT * 256 * 4);
  u16* embh = (u16*)slot2;          u16* embl = embh + (size_t)NT * 256;
  float* aout = (float*)slot2;
  // slot3 (8.4 MB): off+loc (3-6) / mout fp32 (10-11)
  char* slot3 = alloc((size_t)NT * 256 * 4);
  float* off = (float*)slot3;       float* loc = off + (size_t)NT * 32;
  float* mout = (float*)slot3;
  // slot4 (16.8 MB): qb fp32 + EKV bf16 (4-6) / h1 chunk planes (9-10)
  char* slot4 = alloc((size_t)NT * 256 * 8);
  float* qb = (float*)slot4;
  u16* EKV = (u16*)(slot4 + (size_t)NT * 256 * 4);   // [NT,512] packed bf16
  u16* h1h = (u16*)slot4;           u16* h1l = h1h + (size_t)4096 * 1024;
  if ((size_t)(w - (char*)d_ws) > ws_size) return;

  // prep
  split_k<<<2048, 256, 0, stream>>>(hs,  hsph, hspl);
  split_k<<<2048, 256, 0, stream>>>(emb, embh, embl);
  transpose3_k<<<dim3(8, 8),  256, 0, stream>>>(Wq, WqTh, WqTl, 256, 256);
  transpose3_k<<<dim3(8, 8),  256, 0, stream>>>(Wk, kvWh, kvWl, 256, 256);
  transpose3_k<<<dim3(8, 8),  256, 0, stream>>>(Wv, kvWh + 65536, kvWl + 65536, 256, 256);
  transpose3_k<<<dim3(8, 8),  256, 0, stream>>>(Wo, WoTh, WoTl, 256, 256);
  transpose3_k<<<dim3(32, 8), 256, 0, stream>>>(W1, W1Th, W1Tl, 256, 1024);
  transpose3_k<<<dim3(8, 32), 256, 0, stream>>>(W2, W2Th, W2Tl, 1024, 256);
  prepkv_k<<<1, 256, 0, stream>>>(Wkvp, bkvp, Wk, bk, kvc);
  prepkv_k<<<1, 256, 0, stream>>>(Wkvp, bkvp, Wv, bv, kvc + 768);
  offsets_k<<<1024, 256, 0, stream>>>(hs, Woff, boff, off, loc);

  // q and fused K|V projections (project THEN gather: bilinear commutes)
  gemm_k<64, 0><<<dim3(64, 4), 256, 0, stream>>>(hsph, hspl, WqTh, WqTl, bq, qb, nullptr, NT, 256, 256);
  gemm_k<128, 2><<<dim3(64, 4), 256, 0, stream>>>(embh, embl, kvWh, kvWl, nullptr, EKV, nullptr, NT, 512, 256);

  // gather + online-softmax attention
  attn_k<<<2048, 256, 0, stream>>>(qb, EKV, off, loc, kvc, attnh, attnl);

  // out-proj, LN1
  gemm_k<64, 0><<<dim3(64, 4), 256, 0, stream>>>(attnh, attnl, WoTh, WoTl, bo, aout, nullptr, NT, 256, 256);
  ln_k<0, 1><<<2048, 256, 0, stream>>>(hs, nullptr, aout, ln1s, ln1b, xbh, xbl);

  // MLP in two M=4096 chunks (h1 planes fit slot4)
  for (int c = 0; c < 2; c++){
    size_t ao = (size_t)c * 4096 * 256;
    gemm_k<128, 1><<<dim3(32, 8), 256, 0, stream>>>(xbh + ao, xbl + ao, W1Th, W1Tl, b1, h1h, h1l, 4096, 1024, 256);
    gemm_k<64, 0><<<dim3(32, 4), 256, 0, stream>>>(h1h, h1l, W2Th, W2Tl, b2, mout + ao, nullptr, 4096, 256, 1024);
  }
  ln_k<1, 0><<<2048, 256, 0, stream>>>(xbh, xbl, mout, ln2s, ln2b, d_out, nullptr);
}

// Round 6
// 307.904 us; speedup vs baseline: 1.2983x; 1.2983x over previous
//
#include <hip/hip_runtime.h>

// Problem dims
#define NT 8192      // N*H*W tokens
#define DM 256
#define HH 64
#define WW 64

typedef unsigned short u16;
typedef __attribute__((ext_vector_type(8))) short short8;  // 8 x bf16 mfma frag
typedef __attribute__((ext_vector_type(4))) float f4;

__device__ __forceinline__ float bf2f(u16 u){
  union { unsigned int i; float f; } v; v.i = ((unsigned int)u) << 16; return v.f;
}
__device__ __forceinline__ u16 f2bf(float f){
  union { float f; unsigned int i; } v; v.f = f;
  unsigned int r = (v.i + 0x7fffu + ((v.i >> 16) & 1u)) >> 16;
  return (u16)r;
}
// async global->LDS 16B (direct DMA, no VGPR round trip)
__device__ __forceinline__ void gld16(const void* g, void* l){
  __builtin_amdgcn_global_load_lds(
      (const __attribute__((address_space(1))) unsigned int*)g,
      (__attribute__((address_space(3))) unsigned int*)l, 16, 0, 0);
}

// ---------------------------------------------------------------------------
// fp32 -> dual bf16 planes (x = hi + lo, |err| <= 2^-17 rel)
// ---------------------------------------------------------------------------
__global__ __launch_bounds__(256) void split_k(const float* __restrict__ src,
                                               u16* __restrict__ dh,
                                               u16* __restrict__ dl){
  int i = blockIdx.x * 256 + threadIdx.x;
  f4 v = ((const f4*)src)[i];
  ushort4 h, l;
  h.x = f2bf(v.x); l.x = f2bf(v.x - bf2f(h.x));
  h.y = f2bf(v.y); l.y = f2bf(v.y - bf2f(h.y));
  h.z = f2bf(v.z); l.z = f2bf(v.z - bf2f(h.z));
  h.w = f2bf(v.w); l.w = f2bf(v.w - bf2f(h.w));
  ((ushort4*)dh)[i] = h;
  ((ushort4*)dl)[i] = l;
}

// ---------------------------------------------------------------------------
// Transpose fp32 [R,C] -> bf16 hi/lo planes [C,R]
// ---------------------------------------------------------------------------
__global__ __launch_bounds__(256) void transpose3_k(const float* __restrict__ src,
                                                    u16* __restrict__ dh,
                                                    u16* __restrict__ dl,
                                                    int R, int C){
  __shared__ float t[32][33];
  int tx = threadIdx.x & 31, ty = threadIdx.x >> 5;
  int c0 = blockIdx.x * 32, r0 = blockIdx.y * 32;
  for (int i = ty; i < 32; i += 8) t[i][tx] = src[(size_t)(r0 + i) * C + c0 + tx];
  __syncthreads();
  for (int i = ty; i < 32; i += 8){
    float x = t[tx][i];
    u16 h = f2bf(x);
    size_t idx = (size_t)(c0 + i) * R + r0 + tx;
    dh[idx] = h;
    dl[idx] = f2bf(x - bf2f(h));
  }
}

// ---------------------------------------------------------------------------
// Fold W_kvp/b_kvp through Wk (or Wv): out = [Wkk0(256), Wkk1(256), bias2(256)]
// ---------------------------------------------------------------------------
__global__ __launch_bounds__(256) void prepkv_k(const float* __restrict__ Wkvp,
                                                const float* __restrict__ bkvp,
                                                const float* __restrict__ Wx,
                                                const float* __restrict__ bx,
                                                float* __restrict__ outc){
  int e = threadIdx.x;
  float a0 = 0.f, a1 = 0.f, ab = 0.f;
  for (int d = 0; d < 256; d++){
    float w = Wx[d * 256 + e];
    a0 += Wkvp[d] * w;
    a1 += Wkvp[256 + d] * w;
    ab += bkvp[d] * w;
  }
  outc[e] = a0; outc[256 + e] = a1; outc[512 + e] = ab + bx[e];
}

// ---------------------------------------------------------------------------
// Offsets: off = 60*sigmoid(hs @ W_off + b_off) - 30 ; loc = clip(ref+off,0,63)
// ---------------------------------------------------------------------------
__global__ __launch_bounds__(256) void offsets_k(const float* __restrict__ hs,
                                                 const float* __restrict__ Woff,
                                                 const float* __restrict__ boff,
                                                 float* __restrict__ off,
                                                 float* __restrict__ loc){
  __shared__ float hsl[8][256];
  __shared__ float wl[256 * 32];
  const int tid = threadIdx.x;
  const int t0 = blockIdx.x * 8;
  for (int i = tid; i < 8192; i += 256) wl[i] = Woff[i];
  for (int i = tid; i < 2048; i += 256) hsl[i >> 8][i & 255] = hs[(size_t)t0 * 256 + i];
  __syncthreads();
  const int g = tid >> 5, o = tid & 31;
  float acc = 0.f;
  #pragma unroll 8
  for (int d = 0; d < 256; d++) acc += hsl[g][d] * wl[d * 32 + o];
  acc += boff[o];
  float sg = 1.f / (1.f + expf(-acc));
  float of = 60.f * sg - 30.f;
  int tok = t0 + g;
  int hh = (tok >> 6) & 63, ww = tok & 63;
  float base = (o & 1) ? (float)ww : (float)hh;
  float l = fminf(fmaxf(base + of, 0.f), 63.f);
  off[tok * 32 + o] = of;
  loc[tok * 32 + o] = l;
}

// ---------------------------------------------------------------------------
// Split-precision MFMA GEMM. BM=64, BK=32, BN in {64,128}. 4 waves, each a
// 32x(BN/2) subtile of 16x16x32 mfmas. global_load_lds 16B staging.
// APREC 2: A hi/lo planes, product = Al*Bh + Ah*Bl + Ah*Bh  (~2^-17 rel)
// APREC 1: A single bf16 plane, product = Ah*Bl + Ah*Bh
// EPI 0: fp32 +bias -> C0.   EPI 1: gelu(tanh) -> bf16 plane C0.
// EPI 2: bf16 packed-KV layout (row*512 + (d>>2)*8 + part*4 + (d&3)) -> C0.
// grid: (M/64, N/BN) -> >=512 blocks for all shapes here (>=2 blocks/CU).
// ---------------------------------------------------------------------------
template<int BN, int APREC, int EPI>
__global__ __launch_bounds__(256) void gemm_k(const u16* __restrict__ Agh,
                                              const u16* __restrict__ Agl,
                                              const u16* __restrict__ Bgh,
                                              const u16* __restrict__ Bgl,
                                              const float* __restrict__ bias,
                                              void* __restrict__ C0,
                                              int M, int N, int K){
  constexpr int NF = BN / 32;                  // n-frags per wave (2 or 4)
  __shared__ __align__(16) u16 Ah[4][64][8];
  __shared__ __align__(16) u16 Al[APREC == 2 ? 4 : 1][64][8];
  __shared__ __align__(16) u16 Bh[4][BN][8];
  __shared__ __align__(16) u16 Bl[4][BN][8];
  const int m0 = blockIdx.x << 6, n0 = blockIdx.y * BN;
  const int tid = threadIdx.x;
  const int lane = tid & 63, wave = tid >> 6;
  const int quad = lane >> 4, l15 = lane & 15;
  const int wm = (wave >> 1) << 5;
  const int wn = (wave & 1) * (BN >> 1);
  // A staging: 64 rows x 4 k-quads = 256 slots of 16B, one per thread
  const int ar = tid & 63, aq = tid >> 6;
  const u16* gAh = Agh + (size_t)(m0 + ar) * K + aq * 8;
  const u16* gAl = (APREC == 2) ? (Agl + (size_t)(m0 + ar) * K + aq * 8) : nullptr;
  // B staging: BN rows x 4 k-quads; BN=128 -> 2 slots/thread
  const int br = (BN == 128) ? (tid & 127) : (tid & 63);
  const int bq = (BN == 128) ? (tid >> 7) : (tid >> 6);
  const u16* gBh = Bgh + (size_t)(n0 + br) * K + bq * 8;
  const u16* gBl = Bgl + (size_t)(n0 + br) * K + bq * 8;
  f4 acc[2][NF] = {};
  for (int k0 = 0; k0 < K; k0 += 32){
    __syncthreads();
    gld16(gAh + k0, &Ah[aq][ar][0]);
    if (APREC == 2) gld16(gAl + k0, &Al[aq][ar][0]);
    if (BN == 128){
      gld16(gBh + k0,      &Bh[bq][br][0]);
      gld16(gBh + k0 + 16, &Bh[bq + 2][br][0]);
      gld16(gBl + k0,      &Bl[bq][br][0]);
      gld16(gBl + k0 + 16, &Bl[bq + 2][br][0]);
    } else {
      gld16(gBh + k0, &Bh[bq][br][0]);
      gld16(gBl + k0, &Bl[bq][br][0]);
    }
    asm volatile("s_waitcnt vmcnt(0)" ::: "memory");
    __syncthreads();
    short8 ahf[2], alf[2], bhf[NF], blf[NF];
    #pragma unroll
    for (int i = 0; i < 2; i++){
      ahf[i] = *(const short8*)(&Ah[quad][wm + i * 16 + l15][0]);
      if (APREC == 2) alf[i] = *(const short8*)(&Al[quad][wm + i * 16 + l15][0]);
    }
    #pragma unroll
    for (int i = 0; i < NF; i++){
      bhf[i] = *(const short8*)(&Bh[quad][wn + i * 16 + l15][0]);
      blf[i] = *(const short8*)(&Bl[quad][wn + i * 16 + l15][0]);
    }
    #pragma unroll
    for (int mi = 0; mi < 2; mi++)
    #pragma unroll
    for (int ni = 0; ni < NF; ni++){
      if (APREC == 2)
        acc[mi][ni] = __builtin_amdgcn_mfma_f32_16x16x32_bf16(alf[mi], bhf[ni], acc[mi][ni], 0, 0, 0);
      acc[mi][ni] = __builtin_amdgcn_mfma_f32_16x16x32_bf16(ahf[mi], blf[ni], acc[mi][ni], 0, 0, 0);
      acc[mi][ni] = __builtin_amdgcn_mfma_f32_16x16x32_bf16(ahf[mi], bhf[ni], acc[mi][ni], 0, 0, 0);
    }
  }
  #pragma unroll
  for (int mi = 0; mi < 2; mi++)
  #pragma unroll
  for (int ni = 0; ni < NF; ni++){
    int col = n0 + wn + ni * 16 + l15;
    float bval = bias ? bias[col] : 0.f;
    int rowb = m0 + wm + mi * 16 + quad * 4;
    #pragma unroll
    for (int rg = 0; rg < 4; rg++){
      float v = acc[mi][ni][rg] + bval;
      int row = rowb + rg;
      if (EPI == 0){
        ((float*)C0)[(size_t)row * N + col] = v;
      } else if (EPI == 1){
        float t = v + 0.044715f * v * v * v;
        float g = 0.5f * v * (1.f + tanhf(0.7978845608f * t));
        ((u16*)C0)[(size_t)row * N + col] = f2bf(g);
      } else {   // packed KV bf16: part 0 = K dims, part 1 = V dims
        int part = col >> 8, d = col & 255;
        int pc = ((d >> 2) << 3) + (part << 2) + (d & 3);
        ((u16*)C0)[(size_t)row * 512 + pc] = f2bf(v);
      }
    }
  }
}

// ---------------------------------------------------------------------------
// Attention, single pass (online softmax). One wave per token; lane owns dims
// [4*lane,4*lane+4). EKV packed bf16: one 16B load per corner = k4|v4.
// Output: hi/lo bf16 planes (A-operand of out-proj).
// ---------------------------------------------------------------------------
__device__ __forceinline__ void unpack8(int4 p, f4& k4, f4& v4){
  k4.x = bf2f((u16)(p.x & 0xffff)); k4.y = bf2f((u16)((unsigned)p.x >> 16));
  k4.z = bf2f((u16)(p.y & 0xffff)); k4.w = bf2f((u16)((unsigned)p.y >> 16));
  v4.x = bf2f((u16)(p.z & 0xffff)); v4.y = bf2f((u16)((unsigned)p.z >> 16));
  v4.z = bf2f((u16)(p.w & 0xffff)); v4.w = bf2f((u16)((unsigned)p.w >> 16));
}

__global__ __launch_bounds__(256) void attn_k(const float* __restrict__ q,
                                              const u16* __restrict__ EKV,
                                              const float* __restrict__ offb,
                                              const float* __restrict__ locb,
                                              const float* __restrict__ kvc,
                                              u16* __restrict__ ah,
                                              u16* __restrict__ al){
  const int tid = threadIdx.x;
  const int wave = tid >> 6, lane = tid & 63;
  const int tok = blockIdx.x * 4 + wave;
  const int base = (tok >> 12) << 12;   // n*4096
  const int4* E = (const int4*)EKV;     // 16B per (row,lane)
  const f4* kvc4 = (const f4*)kvc;
  f4 qv  = *((const f4*)q + (size_t)tok * 64 + lane);
  f4 wk0 = kvc4[lane], wk1 = kvc4[64 + lane], bkv = kvc4[128 + lane];
  f4 wv0 = kvc4[192 + lane], wv1 = kvc4[256 + lane], bvv = kvc4[320 + lane];
  float m = -1e30f, l = 0.f;
  f4 acc = {0.f, 0.f, 0.f, 0.f};
  #pragma unroll
  for (int s = 0; s < 16; s++){
    float y = locb[tok * 32 + s * 2], x = locb[tok * 32 + s * 2 + 1];
    float o0 = offb[tok * 32 + s * 2], o1 = offb[tok * 32 + s * 2 + 1];
    float yf = floorf(y), xf = floorf(x);
    int y0 = (int)yf, x0 = (int)xf;
    int y1 = min(y0 + 1, 63), x1 = min(x0 + 1, 63);
    float wy = y - yf, wx = x - xf;
    int4 p00 = E[(size_t)(base + y0 * 64 + x0) * 64 + lane];
    int4 p01 = E[(size_t)(base + y0 * 64 + x1) * 64 + lane];
    int4 p10 = E[(size_t)(base + y1 * 64 + x0) * 64 + lane];
    int4 p11 = E[(size_t)(base + y1 * 64 + x1) * 64 + lane];
    f4 k00, v00, k01, v01, k10, v10, k11, v11;
    unpack8(p00, k00, v00); unpack8(p01, k01, v01);
    unpack8(p10, k10, v10); unpack8(p11, k11, v11);
    float w00 = (1.f - wy) * (1.f - wx), w01 = (1.f - wy) * wx;
    float w10 = wy * (1.f - wx), w11 = wy * wx;
    f4 kk = w00 * k00 + w01 * k01 + w10 * k10 + w11 * k11;
    f4 vv = w00 * v00 + w01 * v01 + w10 * v10 + w11 * v11;
    kk += o0 * wk0 + o1 * wk1 + bkv;
    vv += o0 * wv0 + o1 * wv1 + bvv;
    float p = qv.x * kk.x + qv.y * kk.y + qv.z * kk.z + qv.w * kk.w;
    p += __shfl_xor(p, 1); p += __shfl_xor(p, 2);
    p += __shfl_xor(p, 4); p += __shfl_xor(p, 8);
    p *= 0.125f;   // /sqrt(64)
    float mn = fmaxf(m, p);
    float cor = __expf(m - mn);
    float wgt = __expf(p - mn);
    l = l * cor + wgt;
    acc = acc * cor + wgt * vv;
    m = mn;
  }
  float inv = 1.f / l;
  f4 o = acc * inv;
  ushort4 h, lo;
  h.x = f2bf(o.x); lo.x = f2bf(o.x - bf2f(h.x));
  h.y = f2bf(o.y); lo.y = f2bf(o.y - bf2f(h.y));
  h.z = f2bf(o.z); lo.z = f2bf(o.z - bf2f(h.z));
  h.w = f2bf(o.w); lo.w = f2bf(o.w - bf2f(h.w));
  *(ushort4*)(ah + (size_t)tok * 256 + lane * 4) = h;
  *(ushort4*)(al + (size_t)tok * 256 + lane * 4) = lo;
}

// ---------------------------------------------------------------------------
// LayerNorm(a + b) * scale + bias. One wave per token.
// INP: 0 -> a0 fp32; 1 -> a0/a1 hi/lo planes.  OUTP: 0 -> fp32; 1 -> planes.
// ---------------------------------------------------------------------------
template<int INP, int OUTP>
__global__ __launch_bounds__(256) void ln_k(const void* __restrict__ a0,
                                            const void* __restrict__ a1,
                                            const float* __restrict__ b,
                                            const float* __restrict__ sc,
                                            const float* __restrict__ bi,
                                            void* __restrict__ o0,
                                            void* __restrict__ o1){
  const int tid = threadIdx.x;
  const int wave = tid >> 6, lane = tid & 63;
  const int tok = blockIdx.x * 4 + wave;
  float x0, x1, x2, x3;
  if (INP){
    ushort4 h = ((const ushort4*)a0)[(size_t)tok * 64 + lane];
    ushort4 lo = ((const ushort4*)a1)[(size_t)tok * 64 + lane];
    x0 = bf2f(h.x) + bf2f(lo.x); x1 = bf2f(h.y) + bf2f(lo.y);
    x2 = bf2f(h.z) + bf2f(lo.z); x3 = bf2f(h.w) + bf2f(lo.w);
  } else {
    f4 av = ((const f4*)a0)[(size_t)tok * 64 + lane];
    x0 = av.x; x1 = av.y; x2 = av.z; x3 = av.w;
  }
  f4 bv = ((const f4*)b)[(size_t)tok * 64 + lane];
  x0 += bv.x; x1 += bv.y; x2 += bv.z; x3 += bv.w;
  float sm = x0 + x1 + x2 + x3;
  float sq = x0 * x0 + x1 * x1 + x2 * x2 + x3 * x3;
  #pragma unroll
  for (int mm = 1; mm < 64; mm <<= 1){ sm += __shfl_xor(sm, mm); sq += __shfl_xor(sq, mm); }
  float mean = sm * (1.f / 256.f);
  float var = sq * (1.f / 256.f) - mean * mean;
  float rs = rsqrtf(var + 1e-6f);
  f4 sv = ((const f4*)sc)[lane];
  f4 bb = ((const f4*)bi)[lane];
  float y0 = (x0 - mean) * rs * sv.x + bb.x;
  float y1 = (x1 - mean) * rs * sv.y + bb.y;
  float y2 = (x2 - mean) * rs * sv.z + bb.z;
  float y3 = (x3 - mean) * rs * sv.w + bb.w;
  if (OUTP){
    ushort4 h, lo;
    h.x = f2bf(y0); lo.x = f2bf(y0 - bf2f(h.x));
    h.y = f2bf(y1); lo.y = f2bf(y1 - bf2f(h.y));
    h.z = f2bf(y2); lo.z = f2bf(y2 - bf2f(h.z));
    h.w = f2bf(y3); lo.w = f2bf(y3 - bf2f(h.w));
    ((ushort4*)o0)[(size_t)tok * 64 + lane] = h;
    ((ushort4*)o1)[(size_t)tok * 64 + lane] = lo;
  } else {
    f4 ov = {y0, y1, y2, y3};
    ((f4*)o0)[(size_t)tok * 64 + lane] = ov;
  }
}

// ---------------------------------------------------------------------------
extern "C" void kernel_launch(void* const* d_in, const int* in_sizes, int n_in,
                              void* d_out, int out_size, void* d_ws, size_t ws_size,
                              hipStream_t stream){
  const float* hs   = (const float*)d_in[0];
  const float* emb  = (const float*)d_in[1];
  const float* Woff = (const float*)d_in[2];
  const float* boff = (const float*)d_in[3];
  const float* Wkvp = (const float*)d_in[4];
  const float* bkvp = (const float*)d_in[5];
  const float* Wq   = (const float*)d_in[6];
  const float* bq   = (const float*)d_in[7];
  const float* Wk   = (const float*)d_in[8];
  const float* bk   = (const float*)d_in[9];
  const float* Wv   = (const float*)d_in[10];
  const float* bv   = (const float*)d_in[11];
  const float* Wo   = (const float*)d_in[12];
  const float* bo   = (const float*)d_in[13];
  const float* ln1s = (const float*)d_in[14];
  const float* ln1b = (const float*)d_in[15];
  const float* ln2s = (const float*)d_in[16];
  const float* ln2b = (const float*)d_in[17];
  const float* W1   = (const float*)d_in[18];
  const float* b1   = (const float*)d_in[19];
  const float* W2   = (const float*)d_in[20];
  const float* b2   = (const float*)d_in[21];

  char* w = (char*)d_ws;
  auto alloc = [&](size_t bytes){ char* p = w; w += (bytes + 255) & ~(size_t)255; return p; };
  // weight planes (live whole launch)
  u16* WqTh = (u16*)alloc(65536 * 2);  u16* WqTl = (u16*)alloc(65536 * 2);
  u16* kvWh = (u16*)alloc(131072 * 2); u16* kvWl = (u16*)alloc(131072 * 2);  // [512,256]
  u16* WoTh = (u16*)alloc(65536 * 2);  u16* WoTl = (u16*)alloc(65536 * 2);
  u16* W1Th = (u16*)alloc(262144 * 2); u16* W1Tl = (u16*)alloc(262144 * 2);
  u16* W2Th = (u16*)alloc(262144 * 2); u16* W2Tl = (u16*)alloc(262144 * 2);
  float* kvc = (float*)alloc(1536 * 4);
  // slot1 (8.4 MB): hs planes / attn planes / xb planes
  char* slot1 = alloc((size_t)NT * 256 * 4);
  u16* hsph = (u16*)slot1;          u16* hspl = hsph + (size_t)NT * 256;
  u16* attnh = hsph;                u16* attnl = hspl;
  u16* xbh = hsph;                  u16* xbl = hspl;
  // slot2 (8.4 MB): emb planes / aout fp32
  char* slot2 = alloc((size_t)NT * 256 * 4);
  u16* embh = (u16*)slot2;          u16* embl = embh + (size_t)NT * 256;
  float* aout = (float*)slot2;
  // slot3 (8.4 MB): off+loc / mout fp32
  char* slot3 = alloc((size_t)NT * 256 * 4);
  float* off = (float*)slot3;       float* loc = off + (size_t)NT * 32;
  float* mout = (float*)slot3;
  // slot4 (16.8 MB): qb fp32 + EKV bf16 / h1 bf16 [NT,1024] (16 MB)
  char* slot4 = alloc((size_t)NT * 256 * 8);
  float* qb = (float*)slot4;
  u16* EKV = (u16*)(slot4 + (size_t)NT * 256 * 4);   // [NT,512] packed bf16
  u16* h1 = (u16*)slot4;                             // [NT,1024] bf16 plane
  if ((size_t)(w - (char*)d_ws) > ws_size) return;

  // prep
  split_k<<<2048, 256, 0, stream>>>(hs,  hsph, hspl);
  split_k<<<2048, 256, 0, stream>>>(emb, embh, embl);
  transpose3_k<<<dim3(8, 8),  256, 0, stream>>>(Wq, WqTh, WqTl, 256, 256);
  transpose3_k<<<dim3(8, 8),  256, 0, stream>>>(Wk, kvWh, kvWl, 256, 256);
  transpose3_k<<<dim3(8, 8),  256, 0, stream>>>(Wv, kvWh + 65536, kvWl + 65536, 256, 256);
  transpose3_k<<<dim3(8, 8),  256, 0, stream>>>(Wo, WoTh, WoTl, 256, 256);
  transpose3_k<<<dim3(32, 8), 256, 0, stream>>>(W1, W1Th, W1Tl, 256, 1024);
  transpose3_k<<<dim3(8, 32), 256, 0, stream>>>(W2, W2Th, W2Tl, 1024, 256);
  prepkv_k<<<1, 256, 0, stream>>>(Wkvp, bkvp, Wk, bk, kvc);
  prepkv_k<<<1, 256, 0, stream>>>(Wkvp, bkvp, Wv, bv, kvc + 768);
  offsets_k<<<1024, 256, 0, stream>>>(hs, Woff, boff, off, loc);

  // q and fused K|V projections (project THEN gather: bilinear commutes)
  gemm_k<64, 2, 0><<<dim3(128, 4), 256, 0, stream>>>(hsph, hspl, WqTh, WqTl, bq, qb, NT, 256, 256);
  gemm_k<128, 2, 2><<<dim3(128, 4), 256, 0, stream>>>(embh, embl, kvWh, kvWl, nullptr, EKV, NT, 512, 256);

  // gather + online-softmax attention
  attn_k<<<2048, 256, 0, stream>>>(qb, EKV, off, loc, kvc, attnh, attnl);

  // out-proj, LN1, MLP, LN2  (all full-M, >=512-block grids)
  gemm_k<64, 2, 0><<<dim3(128, 4), 256, 0, stream>>>(attnh, attnl, WoTh, WoTl, bo, aout, NT, 256, 256);
  ln_k<0, 1><<<2048, 256, 0, stream>>>(hs, nullptr, aout, ln1s, ln1b, xbh, xbl);
  gemm_k<128, 2, 1><<<dim3(128, 8), 256, 0, stream>>>(xbh, xbl, W1Th, W1Tl, b1, h1, NT, 1024, 256);
  gemm_k<64, 1, 0><<<dim3(128, 4), 256, 0, stream>>>(h1, nullptr, W2Th, W2Tl, b2, mout, NT, 256, 1024);
  ln_k<1, 0><<<2048, 256, 0, stream>>>(xbh, xbl, mout, ln2s, ln2b, d_out, nullptr);
}

// Round 7
// 275.232 us; speedup vs baseline: 1.4524x; 1.1187x over previous
//
#include <hip/hip_runtime.h>

// Problem dims
#define NT 8192      // N*H*W tokens
#define DM 256
#define HH 64
#define WW 64

typedef unsigned short u16;
typedef __attribute__((ext_vector_type(8))) short short8;  // 8 x bf16 mfma frag
typedef __attribute__((ext_vector_type(4))) float f4;

__device__ __forceinline__ float bf2f(u16 u){
  union { unsigned int i; float f; } v; v.i = ((unsigned int)u) << 16; return v.f;
}
__device__ __forceinline__ u16 f2bf(float f){
  union { float f; unsigned int i; } v; v.f = f;
  unsigned int r = (v.i + 0x7fffu + ((v.i >> 16) & 1u)) >> 16;
  return (u16)r;
}
// async global->LDS 16B (direct DMA, no VGPR round trip)
__device__ __forceinline__ void gld16(const void* g, void* l){
  __builtin_amdgcn_global_load_lds(
      (const __attribute__((address_space(1))) unsigned int*)g,
      (__attribute__((address_space(3))) unsigned int*)l, 16, 0, 0);
}

// ---------------------------------------------------------------------------
// fp32 -> dual bf16 planes (x = hi + lo, |err| <= 2^-17 rel)
// ---------------------------------------------------------------------------
__global__ __launch_bounds__(256) void split_k(const float* __restrict__ src,
                                               u16* __restrict__ dh,
                                               u16* __restrict__ dl){
  int i = blockIdx.x * 256 + threadIdx.x;
  f4 v = ((const f4*)src)[i];
  ushort4 h, l;
  h.x = f2bf(v.x); l.x = f2bf(v.x - bf2f(h.x));
  h.y = f2bf(v.y); l.y = f2bf(v.y - bf2f(h.y));
  h.z = f2bf(v.z); l.z = f2bf(v.z - bf2f(h.z));
  h.w = f2bf(v.w); l.w = f2bf(v.w - bf2f(h.w));
  ((ushort4*)dh)[i] = h;
  ((ushort4*)dl)[i] = l;
}

// ---------------------------------------------------------------------------
// fp32 -> single bf16 plane
// ---------------------------------------------------------------------------
__global__ __launch_bounds__(256) void cvt_k(const float* __restrict__ src,
                                             u16* __restrict__ dst){
  int i = blockIdx.x * 256 + threadIdx.x;
  f4 v = ((const f4*)src)[i];
  ushort4 o;
  o.x = f2bf(v.x); o.y = f2bf(v.y); o.z = f2bf(v.z); o.w = f2bf(v.w);
  ((ushort4*)dst)[i] = o;
}

// ---------------------------------------------------------------------------
// Batched transpose of four fp32 [256,256] -> bf16 hi/lo planes [z][256,256]^T
// ---------------------------------------------------------------------------
__global__ __launch_bounds__(256) void transposeB_k(const float* __restrict__ s0,
                                                    const float* __restrict__ s1,
                                                    const float* __restrict__ s2,
                                                    const float* __restrict__ s3,
                                                    u16* __restrict__ dh,
                                                    u16* __restrict__ dl){
  const float* src = blockIdx.z == 0 ? s0 : blockIdx.z == 1 ? s1
                   : blockIdx.z == 2 ? s2 : s3;
  u16* dhp = dh + (size_t)blockIdx.z * 65536;
  u16* dlp = dl + (size_t)blockIdx.z * 65536;
  __shared__ float t[32][33];
  int tx = threadIdx.x & 31, ty = threadIdx.x >> 5;
  int c0 = blockIdx.x * 32, r0 = blockIdx.y * 32;
  for (int i = ty; i < 32; i += 8) t[i][tx] = src[(r0 + i) * 256 + c0 + tx];
  __syncthreads();
  for (int i = ty; i < 32; i += 8){
    float x = t[tx][i];
    u16 h = f2bf(x);
    int idx = (c0 + i) * 256 + r0 + tx;
    dhp[idx] = h;
    dlp[idx] = f2bf(x - bf2f(h));
  }
}

// ---------------------------------------------------------------------------
// Transpose fp32 [R,C] -> bf16 hi/lo planes [C,R]  (W1 / W2)
// ---------------------------------------------------------------------------
__global__ __launch_bounds__(256) void transpose3_k(const float* __restrict__ src,
                                                    u16* __restrict__ dh,
                                                    u16* __restrict__ dl,
                                                    int R, int C){
  __shared__ float t[32][33];
  int tx = threadIdx.x & 31, ty = threadIdx.x >> 5;
  int c0 = blockIdx.x * 32, r0 = blockIdx.y * 32;
  for (int i = ty; i < 32; i += 8) t[i][tx] = src[(size_t)(r0 + i) * C + c0 + tx];
  __syncthreads();
  for (int i = ty; i < 32; i += 8){
    float x = t[tx][i];
    u16 h = f2bf(x);
    size_t idx = (size_t)(c0 + i) * R + r0 + tx;
    dh[idx] = h;
    dl[idx] = f2bf(x - bf2f(h));
  }
}

// ---------------------------------------------------------------------------
// Fold W_kvp/b_kvp through Wk (block 0) and Wv (block 1) -> kvc[1536]
// ---------------------------------------------------------------------------
__global__ __launch_bounds__(256) void prepkv_k(const float* __restrict__ Wkvp,
                                                const float* __restrict__ bkvp,
                                                const float* __restrict__ Wk,
                                                const float* __restrict__ bk,
                                                const float* __restrict__ Wv,
                                                const float* __restrict__ bv,
                                                float* __restrict__ outc){
  const float* Wx = blockIdx.x == 0 ? Wk : Wv;
  const float* bx = blockIdx.x == 0 ? bk : bv;
  float* o = outc + blockIdx.x * 768;
  int e = threadIdx.x;
  float a0 = 0.f, a1 = 0.f, ab = 0.f;
  for (int d = 0; d < 256; d++){
    float w = Wx[d * 256 + e];
    a0 += Wkvp[d] * w;
    a1 += Wkvp[256 + d] * w;
    ab += bkvp[d] * w;
  }
  o[e] = a0; o[256 + e] = a1; o[512 + e] = ab + bx[e];
}

// ---------------------------------------------------------------------------
// Offsets: off = 60*sigmoid(hs @ W_off + b_off) - 30 ; loc = clip(ref+off,0,63)
// ---------------------------------------------------------------------------
__global__ __launch_bounds__(256) void offsets_k(const float* __restrict__ hs,
                                                 const float* __restrict__ Woff,
                                                 const float* __restrict__ boff,
                                                 float* __restrict__ off,
                                                 float* __restrict__ loc){
  __shared__ float hsl[8][256];
  __shared__ float wl[256 * 32];
  const int tid = threadIdx.x;
  const int t0 = blockIdx.x * 8;
  for (int i = tid; i < 8192; i += 256) wl[i] = Woff[i];
  for (int i = tid; i < 2048; i += 256) hsl[i >> 8][i & 255] = hs[(size_t)t0 * 256 + i];
  __syncthreads();
  const int g = tid >> 5, o = tid & 31;
  float acc = 0.f;
  #pragma unroll 8
  for (int d = 0; d < 256; d++) acc += hsl[g][d] * wl[d * 32 + o];
  acc += boff[o];
  float sg = 1.f / (1.f + expf(-acc));
  float of = 60.f * sg - 30.f;
  int tok = t0 + g;
  int hh = (tok >> 6) & 63, ww = tok & 63;
  float base = (o & 1) ? (float)ww : (float)hh;
  float l = fminf(fmaxf(base + of, 0.f), 63.f);
  off[tok * 32 + o] = of;
  loc[tok * 32 + o] = l;
}

// ---------------------------------------------------------------------------
// Split-precision MFMA GEMM. BM=64, BK=64, BN in {64,128}. 4 waves, each a
// 32x(BN/2) subtile of 16x16x32 mfmas. global_load_lds 16B staging.
// APREC 2: A hi/lo planes -> Al*Bh + Ah*Bl + Ah*Bh  (~2^-17 rel)
// APREC 1: A single bf16 plane -> Ah*Bl + Ah*Bh     (~2^-9; use when output
//          is bf16-rounded anyway)
// EPI 0: fp32 +bias -> C0.   EPI 1: gelu(tanh) -> bf16 plane C0.
// EPI 2: bf16 packed-KV layout (row*512 + (d>>2)*8 + part*4 + (d&3)) -> C0.
// ---------------------------------------------------------------------------
template<int BN, int APREC, int EPI>
__global__ __launch_bounds__(256) void gemm_k(const u16* __restrict__ Agh,
                                              const u16* __restrict__ Agl,
                                              const u16* __restrict__ Bgh,
                                              const u16* __restrict__ Bgl,
                                              const float* __restrict__ bias,
                                              void* __restrict__ C0,
                                              int M, int N, int K){
  constexpr int NF = BN / 32;                  // n-frags per wave (2 or 4)
  __shared__ __align__(16) u16 Ah[8][64][8];
  __shared__ __align__(16) u16 Al[APREC == 2 ? 8 : 1][64][8];
  __shared__ __align__(16) u16 Bh[8][BN][8];
  __shared__ __align__(16) u16 Bl[8][BN][8];
  const int m0 = blockIdx.x << 6, n0 = blockIdx.y * BN;
  const int tid = threadIdx.x;
  const int lane = tid & 63, wave = tid >> 6;
  const int quad = lane >> 4, l15 = lane & 15;
  const int wm = (wave >> 1) << 5;
  const int wn = (wave & 1) * (BN >> 1);
  // A staging: 64 rows x 8 k-quads = 512 slots of 16B; thread t -> slots t, t+256
  const int ar = tid & 63, aq = tid >> 6;       // slot t: quad aq in 0..3; slot t+256: aq+4
  const u16* gAh = Agh + (size_t)(m0 + ar) * K + aq * 8;
  const u16* gAl = (APREC == 2) ? (Agl + (size_t)(m0 + ar) * K + aq * 8) : nullptr;
  // B staging: BN rows x 8 quads. BN=64: same scheme as A. BN=128: 4 slots/thread.
  const int br = (BN == 128) ? (tid & 127) : (tid & 63);
  const int bq = (BN == 128) ? (tid >> 7) : (tid >> 6);
  const u16* gBh = Bgh + (size_t)(n0 + br) * K + bq * 8;
  const u16* gBl = Bgl + (size_t)(n0 + br) * K + bq * 8;
  f4 acc[2][NF] = {};
  for (int k0 = 0; k0 < K; k0 += 64){
    __syncthreads();
    gld16(gAh + k0,      &Ah[aq][ar][0]);
    gld16(gAh + k0 + 32, &Ah[aq + 4][ar][0]);
    if (APREC == 2){
      gld16(gAl + k0,      &Al[aq][ar][0]);
      gld16(gAl + k0 + 32, &Al[aq + 4][ar][0]);
    }
    if (BN == 128){
      gld16(gBh + k0,      &Bh[bq][br][0]);
      gld16(gBh + k0 + 16, &Bh[bq + 2][br][0]);
      gld16(gBh + k0 + 32, &Bh[bq + 4][br][0]);
      gld16(gBh + k0 + 48, &Bh[bq + 6][br][0]);
      gld16(gBl + k0,      &Bl[bq][br][0]);
      gld16(gBl + k0 + 16, &Bl[bq + 2][br][0]);
      gld16(gBl + k0 + 32, &Bl[bq + 4][br][0]);
      gld16(gBl + k0 + 48, &Bl[bq + 6][br][0]);
    } else {
      gld16(gBh + k0,      &Bh[bq][br][0]);
      gld16(gBh + k0 + 32, &Bh[bq + 4][br][0]);
      gld16(gBl + k0,      &Bl[bq][br][0]);
      gld16(gBl + k0 + 32, &Bl[bq + 4][br][0]);
    }
    asm volatile("s_waitcnt vmcnt(0)" ::: "memory");
    __syncthreads();
    #pragma unroll
    for (int kh = 0; kh < 2; kh++){
      const int q = kh * 4 + quad;
      short8 ahf[2], alf[2], bhf[NF], blf[NF];
      #pragma unroll
      for (int i = 0; i < 2; i++){
        ahf[i] = *(const short8*)(&Ah[q][wm + i * 16 + l15][0]);
        if (APREC == 2) alf[i] = *(const short8*)(&Al[q][wm + i * 16 + l15][0]);
      }
      #pragma unroll
      for (int i = 0; i < NF; i++){
        bhf[i] = *(const short8*)(&Bh[q][wn + i * 16 + l15][0]);
        blf[i] = *(const short8*)(&Bl[q][wn + i * 16 + l15][0]);
      }
      #pragma unroll
      for (int mi = 0; mi < 2; mi++)
      #pragma unroll
      for (int ni = 0; ni < NF; ni++){
        if (APREC == 2)
          acc[mi][ni] = __builtin_amdgcn_mfma_f32_16x16x32_bf16(alf[mi], bhf[ni], acc[mi][ni], 0, 0, 0);
        acc[mi][ni] = __builtin_amdgcn_mfma_f32_16x16x32_bf16(ahf[mi], blf[ni], acc[mi][ni], 0, 0, 0);
        acc[mi][ni] = __builtin_amdgcn_mfma_f32_16x16x32_bf16(ahf[mi], bhf[ni], acc[mi][ni], 0, 0, 0);
      }
    }
  }
  #pragma unroll
  for (int mi = 0; mi < 2; mi++)
  #pragma unroll
  for (int ni = 0; ni < NF; ni++){
    int col = n0 + wn + ni * 16 + l15;
    float bval = bias ? bias[col] : 0.f;
    int rowb = m0 + wm + mi * 16 + quad * 4;
    #pragma unroll
    for (int rg = 0; rg < 4; rg++){
      float v = acc[mi][ni][rg] + bval;
      int row = rowb + rg;
      if (EPI == 0){
        ((float*)C0)[(size_t)row * N + col] = v;
      } else if (EPI == 1){
        float t = v + 0.044715f * v * v * v;
        float g = 0.5f * v * (1.f + tanhf(0.7978845608f * t));
        ((u16*)C0)[(size_t)row * N + col] = f2bf(g);
      } else {   // packed KV bf16: part 0 = K dims, part 1 = V dims
        int part = col >> 8, d = col & 255;
        int pc = ((d >> 2) << 3) + (part << 2) + (d & 3);
        ((u16*)C0)[(size_t)row * 512 + pc] = f2bf(v);
      }
    }
  }
}

// ---------------------------------------------------------------------------
// Attention, single pass (online softmax). One wave per token; lane owns dims
// [4*lane,4*lane+4). EKV packed bf16: one 16B load per corner = k4|v4.
// Output: hi/lo bf16 planes (A-operand of out-proj).
// ---------------------------------------------------------------------------
__device__ __forceinline__ void unpack8(int4 p, f4& k4, f4& v4){
  k4.x = bf2f((u16)(p.x & 0xffff)); k4.y = bf2f((u16)((unsigned)p.x >> 16));
  k4.z = bf2f((u16)(p.y & 0xffff)); k4.w = bf2f((u16)((unsigned)p.y >> 16));
  v4.x = bf2f((u16)(p.z & 0xffff)); v4.y = bf2f((u16)((unsigned)p.z >> 16));
  v4.z = bf2f((u16)(p.w & 0xffff)); v4.w = bf2f((u16)((unsigned)p.w >> 16));
}

__global__ __launch_bounds__(256) void attn_k(const float* __restrict__ q,
                                              const u16* __restrict__ EKV,
                                              const float* __restrict__ offb,
                                              const float* __restrict__ locb,
                                              const float* __restrict__ kvc,
                                              u16* __restrict__ ah,
                                              u16* __restrict__ al){
  const int tid = threadIdx.x;
  const int wave = tid >> 6, lane = tid & 63;
  const int tok = blockIdx.x * 4 + wave;
  const int base = (tok >> 12) << 12;   // n*4096
  const int4* E = (const int4*)EKV;     // 16B per (row,lane)
  const f4* kvc4 = (const f4*)kvc;
  f4 qv  = *((const f4*)q + (size_t)tok * 64 + lane);
  f4 wk0 = kvc4[lane], wk1 = kvc4[64 + lane], bkv = kvc4[128 + lane];
  f4 wv0 = kvc4[192 + lane], wv1 = kvc4[256 + lane], bvv = kvc4[320 + lane];
  float m = -1e30f, l = 0.f;
  f4 acc = {0.f, 0.f, 0.f, 0.f};
  #pragma unroll
  for (int s = 0; s < 16; s++){
    float y = locb[tok * 32 + s * 2], x = locb[tok * 32 + s * 2 + 1];
    float o0 = offb[tok * 32 + s * 2], o1 = offb[tok * 32 + s * 2 + 1];
    float yf = floorf(y), xf = floorf(x);
    int y0 = (int)yf, x0 = (int)xf;
    int y1 = min(y0 + 1, 63), x1 = min(x0 + 1, 63);
    float wy = y - yf, wx = x - xf;
    int4 p00 = E[(size_t)(base + y0 * 64 + x0) * 64 + lane];
    int4 p01 = E[(size_t)(base + y0 * 64 + x1) * 64 + lane];
    int4 p10 = E[(size_t)(base + y1 * 64 + x0) * 64 + lane];
    int4 p11 = E[(size_t)(base + y1 * 64 + x1) * 64 + lane];
    f4 k00, v00, k01, v01, k10, v10, k11, v11;
    unpack8(p00, k00, v00); unpack8(p01, k01, v01);
    unpack8(p10, k10, v10); unpack8(p11, k11, v11);
    float w00 = (1.f - wy) * (1.f - wx), w01 = (1.f - wy) * wx;
    float w10 = wy * (1.f - wx), w11 = wy * wx;
    f4 kk = w00 * k00 + w01 * k01 + w10 * k10 + w11 * k11;
    f4 vv = w00 * v00 + w01 * v01 + w10 * v10 + w11 * v11;
    kk += o0 * wk0 + o1 * wk1 + bkv;
    vv += o0 * wv0 + o1 * wv1 + bvv;
    float p = qv.x * kk.x + qv.y * kk.y + qv.z * kk.z + qv.w * kk.w;
    p += __shfl_xor(p, 1); p += __shfl_xor(p, 2);
    p += __shfl_xor(p, 4); p += __shfl_xor(p, 8);
    p *= 0.125f;   // /sqrt(64)
    float mn = fmaxf(m, p);
    float cor = __expf(m - mn);
    float wgt = __expf(p - mn);
    l = l * cor + wgt;
    acc = acc * cor + wgt * vv;
    m = mn;
  }
  float inv = 1.f / l;
  f4 o = acc * inv;
  ushort4 h, lo;
  h.x = f2bf(o.x); lo.x = f2bf(o.x - bf2f(h.x));
  h.y = f2bf(o.y); lo.y = f2bf(o.y - bf2f(h.y));
  h.z = f2bf(o.z); lo.z = f2bf(o.z - bf2f(h.z));
  h.w = f2bf(o.w); lo.w = f2bf(o.w - bf2f(h.w));
  *(ushort4*)(ah + (size_t)tok * 256 + lane * 4) = h;
  *(ushort4*)(al + (size_t)tok * 256 + lane * 4) = lo;
}

// ---------------------------------------------------------------------------
// LayerNorm(a + b) * scale + bias. One wave per token.
// INP: 0 -> a0 fp32; 1 -> a0/a1 hi/lo planes.  OUTP: 0 -> fp32; 1 -> planes.
// ---------------------------------------------------------------------------
template<int INP, int OUTP>
__global__ __launch_bounds__(256) void ln_k(const void* __restrict__ a0,
                                            const void* __restrict__ a1,
                                            const float* __restrict__ b,
                                            const float* __restrict__ sc,
                                            const float* __restrict__ bi,
                                            void* __restrict__ o0,
                                            void* __restrict__ o1){
  const int tid = threadIdx.x;
  const int wave = tid >> 6, lane = tid & 63;
  const int tok = blockIdx.x * 4 + wave;
  float x0, x1, x2, x3;
  if (INP){
    ushort4 h = ((const ushort4*)a0)[(size_t)tok * 64 + lane];
    ushort4 lo = ((const ushort4*)a1)[(size_t)tok * 64 + lane];
    x0 = bf2f(h.x) + bf2f(lo.x); x1 = bf2f(h.y) + bf2f(lo.y);
    x2 = bf2f(h.z) + bf2f(lo.z); x3 = bf2f(h.w) + bf2f(lo.w);
  } else {
    f4 av = ((const f4*)a0)[(size_t)tok * 64 + lane];
    x0 = av.x; x1 = av.y; x2 = av.z; x3 = av.w;
  }
  f4 bv = ((const f4*)b)[(size_t)tok * 64 + lane];
  x0 += bv.x; x1 += bv.y; x2 += bv.z; x3 += bv.w;
  float sm = x0 + x1 + x2 + x3;
  float sq = x0 * x0 + x1 * x1 + x2 * x2 + x3 * x3;
  #pragma unroll
  for (int mm = 1; mm < 64; mm <<= 1){ sm += __shfl_xor(sm, mm); sq += __shfl_xor(sq, mm); }
  float mean = sm * (1.f / 256.f);
  float var = sq * (1.f / 256.f) - mean * mean;
  float rs = rsqrtf(var + 1e-6f);
  f4 sv = ((const f4*)sc)[lane];
  f4 bb = ((const f4*)bi)[lane];
  float y0 = (x0 - mean) * rs * sv.x + bb.x;
  float y1 = (x1 - mean) * rs * sv.y + bb.y;
  float y2 = (x2 - mean) * rs * sv.z + bb.z;
  float y3 = (x3 - mean) * rs * sv.w + bb.w;
  if (OUTP){
    ushort4 h, lo;
    h.x = f2bf(y0); lo.x = f2bf(y0 - bf2f(h.x));
    h.y = f2bf(y1); lo.y = f2bf(y1 - bf2f(h.y));
    h.z = f2bf(y2); lo.z = f2bf(y2 - bf2f(h.z));
    h.w = f2bf(y3); lo.w = f2bf(y3 - bf2f(h.w));
    ((ushort4*)o0)[(size_t)tok * 64 + lane] = h;
    ((ushort4*)o1)[(size_t)tok * 64 + lane] = lo;
  } else {
    f4 ov = {y0, y1, y2, y3};
    ((f4*)o0)[(size_t)tok * 64 + lane] = ov;
  }
}

// ---------------------------------------------------------------------------
extern "C" void kernel_launch(void* const* d_in, const int* in_sizes, int n_in,
                              void* d_out, int out_size, void* d_ws, size_t ws_size,
                              hipStream_t stream){
  const float* hs   = (const float*)d_in[0];
  const float* emb  = (const float*)d_in[1];
  const float* Woff = (const float*)d_in[2];
  const float* boff = (const float*)d_in[3];
  const float* Wkvp = (const float*)d_in[4];
  const float* bkvp = (const float*)d_in[5];
  const float* Wq   = (const float*)d_in[6];
  const float* bq   = (const float*)d_in[7];
  const float* Wk   = (const float*)d_in[8];
  const float* bk   = (const float*)d_in[9];
  const float* Wv   = (const float*)d_in[10];
  const float* bv   = (const float*)d_in[11];
  const float* Wo   = (const float*)d_in[12];
  const float* bo   = (const float*)d_in[13];
  const float* ln1s = (const float*)d_in[14];
  const float* ln1b = (const float*)d_in[15];
  const float* ln2s = (const float*)d_in[16];
  const float* ln2b = (const float*)d_in[17];
  const float* W1   = (const float*)d_in[18];
  const float* b1   = (const float*)d_in[19];
  const float* W2   = (const float*)d_in[20];
  const float* b2   = (const float*)d_in[21];

  char* w = (char*)d_ws;
  auto alloc = [&](size_t bytes){ char* p = w; w += (bytes + 255) & ~(size_t)255; return p; };
  // weight planes: [WqT | WkT | WvT | WoT] contiguous hi and lo
  u16* qkvoTh = (u16*)alloc(4 * 65536 * 2);
  u16* qkvoTl = (u16*)alloc(4 * 65536 * 2);
  u16* WqTh = qkvoTh;              u16* WqTl = qkvoTl;
  u16* kvWh = qkvoTh + 65536;      u16* kvWl = qkvoTl + 65536;   // [512,256]
  u16* WoTh = qkvoTh + 3 * 65536;  u16* WoTl = qkvoTl + 3 * 65536;
  u16* W1Th = (u16*)alloc(262144 * 2); u16* W1Tl = (u16*)alloc(262144 * 2);
  u16* W2Th = (u16*)alloc(262144 * 2); u16* W2Tl = (u16*)alloc(262144 * 2);
  float* kvc = (float*)alloc(1536 * 4);
  // slot1 (8.4 MB): hs planes / attn planes / xb planes
  char* slot1 = alloc((size_t)NT * 256 * 4);
  u16* hsph = (u16*)slot1;          u16* hspl = hsph + (size_t)NT * 256;
  u16* attnh = hsph;                u16* attnl = hspl;
  u16* xbh = hsph;                  u16* xbl = hspl;
  // slot2 (8.4 MB): emb bf16 plane / aout fp32
  char* slot2 = alloc((size_t)NT * 256 * 4);
  u16* embh = (u16*)slot2;
  float* aout = (float*)slot2;
  // slot3 (8.4 MB): off+loc / mout fp32
  char* slot3 = alloc((size_t)NT * 256 * 4);
  float* off = (float*)slot3;       float* loc = off + (size_t)NT * 32;
  float* mout = (float*)slot3;
  // slot4 (16.8 MB): qb fp32 + EKV bf16 / h1 bf16 [NT,1024] (16 MB)
  char* slot4 = alloc((size_t)NT * 256 * 8);
  float* qb = (float*)slot4;
  u16* EKV = (u16*)(slot4 + (size_t)NT * 256 * 4);   // [NT,512] packed bf16
  u16* h1 = (u16*)slot4;                             // [NT,1024] bf16 plane
  if ((size_t)(w - (char*)d_ws) > ws_size) return;

  // prep
  split_k<<<2048, 256, 0, stream>>>(hs, hsph, hspl);
  cvt_k<<<2048, 256, 0, stream>>>(emb, embh);
  transposeB_k<<<dim3(8, 8, 4), 256, 0, stream>>>(Wq, Wk, Wv, Wo, qkvoTh, qkvoTl);
  transpose3_k<<<dim3(32, 8), 256, 0, stream>>>(W1, W1Th, W1Tl, 256, 1024);
  transpose3_k<<<dim3(8, 32), 256, 0, stream>>>(W2, W2Th, W2Tl, 1024, 256);
  prepkv_k<<<2, 256, 0, stream>>>(Wkvp, bkvp, Wk, bk, Wv, bv, kvc);
  offsets_k<<<1024, 256, 0, stream>>>(hs, Woff, boff, off, loc);

  // q (3-pass) and fused K|V (2-pass; output is bf16-packed anyway)
  gemm_k<64, 2, 0><<<dim3(128, 4), 256, 0, stream>>>(hsph, hspl, WqTh, WqTl, bq, qb, NT, 256, 256);
  gemm_k<128, 1, 2><<<dim3(128, 4), 256, 0, stream>>>(embh, nullptr, kvWh, kvWl, nullptr, EKV, NT, 512, 256);

  // gather + online-softmax attention
  attn_k<<<2048, 256, 0, stream>>>(qb, EKV, off, loc, kvc, attnh, attnl);

  // out-proj (3-pass), LN1, MLP (W1 2-pass: h1 is bf16 anyway; W2 2-pass), LN2
  gemm_k<64, 2, 0><<<dim3(128, 4), 256, 0, stream>>>(attnh, attnl, WoTh, WoTl, bo, aout, NT, 256, 256);
  ln_k<0, 1><<<2048, 256, 0, stream>>>(hs, nullptr, aout, ln1s, ln1b, xbh, xbl);
  gemm_k<128, 1, 1><<<dim3(128, 8), 256, 0, stream>>>(xbh, nullptr, W1Th, W1Tl, b1, h1, NT, 1024, 256);
  gemm_k<64, 1, 0><<<dim3(128, 4), 256, 0, stream>>>(h1, nullptr, W2Th, W2Tl, b2, mout, NT, 256, 1024);
  ln_k<1, 0><<<2048, 256, 0, stream>>>(xbh, xbl, mout, ln2s, ln2b, d_out, nullptr);
}

// Round 9
// 273.794 us; speedup vs baseline: 1.4600x; 1.0052x over previous
//
#include <hip/hip_runtime.h>

// Problem dims
#define NT 8192      // N*H*W tokens
#define DM 256
#define HH 64
#define WW 64

typedef unsigned short u16;
typedef __attribute__((ext_vector_type(8))) short short8;  // 8 x bf16 mfma frag
typedef __attribute__((ext_vector_type(4))) float f4;

__device__ __forceinline__ float bf2f(u16 u){
  union { unsigned int i; float f; } v; v.i = ((unsigned int)u) << 16; return v.f;
}
__device__ __forceinline__ u16 f2bf(float f){
  union { float f; unsigned int i; } v; v.f = f;
  unsigned int r = (v.i + 0x7fffu + ((v.i >> 16) & 1u)) >> 16;
  return (u16)r;
}
// async global->LDS 16B (direct DMA, no VGPR round trip)
__device__ __forceinline__ void gld16(const void* g, void* l){
  __builtin_amdgcn_global_load_lds(
      (const __attribute__((address_space(1))) unsigned int*)g,
      (__attribute__((address_space(3))) unsigned int*)l, 16, 0, 0);
}

// ---------------------------------------------------------------------------
// fp32 -> dual bf16 planes (x = hi + lo, |err| <= 2^-17 rel)
// ---------------------------------------------------------------------------
__global__ __launch_bounds__(256) void split_k(const float* __restrict__ src,
                                               u16* __restrict__ dh,
                                               u16* __restrict__ dl){
  int i = blockIdx.x * 256 + threadIdx.x;
  f4 v = ((const f4*)src)[i];
  ushort4 h, l;
  h.x = f2bf(v.x); l.x = f2bf(v.x - bf2f(h.x));
  h.y = f2bf(v.y); l.y = f2bf(v.y - bf2f(h.y));
  h.z = f2bf(v.z); l.z = f2bf(v.z - bf2f(h.z));
  h.w = f2bf(v.w); l.w = f2bf(v.w - bf2f(h.w));
  ((ushort4*)dh)[i] = h;
  ((ushort4*)dl)[i] = l;
}

// ---------------------------------------------------------------------------
// fp32 -> single bf16 plane
// ---------------------------------------------------------------------------
__global__ __launch_bounds__(256) void cvt_k(const float* __restrict__ src,
                                             u16* __restrict__ dst){
  int i = blockIdx.x * 256 + threadIdx.x;
  f4 v = ((const f4*)src)[i];
  ushort4 o;
  o.x = f2bf(v.x); o.y = f2bf(v.y); o.z = f2bf(v.z); o.w = f2bf(v.w);
  ((ushort4*)dst)[i] = o;
}

// ---------------------------------------------------------------------------
// Batched transpose of four fp32 [256,256] -> bf16 hi/lo planes [z][256,256]^T
// ---------------------------------------------------------------------------
__global__ __launch_bounds__(256) void transposeB_k(const float* __restrict__ s0,
                                                    const float* __restrict__ s1,
                                                    const float* __restrict__ s2,
                                                    const float* __restrict__ s3,
                                                    u16* __restrict__ dh,
                                                    u16* __restrict__ dl){
  const float* src = blockIdx.z == 0 ? s0 : blockIdx.z == 1 ? s1
                   : blockIdx.z == 2 ? s2 : s3;
  u16* dhp = dh + (size_t)blockIdx.z * 65536;
  u16* dlp = dl + (size_t)blockIdx.z * 65536;
  __shared__ float t[32][33];
  int tx = threadIdx.x & 31, ty = threadIdx.x >> 5;
  int c0 = blockIdx.x * 32, r0 = blockIdx.y * 32;
  for (int i = ty; i < 32; i += 8) t[i][tx] = src[(r0 + i) * 256 + c0 + tx];
  __syncthreads();
  for (int i = ty; i < 32; i += 8){
    float x = t[tx][i];
    u16 h = f2bf(x);
    int idx = (c0 + i) * 256 + r0 + tx;
    dhp[idx] = h;
    dlp[idx] = f2bf(x - bf2f(h));
  }
}

// ---------------------------------------------------------------------------
// Transpose fp32 [R,C] -> bf16 hi/lo planes [C,R]  (W1 / W2)
// ---------------------------------------------------------------------------
__global__ __launch_bounds__(256) void transpose3_k(const float* __restrict__ src,
                                                    u16* __restrict__ dh,
                                                    u16* __restrict__ dl,
                                                    int R, int C){
  __shared__ float t[32][33];
  int tx = threadIdx.x & 31, ty = threadIdx.x >> 5;
  int c0 = blockIdx.x * 32, r0 = blockIdx.y * 32;
  for (int i = ty; i < 32; i += 8) t[i][tx] = src[(size_t)(r0 + i) * C + c0 + tx];
  __syncthreads();
  for (int i = ty; i < 32; i += 8){
    float x = t[tx][i];
    u16 h = f2bf(x);
    size_t idx = (size_t)(c0 + i) * R + r0 + tx;
    dh[idx] = h;
    dl[idx] = f2bf(x - bf2f(h));
  }
}

// ---------------------------------------------------------------------------
// Fold W_kvp/b_kvp through Wk (block 0) and Wv (block 1) -> kvc[1536]
// ---------------------------------------------------------------------------
__global__ __launch_bounds__(256) void prepkv_k(const float* __restrict__ Wkvp,
                                                const float* __restrict__ bkvp,
                                                const float* __restrict__ Wk,
                                                const float* __restrict__ bk,
                                                const float* __restrict__ Wv,
                                                const float* __restrict__ bv,
                                                float* __restrict__ outc){
  const float* Wx = blockIdx.x == 0 ? Wk : Wv;
  const float* bx = blockIdx.x == 0 ? bk : bv;
  float* o = outc + blockIdx.x * 768;
  int e = threadIdx.x;
  float a0 = 0.f, a1 = 0.f, ab = 0.f;
  for (int d = 0; d < 256; d++){
    float w = Wx[d * 256 + e];
    a0 += Wkvp[d] * w;
    a1 += Wkvp[256 + d] * w;
    ab += bkvp[d] * w;
  }
  o[e] = a0; o[256 + e] = a1; o[512 + e] = ab + bx[e];
}

// ---------------------------------------------------------------------------
// Offsets: off = 60*sigmoid(hs @ W_off + b_off) - 30 ; loc = clip(ref+off,0,63)
// ---------------------------------------------------------------------------
__global__ __launch_bounds__(256) void offsets_k(const float* __restrict__ hs,
                                                 const float* __restrict__ Woff,
                                                 const float* __restrict__ boff,
                                                 float* __restrict__ off,
                                                 float* __restrict__ loc){
  __shared__ float hsl[8][256];
  __shared__ float wl[256 * 32];
  const int tid = threadIdx.x;
  const int t0 = blockIdx.x * 8;
  for (int i = tid; i < 8192; i += 256) wl[i] = Woff[i];
  for (int i = tid; i < 2048; i += 256) hsl[i >> 8][i & 255] = hs[(size_t)t0 * 256 + i];
  __syncthreads();
  const int g = tid >> 5, o = tid & 31;
  float acc = 0.f;
  #pragma unroll 8
  for (int d = 0; d < 256; d++) acc += hsl[g][d] * wl[d * 32 + o];
  acc += boff[o];
  float sg = 1.f / (1.f + expf(-acc));
  float of = 60.f * sg - 30.f;
  int tok = t0 + g;
  int hh = (tok >> 6) & 63, ww = tok & 63;
  float base = (o & 1) ? (float)ww : (float)hh;
  float l = fminf(fmaxf(base + of, 0.f), 63.f);
  off[tok * 32 + o] = of;
  loc[tok * 32 + o] = l;
}

// ---------------------------------------------------------------------------
// Split-precision MFMA GEMM. BM=64, BK=64, BN in {64,128}. 4 waves, each a
// 32x(BN/2) subtile of 16x16x32 mfmas. global_load_lds 16B staging.
// APREC 2: A hi/lo planes -> Al*Bh + Ah*Bl + Ah*Bh  (~2^-17 rel)
// APREC 1: A single bf16 plane -> Ah*Bl + Ah*Bh     (~2^-9; use when output
//          is bf16-rounded anyway)
// EPI 0: fp32 +bias -> C0.   EPI 1: gelu(tanh) -> bf16 plane C0.
// EPI 2: bf16 packed-KV layout (row*512 + (d>>2)*8 + part*4 + (d&3)) -> C0.
// ---------------------------------------------------------------------------
template<int BN, int APREC, int EPI>
__global__ __launch_bounds__(256) void gemm_k(const u16* __restrict__ Agh,
                                              const u16* __restrict__ Agl,
                                              const u16* __restrict__ Bgh,
                                              const u16* __restrict__ Bgl,
                                              const float* __restrict__ bias,
                                              void* __restrict__ C0,
                                              int M, int N, int K){
  constexpr int NF = BN / 32;                  // n-frags per wave (2 or 4)
  __shared__ __align__(16) u16 Ah[8][64][8];
  __shared__ __align__(16) u16 Al[APREC == 2 ? 8 : 1][64][8];
  __shared__ __align__(16) u16 Bh[8][BN][8];
  __shared__ __align__(16) u16 Bl[8][BN][8];
  const int m0 = blockIdx.x << 6, n0 = blockIdx.y * BN;
  const int tid = threadIdx.x;
  const int lane = tid & 63, wave = tid >> 6;
  const int quad = lane >> 4, l15 = lane & 15;
  const int wm = (wave >> 1) << 5;
  const int wn = (wave & 1) * (BN >> 1);
  // A staging: 64 rows x 8 k-quads = 512 slots of 16B; thread t -> slots t, t+256
  const int ar = tid & 63, aq = tid >> 6;       // slot t: quad aq in 0..3; slot t+256: aq+4
  const u16* gAh = Agh + (size_t)(m0 + ar) * K + aq * 8;
  const u16* gAl = (APREC == 2) ? (Agl + (size_t)(m0 + ar) * K + aq * 8) : nullptr;
  // B staging: BN rows x 8 quads. BN=64: same scheme as A. BN=128: 4 slots/thread.
  const int br = (BN == 128) ? (tid & 127) : (tid & 63);
  const int bq = (BN == 128) ? (tid >> 7) : (tid >> 6);
  const u16* gBh = Bgh + (size_t)(n0 + br) * K + bq * 8;
  const u16* gBl = Bgl + (size_t)(n0 + br) * K + bq * 8;
  f4 acc[2][NF] = {};
  for (int k0 = 0; k0 < K; k0 += 64){
    __syncthreads();
    gld16(gAh + k0,      &Ah[aq][ar][0]);
    gld16(gAh + k0 + 32, &Ah[aq + 4][ar][0]);
    if (APREC == 2){
      gld16(gAl + k0,      &Al[aq][ar][0]);
      gld16(gAl + k0 + 32, &Al[aq + 4][ar][0]);
    }
    if (BN == 128){
      gld16(gBh + k0,      &Bh[bq][br][0]);
      gld16(gBh + k0 + 16, &Bh[bq + 2][br][0]);
      gld16(gBh + k0 + 32, &Bh[bq + 4][br][0]);
      gld16(gBh + k0 + 48, &Bh[bq + 6][br][0]);
      gld16(gBl + k0,      &Bl[bq][br][0]);
      gld16(gBl + k0 + 16, &Bl[bq + 2][br][0]);
      gld16(gBl + k0 + 32, &Bl[bq + 4][br][0]);
      gld16(gBl + k0 + 48, &Bl[bq + 6][br][0]);
    } else {
      gld16(gBh + k0,      &Bh[bq][br][0]);
      gld16(gBh + k0 + 32, &Bh[bq + 4][br][0]);
      gld16(gBl + k0,      &Bl[bq][br][0]);
      gld16(gBl + k0 + 32, &Bl[bq + 4][br][0]);
    }
    asm volatile("s_waitcnt vmcnt(0)" ::: "memory");
    __syncthreads();
    #pragma unroll
    for (int kh = 0; kh < 2; kh++){
      const int q = kh * 4 + quad;
      short8 ahf[2], alf[2], bhf[NF], blf[NF];
      #pragma unroll
      for (int i = 0; i < 2; i++){
        ahf[i] = *(const short8*)(&Ah[q][wm + i * 16 + l15][0]);
        if (APREC == 2) alf[i] = *(const short8*)(&Al[q][wm + i * 16 + l15][0]);
      }
      #pragma unroll
      for (int i = 0; i < NF; i++){
        bhf[i] = *(const short8*)(&Bh[q][wn + i * 16 + l15][0]);
        blf[i] = *(const short8*)(&Bl[q][wn + i * 16 + l15][0]);
      }
      #pragma unroll
      for (int mi = 0; mi < 2; mi++)
      #pragma unroll
      for (int ni = 0; ni < NF; ni++){
        if (APREC == 2)
          acc[mi][ni] = __builtin_amdgcn_mfma_f32_16x16x32_bf16(alf[mi], bhf[ni], acc[mi][ni], 0, 0, 0);
        acc[mi][ni] = __builtin_amdgcn_mfma_f32_16x16x32_bf16(ahf[mi], blf[ni], acc[mi][ni], 0, 0, 0);
        acc[mi][ni] = __builtin_amdgcn_mfma_f32_16x16x32_bf16(ahf[mi], bhf[ni], acc[mi][ni], 0, 0, 0);
      }
    }
  }
  #pragma unroll
  for (int mi = 0; mi < 2; mi++)
  #pragma unroll
  for (int ni = 0; ni < NF; ni++){
    int col = n0 + wn + ni * 16 + l15;
    float bval = bias ? bias[col] : 0.f;
    int rowb = m0 + wm + mi * 16 + quad * 4;
    #pragma unroll
    for (int rg = 0; rg < 4; rg++){
      float v = acc[mi][ni][rg] + bval;
      int row = rowb + rg;
      if (EPI == 0){
        ((float*)C0)[(size_t)row * N + col] = v;
      } else if (EPI == 1){
        float t = v + 0.044715f * v * v * v;
        float g = 0.5f * v * (1.f + tanhf(0.7978845608f * t));
        ((u16*)C0)[(size_t)row * N + col] = f2bf(g);
      } else {   // packed KV bf16: part 0 = K dims, part 1 = V dims
        int part = col >> 8, d = col & 255;
        int pc = ((d >> 2) << 3) + (part << 2) + (d & 3);
        ((u16*)C0)[(size_t)row * 512 + pc] = f2bf(v);
      }
    }
  }
}

// ---------------------------------------------------------------------------
// Attention, single pass (online softmax). One wave per token; lane owns dims
// [4*lane,4*lane+4). EKV packed bf16: one 16B load per corner = k4|v4.
// Output: bf16 hi plane only (O-proj runs 2-pass on it).
// ---------------------------------------------------------------------------
__device__ __forceinline__ void unpack8(int4 p, f4& k4, f4& v4){
  k4.x = bf2f((u16)(p.x & 0xffff)); k4.y = bf2f((u16)((unsigned)p.x >> 16));
  k4.z = bf2f((u16)(p.y & 0xffff)); k4.w = bf2f((u16)((unsigned)p.y >> 16));
  v4.x = bf2f((u16)(p.z & 0xffff)); v4.y = bf2f((u16)((unsigned)p.z >> 16));
  v4.z = bf2f((u16)(p.w & 0xffff)); v4.w = bf2f((u16)((unsigned)p.w >> 16));
}

__global__ __launch_bounds__(256) void attn_k(const float* __restrict__ q,
                                              const u16* __restrict__ EKV,
                                              const float* __restrict__ offb,
                                              const float* __restrict__ locb,
                                              const float* __restrict__ kvc,
                                              u16* __restrict__ ah){
  const int tid = threadIdx.x;
  const int wave = tid >> 6, lane = tid & 63;
  const int tok = blockIdx.x * 4 + wave;
  const int base = (tok >> 12) << 12;   // n*4096
  const int4* E = (const int4*)EKV;     // 16B per (row,lane)
  const f4* kvc4 = (const f4*)kvc;
  f4 qv  = *((const f4*)q + (size_t)tok * 64 + lane);
  f4 wk0 = kvc4[lane], wk1 = kvc4[64 + lane], bkv = kvc4[128 + lane];
  f4 wv0 = kvc4[192 + lane], wv1 = kvc4[256 + lane], bvv = kvc4[320 + lane];
  float m = -1e30f, l = 0.f;
  f4 acc = {0.f, 0.f, 0.f, 0.f};
  #pragma unroll
  for (int s = 0; s < 16; s++){
    float y = locb[tok * 32 + s * 2], x = locb[tok * 32 + s * 2 + 1];
    float o0 = offb[tok * 32 + s * 2], o1 = offb[tok * 32 + s * 2 + 1];
    float yf = floorf(y), xf = floorf(x);
    int y0 = (int)yf, x0 = (int)xf;
    int y1 = min(y0 + 1, 63), x1 = min(x0 + 1, 63);
    float wy = y - yf, wx = x - xf;
    int4 p00 = E[(size_t)(base + y0 * 64 + x0) * 64 + lane];
    int4 p01 = E[(size_t)(base + y0 * 64 + x1) * 64 + lane];
    int4 p10 = E[(size_t)(base + y1 * 64 + x0) * 64 + lane];
    int4 p11 = E[(size_t)(base + y1 * 64 + x1) * 64 + lane];
    f4 k00, v00, k01, v01, k10, v10, k11, v11;
    unpack8(p00, k00, v00); unpack8(p01, k01, v01);
    unpack8(p10, k10, v10); unpack8(p11, k11, v11);
    float w00 = (1.f - wy) * (1.f - wx), w01 = (1.f - wy) * wx;
    float w10 = wy * (1.f - wx), w11 = wy * wx;
    f4 kk = w00 * k00 + w01 * k01 + w10 * k10 + w11 * k11;
    f4 vv = w00 * v00 + w01 * v01 + w10 * v10 + w11 * v11;
    kk += o0 * wk0 + o1 * wk1 + bkv;
    vv += o0 * wv0 + o1 * wv1 + bvv;
    float p = qv.x * kk.x + qv.y * kk.y + qv.z * kk.z + qv.w * kk.w;
    p += __shfl_xor(p, 1); p += __shfl_xor(p, 2);
    p += __shfl_xor(p, 4); p += __shfl_xor(p, 8);
    p *= 0.125f;   // /sqrt(64)
    float mn = fmaxf(m, p);
    float cor = __expf(m - mn);
    float wgt = __expf(p - mn);
    l = l * cor + wgt;
    acc = acc * cor + wgt * vv;
    m = mn;
  }
  float inv = 1.f / l;
  f4 o = acc * inv;
  ushort4 h;
  h.x = f2bf(o.x); h.y = f2bf(o.y); h.z = f2bf(o.z); h.w = f2bf(o.w);
  *(ushort4*)(ah + (size_t)tok * 256 + lane * 4) = h;
}

// ---------------------------------------------------------------------------
// LayerNorm(a + b) * scale + bias. One wave per token.
// INP: 0 -> a0 fp32; 1 -> a0/a1 hi/lo planes.  OUTP: 0 -> fp32; 1 -> planes.
// ---------------------------------------------------------------------------
template<int INP, int OUTP>
__global__ __launch_bounds__(256) void ln_k(const void* __restrict__ a0,
                                            const void* __restrict__ a1,
                                            const float* __restrict__ b,
                                            const float* __restrict__ sc,
                                            const float* __restrict__ bi,
                                            void* __restrict__ o0,
                                            void* __restrict__ o1){
  const int tid = threadIdx.x;
  const int wave = tid >> 6, lane = tid & 63;
  const int tok = blockIdx.x * 4 + wave;
  float x0, x1, x2, x3;
  if (INP){
    ushort4 h = ((const ushort4*)a0)[(size_t)tok * 64 + lane];
    ushort4 lo = ((const ushort4*)a1)[(size_t)tok * 64 + lane];
    x0 = bf2f(h.x) + bf2f(lo.x); x1 = bf2f(h.y) + bf2f(lo.y);
    x2 = bf2f(h.z) + bf2f(lo.z); x3 = bf2f(h.w) + bf2f(lo.w);
  } else {
    f4 av = ((const f4*)a0)[(size_t)tok * 64 + lane];
    x0 = av.x; x1 = av.y; x2 = av.z; x3 = av.w;
  }
  f4 bv = ((const f4*)b)[(size_t)tok * 64 + lane];
  x0 += bv.x; x1 += bv.y; x2 += bv.z; x3 += bv.w;
  float sm = x0 + x1 + x2 + x3;
  float sq = x0 * x0 + x1 * x1 + x2 * x2 + x3 * x3;
  #pragma unroll
  for (int mm = 1; mm < 64; mm <<= 1){ sm += __shfl_xor(sm, mm); sq += __shfl_xor(sq, mm); }
  float mean = sm * (1.f / 256.f);
  float var = sq * (1.f / 256.f) - mean * mean;
  float rs = rsqrtf(var + 1e-6f);
  f4 sv = ((const f4*)sc)[lane];
  f4 bb = ((const f4*)bi)[lane];
  float y0 = (x0 - mean) * rs * sv.x + bb.x;
  float y1 = (x1 - mean) * rs * sv.y + bb.y;
  float y2 = (x2 - mean) * rs * sv.z + bb.z;
  float y3 = (x3 - mean) * rs * sv.w + bb.w;
  if (OUTP){
    ushort4 h, lo;
    h.x = f2bf(y0); lo.x = f2bf(y0 - bf2f(h.x));
    h.y = f2bf(y1); lo.y = f2bf(y1 - bf2f(h.y));
    h.z = f2bf(y2); lo.z = f2bf(y2 - bf2f(h.z));
    h.w = f2bf(y3); lo.w = f2bf(y3 - bf2f(h.w));
    ((ushort4*)o0)[(size_t)tok * 64 + lane] = h;
    ((ushort4*)o1)[(size_t)tok * 64 + lane] = lo;
  } else {
    f4 ov = {y0, y1, y2, y3};
    ((f4*)o0)[(size_t)tok * 64 + lane] = ov;
  }
}

// ---------------------------------------------------------------------------
extern "C" void kernel_launch(void* const* d_in, const int* in_sizes, int n_in,
                              void* d_out, int out_size, void* d_ws, size_t ws_size,
                              hipStream_t stream){
  const float* hs   = (const float*)d_in[0];
  const float* emb  = (const float*)d_in[1];
  const float* Woff = (const float*)d_in[2];
  const float* boff = (const float*)d_in[3];
  const float* Wkvp = (const float*)d_in[4];
  const float* bkvp = (const float*)d_in[5];
  const float* Wq   = (const float*)d_in[6];
  const float* bq   = (const float*)d_in[7];
  const float* Wk   = (const float*)d_in[8];
  const float* bk   = (const float*)d_in[9];
  const float* Wv   = (const float*)d_in[10];
  const float* bv   = (const float*)d_in[11];
  const float* Wo   = (const float*)d_in[12];
  const float* bo   = (const float*)d_in[13];
  const float* ln1s = (const float*)d_in[14];
  const float* ln1b = (const float*)d_in[15];
  const float* ln2s = (const float*)d_in[16];
  const float* ln2b = (const float*)d_in[17];
  const float* W1   = (const float*)d_in[18];
  const float* b1   = (const float*)d_in[19];
  const float* W2   = (const float*)d_in[20];
  const float* b2   = (const float*)d_in[21];

  char* w = (char*)d_ws;
  auto alloc = [&](size_t bytes){ char* p = w; w += (bytes + 255) & ~(size_t)255; return p; };
  // weight planes: [WqT | WkT | WvT | WoT] contiguous hi and lo
  u16* qkvoTh = (u16*)alloc(4 * 65536 * 2);
  u16* qkvoTl = (u16*)alloc(4 * 65536 * 2);
  u16* WqTh = qkvoTh;              u16* WqTl = qkvoTl;
  u16* kvWh = qkvoTh + 65536;      u16* kvWl = qkvoTl + 65536;   // [512,256]
  u16* WoTh = qkvoTh + 3 * 65536;  u16* WoTl = qkvoTl + 3 * 65536;
  u16* W1Th = (u16*)alloc(262144 * 2); u16* W1Tl = (u16*)alloc(262144 * 2);
  u16* W2Th = (u16*)alloc(262144 * 2); u16* W2Tl = (u16*)alloc(262144 * 2);
  float* kvc = (float*)alloc(1536 * 4);
  // slot1 (8.4 MB): hs planes / attn hi plane / xb planes
  char* slot1 = alloc((size_t)NT * 256 * 4);
  u16* hsph = (u16*)slot1;          u16* hspl = hsph + (size_t)NT * 256;
  u16* attnh = hsph;
  u16* xbh = hsph;                  u16* xbl = hspl;
  // slot2 (8.4 MB): emb bf16 plane / aout fp32
  char* slot2 = alloc((size_t)NT * 256 * 4);
  u16* embh = (u16*)slot2;
  float* aout = (float*)slot2;
  // slot3 (8.4 MB): off+loc / mout fp32
  char* slot3 = alloc((size_t)NT * 256 * 4);
  float* off = (float*)slot3;       float* loc = off + (size_t)NT * 32;
  float* mout = (float*)slot3;
  // slot4 (16.8 MB): qb fp32 + EKV bf16 / h1 bf16 [NT,1024] (16 MB)
  char* slot4 = alloc((size_t)NT * 256 * 8);
  float* qb = (float*)slot4;
  u16* EKV = (u16*)(slot4 + (size_t)NT * 256 * 4);   // [NT,512] packed bf16
  u16* h1 = (u16*)slot4;                             // [NT,1024] bf16 plane
  if ((size_t)(w - (char*)d_ws) > ws_size) return;

  // prep (r7-proven kernels)
  split_k<<<2048, 256, 0, stream>>>(hs, hsph, hspl);
  cvt_k<<<2048, 256, 0, stream>>>(emb, embh);
  transposeB_k<<<dim3(8, 8, 4), 256, 0, stream>>>(Wq, Wk, Wv, Wo, qkvoTh, qkvoTl);
  transpose3_k<<<dim3(32, 8), 256, 0, stream>>>(W1, W1Th, W1Tl, 256, 1024);
  transpose3_k<<<dim3(8, 32), 256, 0, stream>>>(W2, W2Th, W2Tl, 1024, 256);
  prepkv_k<<<2, 256, 0, stream>>>(Wkvp, bkvp, Wk, bk, Wv, bv, kvc);
  offsets_k<<<1024, 256, 0, stream>>>(hs, Woff, boff, off, loc);

  // q (3-pass) and fused K|V (2-pass; output is bf16-packed anyway)
  gemm_k<64, 2, 0><<<dim3(128, 4), 256, 0, stream>>>(hsph, hspl, WqTh, WqTl, bq, qb, NT, 256, 256);
  gemm_k<128, 1, 2><<<dim3(128, 4), 256, 0, stream>>>(embh, nullptr, kvWh, kvWl, nullptr, EKV, NT, 512, 256);

  // gather + online-softmax attention (linear token mapping)
  attn_k<<<2048, 256, 0, stream>>>(qb, EKV, off, loc, kvc, attnh);

  // out-proj (2-pass: attn is bf16-rounded anyway), LN1, MLP, LN2
  gemm_k<64, 1, 0><<<dim3(128, 4), 256, 0, stream>>>(attnh, nullptr, WoTh, WoTl, bo, aout, NT, 256, 256);
  ln_k<0, 1><<<2048, 256, 0, stream>>>(hs, nullptr, aout, ln1s, ln1b, xbh, xbl);
  gemm_k<128, 1, 1><<<dim3(128, 8), 256, 0, stream>>>(xbh, nullptr, W1Th, W1Tl, b1, h1, NT, 1024, 256);
  gemm_k<64, 1, 0><<<dim3(128, 4), 256, 0, stream>>>(h1, nullptr, W2Th, W2Tl, b2, mout, NT, 256, 1024);
  ln_k<1, 0><<<2048, 256, 0, stream>>>(xbh, xbl, mout, ln2s, ln2b, d_out, nullptr);
}

// Round 10
// 270.682 us; speedup vs baseline: 1.4768x; 1.0115x over previous
//
#include <hip/hip_runtime.h>

// Problem dims
#define NT 8192      // N*H*W tokens
#define DM 256
#define HH 64
#define WW 64

typedef unsigned short u16;
typedef __attribute__((ext_vector_type(8))) short short8;  // 8 x bf16 mfma frag
typedef __attribute__((ext_vector_type(4))) float f4;

__device__ __forceinline__ float bf2f(u16 u){
  union { unsigned int i; float f; } v; v.i = ((unsigned int)u) << 16; return v.f;
}
__device__ __forceinline__ u16 f2bf(float f){
  union { float f; unsigned int i; } v; v.f = f;
  unsigned int r = (v.i + 0x7fffu + ((v.i >> 16) & 1u)) >> 16;
  return (u16)r;
}
// async global->LDS 16B (direct DMA, no VGPR round trip)
__device__ __forceinline__ void gld16(const void* g, void* l){
  __builtin_amdgcn_global_load_lds(
      (const __attribute__((address_space(1))) unsigned int*)g,
      (__attribute__((address_space(3))) unsigned int*)l, 16, 0, 0);
}

// ---------------------------------------------------------------------------
// fp32 -> single bf16 plane
// ---------------------------------------------------------------------------
__global__ __launch_bounds__(256) void cvt_k(const float* __restrict__ src,
                                             u16* __restrict__ dst){
  int i = blockIdx.x * 256 + threadIdx.x;
  f4 v = ((const f4*)src)[i];
  ushort4 o;
  o.x = f2bf(v.x); o.y = f2bf(v.y); o.z = f2bf(v.z); o.w = f2bf(v.w);
  ((ushort4*)dst)[i] = o;
}

// ---------------------------------------------------------------------------
// Batched transpose of four fp32 [256,256] -> bf16 hi/lo planes [z][256,256]^T
// ---------------------------------------------------------------------------
__global__ __launch_bounds__(256) void transposeB_k(const float* __restrict__ s0,
                                                    const float* __restrict__ s1,
                                                    const float* __restrict__ s2,
                                                    const float* __restrict__ s3,
                                                    u16* __restrict__ dh,
                                                    u16* __restrict__ dl){
  const float* src = blockIdx.z == 0 ? s0 : blockIdx.z == 1 ? s1
                   : blockIdx.z == 2 ? s2 : s3;
  u16* dhp = dh + (size_t)blockIdx.z * 65536;
  u16* dlp = dl + (size_t)blockIdx.z * 65536;
  __shared__ float t[32][33];
  int tx = threadIdx.x & 31, ty = threadIdx.x >> 5;
  int c0 = blockIdx.x * 32, r0 = blockIdx.y * 32;
  for (int i = ty; i < 32; i += 8) t[i][tx] = src[(r0 + i) * 256 + c0 + tx];
  __syncthreads();
  for (int i = ty; i < 32; i += 8){
    float x = t[tx][i];
    u16 h = f2bf(x);
    int idx = (c0 + i) * 256 + r0 + tx;
    dhp[idx] = h;
    dlp[idx] = f2bf(x - bf2f(h));
  }
}

// ---------------------------------------------------------------------------
// Transpose fp32 [R,C] -> bf16 hi/lo planes [C,R]  (W1 / W2)
// ---------------------------------------------------------------------------
__global__ __launch_bounds__(256) void transpose3_k(const float* __restrict__ src,
                                                    u16* __restrict__ dh,
                                                    u16* __restrict__ dl,
                                                    int R, int C){
  __shared__ float t[32][33];
  int tx = threadIdx.x & 31, ty = threadIdx.x >> 5;
  int c0 = blockIdx.x * 32, r0 = blockIdx.y * 32;
  for (int i = ty; i < 32; i += 8) t[i][tx] = src[(size_t)(r0 + i) * C + c0 + tx];
  __syncthreads();
  for (int i = ty; i < 32; i += 8){
    float x = t[tx][i];
    u16 h = f2bf(x);
    size_t idx = (size_t)(c0 + i) * R + r0 + tx;
    dh[idx] = h;
    dl[idx] = f2bf(x - bf2f(h));
  }
}

// ---------------------------------------------------------------------------
// Fold W_kvp/b_kvp through Wk (block 0) and Wv (block 1) -> kvc[1536]
// ---------------------------------------------------------------------------
__global__ __launch_bounds__(256) void prepkv_k(const float* __restrict__ Wkvp,
                                                const float* __restrict__ bkvp,
                                                const float* __restrict__ Wk,
                                                const float* __restrict__ bk,
                                                const float* __restrict__ Wv,
                                                const float* __restrict__ bv,
                                                float* __restrict__ outc){
  const float* Wx = blockIdx.x == 0 ? Wk : Wv;
  const float* bx = blockIdx.x == 0 ? bk : bv;
  float* o = outc + blockIdx.x * 768;
  int e = threadIdx.x;
  float a0 = 0.f, a1 = 0.f, ab = 0.f;
  for (int d = 0; d < 256; d++){
    float w = Wx[d * 256 + e];
    a0 += Wkvp[d] * w;
    a1 += Wkvp[256 + d] * w;
    ab += bkvp[d] * w;
  }
  o[e] = a0; o[256 + e] = a1; o[512 + e] = ab + bx[e];
}

// ---------------------------------------------------------------------------
// Offsets: off = 60*sigmoid(hs @ W_off + b_off) - 30 ; loc = clip(ref+off,0,63)
// ---------------------------------------------------------------------------
__global__ __launch_bounds__(256) void offsets_k(const float* __restrict__ hs,
                                                 const float* __restrict__ Woff,
                                                 const float* __restrict__ boff,
                                                 float* __restrict__ off,
                                                 float* __restrict__ loc){
  __shared__ float hsl[8][256];
  __shared__ float wl[256 * 32];
  const int tid = threadIdx.x;
  const int t0 = blockIdx.x * 8;
  for (int i = tid; i < 8192; i += 256) wl[i] = Woff[i];
  for (int i = tid; i < 2048; i += 256) hsl[i >> 8][i & 255] = hs[(size_t)t0 * 256 + i];
  __syncthreads();
  const int g = tid >> 5, o = tid & 31;
  float acc = 0.f;
  #pragma unroll 8
  for (int d = 0; d < 256; d++) acc += hsl[g][d] * wl[d * 32 + o];
  acc += boff[o];
  float sg = 1.f / (1.f + expf(-acc));
  float of = 60.f * sg - 30.f;
  int tok = t0 + g;
  int hh = (tok >> 6) & 63, ww = tok & 63;
  float base = (o & 1) ? (float)ww : (float)hh;
  float l = fminf(fmaxf(base + of, 0.f), 63.f);
  off[tok * 32 + o] = of;
  loc[tok * 32 + o] = l;
}

// ---------------------------------------------------------------------------
// Split-precision MFMA GEMM. BM=64, BK=64, BN in {64,128}. 4 waves, each a
// 32x(BN/2) subtile of 16x16x32 mfmas. global_load_lds 16B staging.
// APREC 2: A hi/lo planes -> Al*Bh + Ah*Bl + Ah*Bh  (~2^-17 rel)
// APREC 1: A single bf16 plane -> Ah*Bl + Ah*Bh     (~2^-9 A-side residual;
//          fine when A was already bf16-rounded or output is)
// EPI 0: fp32 +bias -> C0.   EPI 1: gelu(tanh) -> bf16 plane C0.
// EPI 2: bf16 packed-KV layout (row*512 + (d>>2)*8 + part*4 + (d&3)) -> C0.
// ---------------------------------------------------------------------------
template<int BN, int APREC, int EPI>
__global__ __launch_bounds__(256) void gemm_k(const u16* __restrict__ Agh,
                                              const u16* __restrict__ Agl,
                                              const u16* __restrict__ Bgh,
                                              const u16* __restrict__ Bgl,
                                              const float* __restrict__ bias,
                                              void* __restrict__ C0,
                                              int M, int N, int K){
  constexpr int NF = BN / 32;                  // n-frags per wave (2 or 4)
  __shared__ __align__(16) u16 Ah[8][64][8];
  __shared__ __align__(16) u16 Al[APREC == 2 ? 8 : 1][64][8];
  __shared__ __align__(16) u16 Bh[8][BN][8];
  __shared__ __align__(16) u16 Bl[8][BN][8];
  const int m0 = blockIdx.x << 6, n0 = blockIdx.y * BN;
  const int tid = threadIdx.x;
  const int lane = tid & 63, wave = tid >> 6;
  const int quad = lane >> 4, l15 = lane & 15;
  const int wm = (wave >> 1) << 5;
  const int wn = (wave & 1) * (BN >> 1);
  // A staging: 64 rows x 8 k-quads = 512 slots of 16B; thread t -> slots t, t+256
  const int ar = tid & 63, aq = tid >> 6;       // slot t: quad aq in 0..3; slot t+256: aq+4
  const u16* gAh = Agh + (size_t)(m0 + ar) * K + aq * 8;
  const u16* gAl = (APREC == 2) ? (Agl + (size_t)(m0 + ar) * K + aq * 8) : nullptr;
  // B staging: BN rows x 8 quads. BN=64: same scheme as A. BN=128: 4 slots/thread.
  const int br = (BN == 128) ? (tid & 127) : (tid & 63);
  const int bq = (BN == 128) ? (tid >> 7) : (tid >> 6);
  const u16* gBh = Bgh + (size_t)(n0 + br) * K + bq * 8;
  const u16* gBl = Bgl + (size_t)(n0 + br) * K + bq * 8;
  f4 acc[2][NF] = {};
  for (int k0 = 0; k0 < K; k0 += 64){
    __syncthreads();
    gld16(gAh + k0,      &Ah[aq][ar][0]);
    gld16(gAh + k0 + 32, &Ah[aq + 4][ar][0]);
    if (APREC == 2){
      gld16(gAl + k0,      &Al[aq][ar][0]);
      gld16(gAl + k0 + 32, &Al[aq + 4][ar][0]);
    }
    if (BN == 128){
      gld16(gBh + k0,      &Bh[bq][br][0]);
      gld16(gBh + k0 + 16, &Bh[bq + 2][br][0]);
      gld16(gBh + k0 + 32, &Bh[bq + 4][br][0]);
      gld16(gBh + k0 + 48, &Bh[bq + 6][br][0]);
      gld16(gBl + k0,      &Bl[bq][br][0]);
      gld16(gBl + k0 + 16, &Bl[bq + 2][br][0]);
      gld16(gBl + k0 + 32, &Bl[bq + 4][br][0]);
      gld16(gBl + k0 + 48, &Bl[bq + 6][br][0]);
    } else {
      gld16(gBh + k0,      &Bh[bq][br][0]);
      gld16(gBh + k0 + 32, &Bh[bq + 4][br][0]);
      gld16(gBl + k0,      &Bl[bq][br][0]);
      gld16(gBl + k0 + 32, &Bl[bq + 4][br][0]);
    }
    asm volatile("s_waitcnt vmcnt(0)" ::: "memory");
    __syncthreads();
    #pragma unroll
    for (int kh = 0; kh < 2; kh++){
      const int q = kh * 4 + quad;
      short8 ahf[2], alf[2], bhf[NF], blf[NF];
      #pragma unroll
      for (int i = 0; i < 2; i++){
        ahf[i] = *(const short8*)(&Ah[q][wm + i * 16 + l15][0]);
        if (APREC == 2) alf[i] = *(const short8*)(&Al[q][wm + i * 16 + l15][0]);
      }
      #pragma unroll
      for (int i = 0; i < NF; i++){
        bhf[i] = *(const short8*)(&Bh[q][wn + i * 16 + l15][0]);
        blf[i] = *(const short8*)(&Bl[q][wn + i * 16 + l15][0]);
      }
      #pragma unroll
      for (int mi = 0; mi < 2; mi++)
      #pragma unroll
      for (int ni = 0; ni < NF; ni++){
        if (APREC == 2)
          acc[mi][ni] = __builtin_amdgcn_mfma_f32_16x16x32_bf16(alf[mi], bhf[ni], acc[mi][ni], 0, 0, 0);
        acc[mi][ni] = __builtin_amdgcn_mfma_f32_16x16x32_bf16(ahf[mi], blf[ni], acc[mi][ni], 0, 0, 0);
        acc[mi][ni] = __builtin_amdgcn_mfma_f32_16x16x32_bf16(ahf[mi], bhf[ni], acc[mi][ni], 0, 0, 0);
      }
    }
  }
  #pragma unroll
  for (int mi = 0; mi < 2; mi++)
  #pragma unroll
  for (int ni = 0; ni < NF; ni++){
    int col = n0 + wn + ni * 16 + l15;
    float bval = bias ? bias[col] : 0.f;
    int rowb = m0 + wm + mi * 16 + quad * 4;
    #pragma unroll
    for (int rg = 0; rg < 4; rg++){
      float v = acc[mi][ni][rg] + bval;
      int row = rowb + rg;
      if (EPI == 0){
        ((float*)C0)[(size_t)row * N + col] = v;
      } else if (EPI == 1){
        float t = v + 0.044715f * v * v * v;
        float g = 0.5f * v * (1.f + tanhf(0.7978845608f * t));
        ((u16*)C0)[(size_t)row * N + col] = f2bf(g);
      } else {   // packed KV bf16: part 0 = K dims, part 1 = V dims
        int part = col >> 8, d = col & 255;
        int pc = ((d >> 2) << 3) + (part << 2) + (d & 3);
        ((u16*)C0)[(size_t)row * 512 + pc] = f2bf(v);
      }
    }
  }
}

// ---------------------------------------------------------------------------
// Dedicated W1 GEMM: 128x128 tile, BK=64, A single bf16 plane (2-pass),
// gelu -> bf16. 4 waves, each a 64x64 subtile: 32 MFMA : 12 ds_read per
// K-half. LDS 48 KB. grid (M/128, N/128) = 512 blocks (2/CU).
// ---------------------------------------------------------------------------
__global__ __launch_bounds__(256) void gemm128_k(const u16* __restrict__ Agh,
                                                 const u16* __restrict__ Bgh,
                                                 const u16* __restrict__ Bgl,
                                                 const float* __restrict__ bias,
                                                 u16* __restrict__ C0,
                                                 int M, int N, int K){
  __shared__ __align__(16) u16 Ah[8][128][8];
  __shared__ __align__(16) u16 Bh[8][128][8];
  __shared__ __align__(16) u16 Bl[8][128][8];
  const int m0 = blockIdx.x << 7, n0 = blockIdx.y << 7;
  const int tid = threadIdx.x;
  const int lane = tid & 63, wave = tid >> 6;
  const int quad = lane >> 4, l15 = lane & 15;
  const int wm = (wave >> 1) << 6, wn = (wave & 1) << 6;
  // staging: 128 rows x 8 quads = 1024 slots/plane; thread -> 4 slots/plane
  const int ar = tid & 127, q0 = tid >> 7;   // q0 in {0,1}; slots q0+2j
  const u16* gA  = Agh + (size_t)(m0 + ar) * K + q0 * 8;
  const u16* gBhp = Bgh + (size_t)(n0 + ar) * K + q0 * 8;
  const u16* gBlp = Bgl + (size_t)(n0 + ar) * K + q0 * 8;
  f4 acc[4][4] = {};
  for (int k0 = 0; k0 < K; k0 += 64){
    __syncthreads();
    #pragma unroll
    for (int j = 0; j < 4; j++){
      gld16(gA   + k0 + j * 16, &Ah[q0 + 2 * j][ar][0]);
      gld16(gBhp + k0 + j * 16, &Bh[q0 + 2 * j][ar][0]);
      gld16(gBlp + k0 + j * 16, &Bl[q0 + 2 * j][ar][0]);
    }
    asm volatile("s_waitcnt vmcnt(0)" ::: "memory");
    __syncthreads();
    #pragma unroll
    for (int kh = 0; kh < 2; kh++){
      const int q = kh * 4 + quad;
      short8 af[4], bh8[4], bl8[4];
      #pragma unroll
      for (int i = 0; i < 4; i++){
        af[i]  = *(const short8*)(&Ah[q][wm + i * 16 + l15][0]);
        bh8[i] = *(const short8*)(&Bh[q][wn + i * 16 + l15][0]);
        bl8[i] = *(const short8*)(&Bl[q][wn + i * 16 + l15][0]);
      }
      #pragma unroll
      for (int mi = 0; mi < 4; mi++)
      #pragma unroll
      for (int ni = 0; ni < 4; ni++){
        acc[mi][ni] = __builtin_amdgcn_mfma_f32_16x16x32_bf16(af[mi], bl8[ni], acc[mi][ni], 0, 0, 0);
        acc[mi][ni] = __builtin_amdgcn_mfma_f32_16x16x32_bf16(af[mi], bh8[ni], acc[mi][ni], 0, 0, 0);
      }
    }
  }
  #pragma unroll
  for (int mi = 0; mi < 4; mi++)
  #pragma unroll
  for (int ni = 0; ni < 4; ni++){
    int col = n0 + wn + ni * 16 + l15;
    float bval = bias[col];
    int rowb = m0 + wm + mi * 16 + quad * 4;
    #pragma unroll
    for (int rg = 0; rg < 4; rg++){
      float v = acc[mi][ni][rg] + bval;
      float t = v + 0.044715f * v * v * v;
      float g = 0.5f * v * (1.f + tanhf(0.7978845608f * t));
      C0[(size_t)(rowb + rg) * N + col] = f2bf(g);
    }
  }
}

// ---------------------------------------------------------------------------
// Attention, single pass (online softmax). One wave per token; lane owns dims
// [4*lane,4*lane+4). EKV packed bf16: one 16B load per corner = k4|v4.
// Output: bf16 hi plane only (O-proj runs 2-pass on it).
// ---------------------------------------------------------------------------
__device__ __forceinline__ void unpack8(int4 p, f4& k4, f4& v4){
  k4.x = bf2f((u16)(p.x & 0xffff)); k4.y = bf2f((u16)((unsigned)p.x >> 16));
  k4.z = bf2f((u16)(p.y & 0xffff)); k4.w = bf2f((u16)((unsigned)p.y >> 16));
  v4.x = bf2f((u16)(p.z & 0xffff)); v4.y = bf2f((u16)((unsigned)p.z >> 16));
  v4.z = bf2f((u16)(p.w & 0xffff)); v4.w = bf2f((u16)((unsigned)p.w >> 16));
}

__global__ __launch_bounds__(256) void attn_k(const float* __restrict__ q,
                                              const u16* __restrict__ EKV,
                                              const float* __restrict__ offb,
                                              const float* __restrict__ locb,
                                              const float* __restrict__ kvc,
                                              u16* __restrict__ ah){
  const int tid = threadIdx.x;
  const int wave = tid >> 6, lane = tid & 63;
  const int tok = blockIdx.x * 4 + wave;
  const int base = (tok >> 12) << 12;   // n*4096
  const int4* E = (const int4*)EKV;     // 16B per (row,lane)
  const f4* kvc4 = (const f4*)kvc;
  f4 qv  = *((const f4*)q + (size_t)tok * 64 + lane);
  f4 wk0 = kvc4[lane], wk1 = kvc4[64 + lane], bkv = kvc4[128 + lane];
  f4 wv0 = kvc4[192 + lane], wv1 = kvc4[256 + lane], bvv = kvc4[320 + lane];
  float m = -1e30f, l = 0.f;
  f4 acc = {0.f, 0.f, 0.f, 0.f};
  #pragma unroll
  for (int s = 0; s < 16; s++){
    float y = locb[tok * 32 + s * 2], x = locb[tok * 32 + s * 2 + 1];
    float o0 = offb[tok * 32 + s * 2], o1 = offb[tok * 32 + s * 2 + 1];
    float yf = floorf(y), xf = floorf(x);
    int y0 = (int)yf, x0 = (int)xf;
    int y1 = min(y0 + 1, 63), x1 = min(x0 + 1, 63);
    float wy = y - yf, wx = x - xf;
    int4 p00 = E[(size_t)(base + y0 * 64 + x0) * 64 + lane];
    int4 p01 = E[(size_t)(base + y0 * 64 + x1) * 64 + lane];
    int4 p10 = E[(size_t)(base + y1 * 64 + x0) * 64 + lane];
    int4 p11 = E[(size_t)(base + y1 * 64 + x1) * 64 + lane];
    f4 k00, v00, k01, v01, k10, v10, k11, v11;
    unpack8(p00, k00, v00); unpack8(p01, k01, v01);
    unpack8(p10, k10, v10); unpack8(p11, k11, v11);
    float w00 = (1.f - wy) * (1.f - wx), w01 = (1.f - wy) * wx;
    float w10 = wy * (1.f - wx), w11 = wy * wx;
    f4 kk = w00 * k00 + w01 * k01 + w10 * k10 + w11 * k11;
    f4 vv = w00 * v00 + w01 * v01 + w10 * v10 + w11 * v11;
    kk += o0 * wk0 + o1 * wk1 + bkv;
    vv += o0 * wv0 + o1 * wv1 + bvv;
    float p = qv.x * kk.x + qv.y * kk.y + qv.z * kk.z + qv.w * kk.w;
    p += __shfl_xor(p, 1); p += __shfl_xor(p, 2);
    p += __shfl_xor(p, 4); p += __shfl_xor(p, 8);
    p *= 0.125f;   // /sqrt(64)
    float mn = fmaxf(m, p);
    float cor = __expf(m - mn);
    float wgt = __expf(p - mn);
    l = l * cor + wgt;
    acc = acc * cor + wgt * vv;
    m = mn;
  }
  float inv = 1.f / l;
  f4 o = acc * inv;
  ushort4 h;
  h.x = f2bf(o.x); h.y = f2bf(o.y); h.z = f2bf(o.z); h.w = f2bf(o.w);
  *(ushort4*)(ah + (size_t)tok * 256 + lane * 4) = h;
}

// ---------------------------------------------------------------------------
// LayerNorm(a + b) * scale + bias. One wave per token.
// INP: 0 -> a0 fp32; 1 -> a0/a1 hi/lo planes.  OUTP: 0 -> fp32; 1 -> planes.
// ---------------------------------------------------------------------------
template<int INP, int OUTP>
__global__ __launch_bounds__(256) void ln_k(const void* __restrict__ a0,
                                            const void* __restrict__ a1,
                                            const float* __restrict__ b,
                                            const float* __restrict__ sc,
                                            const float* __restrict__ bi,
                                            void* __restrict__ o0,
                                            void* __restrict__ o1){
  const int tid = threadIdx.x;
  const int wave = tid >> 6, lane = tid & 63;
  const int tok = blockIdx.x * 4 + wave;
  float x0, x1, x2, x3;
  if (INP){
    ushort4 h = ((const ushort4*)a0)[(size_t)tok * 64 + lane];
    ushort4 lo = ((const ushort4*)a1)[(size_t)tok * 64 + lane];
    x0 = bf2f(h.x) + bf2f(lo.x); x1 = bf2f(h.y) + bf2f(lo.y);
    x2 = bf2f(h.z) + bf2f(lo.z); x3 = bf2f(h.w) + bf2f(lo.w);
  } else {
    f4 av = ((const f4*)a0)[(size_t)tok * 64 + lane];
    x0 = av.x; x1 = av.y; x2 = av.z; x3 = av.w;
  }
  f4 bv = ((const f4*)b)[(size_t)tok * 64 + lane];
  x0 += bv.x; x1 += bv.y; x2 += bv.z; x3 += bv.w;
  float sm = x0 + x1 + x2 + x3;
  float sq = x0 * x0 + x1 * x1 + x2 * x2 + x3 * x3;
  #pragma unroll
  for (int mm = 1; mm < 64; mm <<= 1){ sm += __shfl_xor(sm, mm); sq += __shfl_xor(sq, mm); }
  float mean = sm * (1.f / 256.f);
  float var = sq * (1.f / 256.f) - mean * mean;
  float rs = rsqrtf(var + 1e-6f);
  f4 sv = ((const f4*)sc)[lane];
  f4 bb = ((const f4*)bi)[lane];
  float y0 = (x0 - mean) * rs * sv.x + bb.x;
  float y1 = (x1 - mean) * rs * sv.y + bb.y;
  float y2 = (x2 - mean) * rs * sv.z + bb.z;
  float y3 = (x3 - mean) * rs * sv.w + bb.w;
  if (OUTP){
    ushort4 h, lo;
    h.x = f2bf(y0); lo.x = f2bf(y0 - bf2f(h.x));
    h.y = f2bf(y1); lo.y = f2bf(y1 - bf2f(h.y));
    h.z = f2bf(y2); lo.z = f2bf(y2 - bf2f(h.z));
    h.w = f2bf(y3); lo.w = f2bf(y3 - bf2f(h.w));
    ((ushort4*)o0)[(size_t)tok * 64 + lane] = h;
    ((ushort4*)o1)[(size_t)tok * 64 + lane] = lo;
  } else {
    f4 ov = {y0, y1, y2, y3};
    ((f4*)o0)[(size_t)tok * 64 + lane] = ov;
  }
}

// ---------------------------------------------------------------------------
extern "C" void kernel_launch(void* const* d_in, const int* in_sizes, int n_in,
                              void* d_out, int out_size, void* d_ws, size_t ws_size,
                              hipStream_t stream){
  const float* hs   = (const float*)d_in[0];
  const float* emb  = (const float*)d_in[1];
  const float* Woff = (const float*)d_in[2];
  const float* boff = (const float*)d_in[3];
  const float* Wkvp = (const float*)d_in[4];
  const float* bkvp = (const float*)d_in[5];
  const float* Wq   = (const float*)d_in[6];
  const float* bq   = (const float*)d_in[7];
  const float* Wk   = (const float*)d_in[8];
  const float* bk   = (const float*)d_in[9];
  const float* Wv   = (const float*)d_in[10];
  const float* bv   = (const float*)d_in[11];
  const float* Wo   = (const float*)d_in[12];
  const float* bo   = (const float*)d_in[13];
  const float* ln1s = (const float*)d_in[14];
  const float* ln1b = (const float*)d_in[15];
  const float* ln2s = (const float*)d_in[16];
  const float* ln2b = (const float*)d_in[17];
  const float* W1   = (const float*)d_in[18];
  const float* b1   = (const float*)d_in[19];
  const float* W2   = (const float*)d_in[20];
  const float* b2   = (const float*)d_in[21];

  char* w = (char*)d_ws;
  auto alloc = [&](size_t bytes){ char* p = w; w += (bytes + 255) & ~(size_t)255; return p; };
  // weight planes: [WqT | WkT | WvT | WoT] contiguous hi and lo
  u16* qkvoTh = (u16*)alloc(4 * 65536 * 2);
  u16* qkvoTl = (u16*)alloc(4 * 65536 * 2);
  u16* WqTh = qkvoTh;              u16* WqTl = qkvoTl;
  u16* kvWh = qkvoTh + 65536;      u16* kvWl = qkvoTl + 65536;   // [512,256]
  u16* WoTh = qkvoTh + 3 * 65536;  u16* WoTl = qkvoTl + 3 * 65536;
  u16* W1Th = (u16*)alloc(262144 * 2); u16* W1Tl = (u16*)alloc(262144 * 2);
  u16* W2Th = (u16*)alloc(262144 * 2); u16* W2Tl = (u16*)alloc(262144 * 2);
  float* kvc = (float*)alloc(1536 * 4);
  // slot1 (8.4 MB): hs hi plane / attn hi plane / xb planes
  char* slot1 = alloc((size_t)NT * 256 * 4);
  u16* hsph = (u16*)slot1;          u16* hspl = hsph + (size_t)NT * 256;
  u16* attnh = hsph;
  u16* xbh = hsph;                  u16* xbl = hspl;
  // slot2 (8.4 MB): emb bf16 plane / aout fp32
  char* slot2 = alloc((size_t)NT * 256 * 4);
  u16* embh = (u16*)slot2;
  float* aout = (float*)slot2;
  // slot3 (8.4 MB): off+loc / mout fp32
  char* slot3 = alloc((size_t)NT * 256 * 4);
  float* off = (float*)slot3;       float* loc = off + (size_t)NT * 32;
  float* mout = (float*)slot3;
  // slot4 (16.8 MB): qb fp32 + EKV bf16 / h1 bf16 [NT,1024] (16 MB)
  char* slot4 = alloc((size_t)NT * 256 * 8);
  float* qb = (float*)slot4;
  u16* EKV = (u16*)(slot4 + (size_t)NT * 256 * 4);   // [NT,512] packed bf16
  u16* h1 = (u16*)slot4;                             // [NT,1024] bf16 plane
  if ((size_t)(w - (char*)d_ws) > ws_size) return;

  // prep
  cvt_k<<<2048, 256, 0, stream>>>(hs, hsph);
  cvt_k<<<2048, 256, 0, stream>>>(emb, embh);
  transposeB_k<<<dim3(8, 8, 4), 256, 0, stream>>>(Wq, Wk, Wv, Wo, qkvoTh, qkvoTl);
  transpose3_k<<<dim3(32, 8), 256, 0, stream>>>(W1, W1Th, W1Tl, 256, 1024);
  transpose3_k<<<dim3(8, 32), 256, 0, stream>>>(W2, W2Th, W2Tl, 1024, 256);
  prepkv_k<<<2, 256, 0, stream>>>(Wkvp, bkvp, Wk, bk, Wv, bv, kvc);
  offsets_k<<<1024, 256, 0, stream>>>(hs, Woff, boff, off, loc);

  // q (2-pass: residual hs_lo*Wq ~1e-3, subdominant) and fused K|V (2-pass)
  gemm_k<64, 1, 0><<<dim3(128, 4), 256, 0, stream>>>(hsph, nullptr, WqTh, WqTl, bq, qb, NT, 256, 256);
  gemm_k<128, 1, 2><<<dim3(128, 4), 256, 0, stream>>>(embh, nullptr, kvWh, kvWl, nullptr, EKV, NT, 512, 256);

  // gather + online-softmax attention (linear token mapping)
  attn_k<<<2048, 256, 0, stream>>>(qb, EKV, off, loc, kvc, attnh);

  // out-proj (2-pass), LN1, MLP (W1 via 128x128 tile), LN2
  gemm_k<64, 1, 0><<<dim3(128, 4), 256, 0, stream>>>(attnh, nullptr, WoTh, WoTl, bo, aout, NT, 256, 256);
  ln_k<0, 1><<<2048, 256, 0, stream>>>(hs, nullptr, aout, ln1s, ln1b, xbh, xbl);
  gemm128_k<<<dim3(64, 8), 256, 0, stream>>>(xbh, W1Th, W1Tl, b1, h1, NT, 1024, 256);
  gemm_k<64, 1, 0><<<dim3(128, 4), 256, 0, stream>>>(h1, nullptr, W2Th, W2Tl, b2, mout, NT, 256, 1024);
  ln_k<1, 0><<<2048, 256, 0, stream>>>(xbh, xbl, mout, ln2s, ln2b, d_out, nullptr);
}

// Round 11
// 269.015 us; speedup vs baseline: 1.4859x; 1.0062x over previous
//
#include <hip/hip_runtime.h>

// Problem dims
#define NT 8192      // N*H*W tokens
#define DM 256
#define HH 64
#define WW 64

typedef unsigned short u16;
typedef __attribute__((ext_vector_type(8))) short short8;  // 8 x bf16 mfma frag
typedef __attribute__((ext_vector_type(4))) float f4;

__device__ __forceinline__ float bf2f(u16 u){
  union { unsigned int i; float f; } v; v.i = ((unsigned int)u) << 16; return v.f;
}
__device__ __forceinline__ u16 f2bf(float f){
  union { float f; unsigned int i; } v; v.f = f;
  unsigned int r = (v.i + 0x7fffu + ((v.i >> 16) & 1u)) >> 16;
  return (u16)r;
}
// async global->LDS 16B (direct DMA, no VGPR round trip)
__device__ __forceinline__ void gld16(const void* g, void* l){
  __builtin_amdgcn_global_load_lds(
      (const __attribute__((address_space(1))) unsigned int*)g,
      (__attribute__((address_space(3))) unsigned int*)l, 16, 0, 0);
}

// ---------------------------------------------------------------------------
// prep: blocks 0..2047 -> hs fp32 -> hi/lo planes; 2048..4095 -> emb -> hi.
// ---------------------------------------------------------------------------
__global__ __launch_bounds__(256) void prep_k(const float* __restrict__ hs,
                                              const float* __restrict__ emb,
                                              u16* __restrict__ hsph,
                                              u16* __restrict__ hspl,
                                              u16* __restrict__ embh){
  int b = blockIdx.x;
  if (b < 2048){
    int i = b * 256 + threadIdx.x;
    f4 v = ((const f4*)hs)[i];
    ushort4 h, l;
    h.x = f2bf(v.x); l.x = f2bf(v.x - bf2f(h.x));
    h.y = f2bf(v.y); l.y = f2bf(v.y - bf2f(h.y));
    h.z = f2bf(v.z); l.z = f2bf(v.z - bf2f(h.z));
    h.w = f2bf(v.w); l.w = f2bf(v.w - bf2f(h.w));
    ((ushort4*)hsph)[i] = h;
    ((ushort4*)hspl)[i] = l;
  } else {
    int i = (b - 2048) * 256 + threadIdx.x;
    f4 v = ((const f4*)emb)[i];
    ushort4 o;
    o.x = f2bf(v.x); o.y = f2bf(v.y); o.z = f2bf(v.z); o.w = f2bf(v.w);
    ((ushort4*)embh)[i] = o;
  }
}

// ---------------------------------------------------------------------------
// Batched transpose of four fp32 [256,256] -> bf16 hi/lo planes [z][256,256]^T
// ---------------------------------------------------------------------------
__global__ __launch_bounds__(256) void transposeB_k(const float* __restrict__ s0,
                                                    const float* __restrict__ s1,
                                                    const float* __restrict__ s2,
                                                    const float* __restrict__ s3,
                                                    u16* __restrict__ dh,
                                                    u16* __restrict__ dl){
  const float* src = blockIdx.z == 0 ? s0 : blockIdx.z == 1 ? s1
                   : blockIdx.z == 2 ? s2 : s3;
  u16* dhp = dh + (size_t)blockIdx.z * 65536;
  u16* dlp = dl + (size_t)blockIdx.z * 65536;
  __shared__ float t[32][33];
  int tx = threadIdx.x & 31, ty = threadIdx.x >> 5;
  int c0 = blockIdx.x * 32, r0 = blockIdx.y * 32;
  for (int i = ty; i < 32; i += 8) t[i][tx] = src[(r0 + i) * 256 + c0 + tx];
  __syncthreads();
  for (int i = ty; i < 32; i += 8){
    float x = t[tx][i];
    u16 h = f2bf(x);
    int idx = (c0 + i) * 256 + r0 + tx;
    dhp[idx] = h;
    dlp[idx] = f2bf(x - bf2f(h));
  }
}

// ---------------------------------------------------------------------------
// Transpose fp32 [R,C] -> bf16 hi/lo planes [C,R]  (W1 / W2)
// ---------------------------------------------------------------------------
__global__ __launch_bounds__(256) void transpose3_k(const float* __restrict__ src,
                                                    u16* __restrict__ dh,
                                                    u16* __restrict__ dl,
                                                    int R, int C){
  __shared__ float t[32][33];
  int tx = threadIdx.x & 31, ty = threadIdx.x >> 5;
  int c0 = blockIdx.x * 32, r0 = blockIdx.y * 32;
  for (int i = ty; i < 32; i += 8) t[i][tx] = src[(size_t)(r0 + i) * C + c0 + tx];
  __syncthreads();
  for (int i = ty; i < 32; i += 8){
    float x = t[tx][i];
    u16 h = f2bf(x);
    size_t idx = (size_t)(c0 + i) * R + r0 + tx;
    dh[idx] = h;
    dl[idx] = f2bf(x - bf2f(h));
  }
}

// ---------------------------------------------------------------------------
// Fold W_kvp/b_kvp through Wk (block 0) and Wv (block 1) -> kvc[1536]
// ---------------------------------------------------------------------------
__global__ __launch_bounds__(256) void prepkv_k(const float* __restrict__ Wkvp,
                                                const float* __restrict__ bkvp,
                                                const float* __restrict__ Wk,
                                                const float* __restrict__ bk,
                                                const float* __restrict__ Wv,
                                                const float* __restrict__ bv,
                                                float* __restrict__ outc){
  const float* Wx = blockIdx.x == 0 ? Wk : Wv;
  const float* bx = blockIdx.x == 0 ? bk : bv;
  float* o = outc + blockIdx.x * 768;
  int e = threadIdx.x;
  float a0 = 0.f, a1 = 0.f, ab = 0.f;
  for (int d = 0; d < 256; d++){
    float w = Wx[d * 256 + e];
    a0 += Wkvp[d] * w;
    a1 += Wkvp[256 + d] * w;
    ab += bkvp[d] * w;
  }
  o[e] = a0; o[256 + e] = a1; o[512 + e] = ab + bx[e];
}

// ---------------------------------------------------------------------------
// Offsets: off = 60*sigmoid(hs @ W_off + b_off) - 30 ; loc = clip(ref+off,0,63)
// ---------------------------------------------------------------------------
__global__ __launch_bounds__(256) void offsets_k(const float* __restrict__ hs,
                                                 const float* __restrict__ Woff,
                                                 const float* __restrict__ boff,
                                                 float* __restrict__ off,
                                                 float* __restrict__ loc){
  __shared__ float hsl[8][256];
  __shared__ float wl[256 * 32];
  const int tid = threadIdx.x;
  const int t0 = blockIdx.x * 8;
  for (int i = tid; i < 8192; i += 256) wl[i] = Woff[i];
  for (int i = tid; i < 2048; i += 256) hsl[i >> 8][i & 255] = hs[(size_t)t0 * 256 + i];
  __syncthreads();
  const int g = tid >> 5, o = tid & 31;
  float acc = 0.f;
  #pragma unroll 8
  for (int d = 0; d < 256; d++) acc += hsl[g][d] * wl[d * 32 + o];
  acc += boff[o];
  float sg = 1.f / (1.f + expf(-acc));
  float of = 60.f * sg - 30.f;
  int tok = t0 + g;
  int hh = (tok >> 6) & 63, ww = tok & 63;
  float base = (o & 1) ? (float)ww : (float)hh;
  float l = fminf(fmaxf(base + of, 0.f), 63.f);
  off[tok * 32 + o] = of;
  loc[tok * 32 + o] = l;
}

// ---------------------------------------------------------------------------
// Grouped q + EKV GEMM, ONE dispatch (1536 blocks), BM=BN=64, BK=64, K=256.
//  blocks 0..511:    q   = hs(hi/lo, 3-pass) x WqT(hi/lo) + bq -> fp32 qb
//  blocks 512..1535: EKV = emb(hi, 2-pass)  x kvWT(hi/lo)      -> packed bf16
// Branches are wave-uniform. Same staging/math as gemm_k (r7-proven).
// ---------------------------------------------------------------------------
__global__ __launch_bounds__(256) void qekv_k(const u16* __restrict__ hsph,
                                              const u16* __restrict__ hspl,
                                              const u16* __restrict__ WqTh,
                                              const u16* __restrict__ WqTl,
                                              const float* __restrict__ bq,
                                              const u16* __restrict__ embh,
                                              const u16* __restrict__ kvWh,
                                              const u16* __restrict__ kvWl,
                                              float* __restrict__ qb,
                                              u16* __restrict__ EKV){
  __shared__ __align__(16) u16 Ah[8][64][8];
  __shared__ __align__(16) u16 Al[8][64][8];
  __shared__ __align__(16) u16 Bh[8][64][8];
  __shared__ __align__(16) u16 Bl[8][64][8];
  const int bid = blockIdx.x;
  const bool isQ = bid < 512;
  const int b2 = isQ ? bid : bid - 512;
  const int m0 = (isQ ? (b2 & 127) : (b2 & 127)) << 6;
  const int n0 = (isQ ? (b2 >> 7) : (b2 >> 7)) << 6;
  const int K = 256;
  const u16* Agh = isQ ? hsph : embh;
  const u16* Bgh = isQ ? WqTh : kvWh;
  const u16* Bgl = isQ ? WqTl : kvWl;
  const int tid = threadIdx.x;
  const int lane = tid & 63, wave = tid >> 6;
  const int quad = lane >> 4, l15 = lane & 15;
  const int wm = (wave >> 1) << 5, wn = (wave & 1) << 5;
  const int ar = tid & 63, aq = tid >> 6;
  const u16* gAh = Agh + (size_t)(m0 + ar) * K + aq * 8;
  const u16* gAl = hspl + (size_t)(m0 + ar) * K + aq * 8;   // only read if isQ
  const u16* gBh = Bgh + (size_t)(n0 + ar) * K + aq * 8;
  const u16* gBl = Bgl + (size_t)(n0 + ar) * K + aq * 8;
  f4 acc[2][2] = {};
  for (int k0 = 0; k0 < K; k0 += 64){
    __syncthreads();
    gld16(gAh + k0,      &Ah[aq][ar][0]);
    gld16(gAh + k0 + 32, &Ah[aq + 4][ar][0]);
    if (isQ){
      gld16(gAl + k0,      &Al[aq][ar][0]);
      gld16(gAl + k0 + 32, &Al[aq + 4][ar][0]);
    }
    gld16(gBh + k0,      &Bh[aq][ar][0]);
    gld16(gBh + k0 + 32, &Bh[aq + 4][ar][0]);
    gld16(gBl + k0,      &Bl[aq][ar][0]);
    gld16(gBl + k0 + 32, &Bl[aq + 4][ar][0]);
    asm volatile("s_waitcnt vmcnt(0)" ::: "memory");
    __syncthreads();
    #pragma unroll
    for (int kh = 0; kh < 2; kh++){
      const int q = kh * 4 + quad;
      short8 ahf[2], alf[2], bhf[2], blf[2];
      #pragma unroll
      for (int i = 0; i < 2; i++){
        ahf[i] = *(const short8*)(&Ah[q][wm + i * 16 + l15][0]);
        bhf[i] = *(const short8*)(&Bh[q][wn + i * 16 + l15][0]);
        blf[i] = *(const short8*)(&Bl[q][wn + i * 16 + l15][0]);
      }
      if (isQ){
        #pragma unroll
        for (int i = 0; i < 2; i++)
          alf[i] = *(const short8*)(&Al[q][wm + i * 16 + l15][0]);
      }
      #pragma unroll
      for (int mi = 0; mi < 2; mi++)
      #pragma unroll
      for (int ni = 0; ni < 2; ni++){
        if (isQ)
          acc[mi][ni] = __builtin_amdgcn_mfma_f32_16x16x32_bf16(alf[mi], bhf[ni], acc[mi][ni], 0, 0, 0);
        acc[mi][ni] = __builtin_amdgcn_mfma_f32_16x16x32_bf16(ahf[mi], blf[ni], acc[mi][ni], 0, 0, 0);
        acc[mi][ni] = __builtin_amdgcn_mfma_f32_16x16x32_bf16(ahf[mi], bhf[ni], acc[mi][ni], 0, 0, 0);
      }
    }
  }
  #pragma unroll
  for (int mi = 0; mi < 2; mi++)
  #pragma unroll
  for (int ni = 0; ni < 2; ni++){
    int col = n0 + wn + ni * 16 + l15;
    int rowb = m0 + wm + mi * 16 + quad * 4;
    if (isQ){
      float bval = bq[col];
      #pragma unroll
      for (int rg = 0; rg < 4; rg++)
        qb[(size_t)(rowb + rg) * 256 + col] = acc[mi][ni][rg] + bval;
    } else {
      int part = col >> 8, d = col & 255;
      int pc = ((d >> 2) << 3) + (part << 2) + (d & 3);
      #pragma unroll
      for (int rg = 0; rg < 4; rg++)
        EKV[(size_t)(rowb + rg) * 512 + pc] = f2bf(acc[mi][ni][rg]);
    }
  }
}

// ---------------------------------------------------------------------------
// Split-precision MFMA GEMM (r7-proven). BM=64, BK=64, BN=64 used here.
// APREC 1: A single bf16 plane -> Ah*Bl + Ah*Bh.  EPI 0: fp32 +bias.
// ---------------------------------------------------------------------------
template<int BN, int APREC, int EPI>
__global__ __launch_bounds__(256) void gemm_k(const u16* __restrict__ Agh,
                                              const u16* __restrict__ Agl,
                                              const u16* __restrict__ Bgh,
                                              const u16* __restrict__ Bgl,
                                              const float* __restrict__ bias,
                                              void* __restrict__ C0,
                                              int M, int N, int K){
  constexpr int NF = BN / 32;
  __shared__ __align__(16) u16 Ah[8][64][8];
  __shared__ __align__(16) u16 Al[APREC == 2 ? 8 : 1][64][8];
  __shared__ __align__(16) u16 Bh[8][BN][8];
  __shared__ __align__(16) u16 Bl[8][BN][8];
  const int m0 = blockIdx.x << 6, n0 = blockIdx.y * BN;
  const int tid = threadIdx.x;
  const int lane = tid & 63, wave = tid >> 6;
  const int quad = lane >> 4, l15 = lane & 15;
  const int wm = (wave >> 1) << 5;
  const int wn = (wave & 1) * (BN >> 1);
  const int ar = tid & 63, aq = tid >> 6;
  const u16* gAh = Agh + (size_t)(m0 + ar) * K + aq * 8;
  const u16* gAl = (APREC == 2) ? (Agl + (size_t)(m0 + ar) * K + aq * 8) : nullptr;
  const int br = (BN == 128) ? (tid & 127) : (tid & 63);
  const int bq = (BN == 128) ? (tid >> 7) : (tid >> 6);
  const u16* gBh = Bgh + (size_t)(n0 + br) * K + bq * 8;
  const u16* gBl = Bgl + (size_t)(n0 + br) * K + bq * 8;
  f4 acc[2][NF] = {};
  for (int k0 = 0; k0 < K; k0 += 64){
    __syncthreads();
    gld16(gAh + k0,      &Ah[aq][ar][0]);
    gld16(gAh + k0 + 32, &Ah[aq + 4][ar][0]);
    if (APREC == 2){
      gld16(gAl + k0,      &Al[aq][ar][0]);
      gld16(gAl + k0 + 32, &Al[aq + 4][ar][0]);
    }
    if (BN == 128){
      gld16(gBh + k0,      &Bh[bq][br][0]);
      gld16(gBh + k0 + 16, &Bh[bq + 2][br][0]);
      gld16(gBh + k0 + 32, &Bh[bq + 4][br][0]);
      gld16(gBh + k0 + 48, &Bh[bq + 6][br][0]);
      gld16(gBl + k0,      &Bl[bq][br][0]);
      gld16(gBl + k0 + 16, &Bl[bq + 2][br][0]);
      gld16(gBl + k0 + 32, &Bl[bq + 4][br][0]);
      gld16(gBl + k0 + 48, &Bl[bq + 6][br][0]);
    } else {
      gld16(gBh + k0,      &Bh[bq][br][0]);
      gld16(gBh + k0 + 32, &Bh[bq + 4][br][0]);
      gld16(gBl + k0,      &Bl[bq][br][0]);
      gld16(gBl + k0 + 32, &Bl[bq + 4][br][0]);
    }
    asm volatile("s_waitcnt vmcnt(0)" ::: "memory");
    __syncthreads();
    #pragma unroll
    for (int kh = 0; kh < 2; kh++){
      const int q = kh * 4 + quad;
      short8 ahf[2], alf[2], bhf[NF], blf[NF];
      #pragma unroll
      for (int i = 0; i < 2; i++){
        ahf[i] = *(const short8*)(&Ah[q][wm + i * 16 + l15][0]);
        if (APREC == 2) alf[i] = *(const short8*)(&Al[q][wm + i * 16 + l15][0]);
      }
      #pragma unroll
      for (int i = 0; i < NF; i++){
        bhf[i] = *(const short8*)(&Bh[q][wn + i * 16 + l15][0]);
        blf[i] = *(const short8*)(&Bl[q][wn + i * 16 + l15][0]);
      }
      #pragma unroll
      for (int mi = 0; mi < 2; mi++)
      #pragma unroll
      for (int ni = 0; ni < NF; ni++){
        if (APREC == 2)
          acc[mi][ni] = __builtin_amdgcn_mfma_f32_16x16x32_bf16(alf[mi], bhf[ni], acc[mi][ni], 0, 0, 0);
        acc[mi][ni] = __builtin_amdgcn_mfma_f32_16x16x32_bf16(ahf[mi], blf[ni], acc[mi][ni], 0, 0, 0);
        acc[mi][ni] = __builtin_amdgcn_mfma_f32_16x16x32_bf16(ahf[mi], bhf[ni], acc[mi][ni], 0, 0, 0);
      }
    }
  }
  #pragma unroll
  for (int mi = 0; mi < 2; mi++)
  #pragma unroll
  for (int ni = 0; ni < NF; ni++){
    int col = n0 + wn + ni * 16 + l15;
    float bval = bias ? bias[col] : 0.f;
    int rowb = m0 + wm + mi * 16 + quad * 4;
    #pragma unroll
    for (int rg = 0; rg < 4; rg++){
      float v = acc[mi][ni][rg] + bval;
      int row = rowb + rg;
      if (EPI == 0){
        ((float*)C0)[(size_t)row * N + col] = v;
      } else if (EPI == 1){
        float t = v + 0.044715f * v * v * v;
        float g = 0.5f * v * (1.f + tanhf(0.7978845608f * t));
        ((u16*)C0)[(size_t)row * N + col] = f2bf(g);
      } else {
        int part = col >> 8, d = col & 255;
        int pc = ((d >> 2) << 3) + (part << 2) + (d & 3);
        ((u16*)C0)[(size_t)row * 512 + pc] = f2bf(v);
      }
    }
  }
}

// ---------------------------------------------------------------------------
// Dedicated W1 GEMM: 128x128 tile, BK=64, A single bf16 plane (2-pass),
// gelu -> bf16. Proven clean under replay tripwire (r10).
// ---------------------------------------------------------------------------
__global__ __launch_bounds__(256) void gemm128_k(const u16* __restrict__ Agh,
                                                 const u16* __restrict__ Bgh,
                                                 const u16* __restrict__ Bgl,
                                                 const float* __restrict__ bias,
                                                 u16* __restrict__ C0,
                                                 int M, int N, int K){
  __shared__ __align__(16) u16 Ah[8][128][8];
  __shared__ __align__(16) u16 Bh[8][128][8];
  __shared__ __align__(16) u16 Bl[8][128][8];
  const int m0 = blockIdx.x << 7, n0 = blockIdx.y << 7;
  const int tid = threadIdx.x;
  const int lane = tid & 63, wave = tid >> 6;
  const int quad = lane >> 4, l15 = lane & 15;
  const int wm = (wave >> 1) << 6, wn = (wave & 1) << 6;
  const int ar = tid & 127, q0 = tid >> 7;
  const u16* gA  = Agh + (size_t)(m0 + ar) * K + q0 * 8;
  const u16* gBhp = Bgh + (size_t)(n0 + ar) * K + q0 * 8;
  const u16* gBlp = Bgl + (size_t)(n0 + ar) * K + q0 * 8;
  f4 acc[4][4] = {};
  for (int k0 = 0; k0 < K; k0 += 64){
    __syncthreads();
    #pragma unroll
    for (int j = 0; j < 4; j++){
      gld16(gA   + k0 + j * 16, &Ah[q0 + 2 * j][ar][0]);
      gld16(gBhp + k0 + j * 16, &Bh[q0 + 2 * j][ar][0]);
      gld16(gBlp + k0 + j * 16, &Bl[q0 + 2 * j][ar][0]);
    }
    asm volatile("s_waitcnt vmcnt(0)" ::: "memory");
    __syncthreads();
    #pragma unroll
    for (int kh = 0; kh < 2; kh++){
      const int q = kh * 4 + quad;
      short8 af[4], bh8[4], bl8[4];
      #pragma unroll
      for (int i = 0; i < 4; i++){
        af[i]  = *(const short8*)(&Ah[q][wm + i * 16 + l15][0]);
        bh8[i] = *(const short8*)(&Bh[q][wn + i * 16 + l15][0]);
        bl8[i] = *(const short8*)(&Bl[q][wn + i * 16 + l15][0]);
      }
      #pragma unroll
      for (int mi = 0; mi < 4; mi++)
      #pragma unroll
      for (int ni = 0; ni < 4; ni++){
        acc[mi][ni] = __builtin_amdgcn_mfma_f32_16x16x32_bf16(af[mi], bl8[ni], acc[mi][ni], 0, 0, 0);
        acc[mi][ni] = __builtin_amdgcn_mfma_f32_16x16x32_bf16(af[mi], bh8[ni], acc[mi][ni], 0, 0, 0);
      }
    }
  }
  #pragma unroll
  for (int mi = 0; mi < 4; mi++)
  #pragma unroll
  for (int ni = 0; ni < 4; ni++){
    int col = n0 + wn + ni * 16 + l15;
    float bval = bias[col];
    int rowb = m0 + wm + mi * 16 + quad * 4;
    #pragma unroll
    for (int rg = 0; rg < 4; rg++){
      float v = acc[mi][ni][rg] + bval;
      float t = v + 0.044715f * v * v * v;
      float g = 0.5f * v * (1.f + tanhf(0.7978845608f * t));
      C0[(size_t)(rowb + rg) * N + col] = f2bf(g);
    }
  }
}

// ---------------------------------------------------------------------------
// Attention, single pass (online softmax). One wave per token; lane owns dims
// [4*lane,4*lane+4). EKV packed bf16: one 16B load per corner = k4|v4.
// Output: bf16 hi plane only (O-proj runs 2-pass on it).
// ---------------------------------------------------------------------------
__device__ __forceinline__ void unpack8(int4 p, f4& k4, f4& v4){
  k4.x = bf2f((u16)(p.x & 0xffff)); k4.y = bf2f((u16)((unsigned)p.x >> 16));
  k4.z = bf2f((u16)(p.y & 0xffff)); k4.w = bf2f((u16)((unsigned)p.y >> 16));
  v4.x = bf2f((u16)(p.z & 0xffff)); v4.y = bf2f((u16)((unsigned)p.z >> 16));
  v4.z = bf2f((u16)(p.w & 0xffff)); v4.w = bf2f((u16)((unsigned)p.w >> 16));
}

__global__ __launch_bounds__(256) void attn_k(const float* __restrict__ q,
                                              const u16* __restrict__ EKV,
                                              const float* __restrict__ offb,
                                              const float* __restrict__ locb,
                                              const float* __restrict__ kvc,
                                              u16* __restrict__ ah){
  const int tid = threadIdx.x;
  const int wave = tid >> 6, lane = tid & 63;
  const int tok = blockIdx.x * 4 + wave;
  const int base = (tok >> 12) << 12;   // n*4096
  const int4* E = (const int4*)EKV;     // 16B per (row,lane)
  const f4* kvc4 = (const f4*)kvc;
  f4 qv  = *((const f4*)q + (size_t)tok * 64 + lane);
  f4 wk0 = kvc4[lane], wk1 = kvc4[64 + lane], bkv = kvc4[128 + lane];
  f4 wv0 = kvc4[192 + lane], wv1 = kvc4[256 + lane], bvv = kvc4[320 + lane];
  float m = -1e30f, l = 0.f;
  f4 acc = {0.f, 0.f, 0.f, 0.f};
  #pragma unroll
  for (int s = 0; s < 16; s++){
    float y = locb[tok * 32 + s * 2], x = locb[tok * 32 + s * 2 + 1];
    float o0 = offb[tok * 32 + s * 2], o1 = offb[tok * 32 + s * 2 + 1];
    float yf = floorf(y), xf = floorf(x);
    int y0 = (int)yf, x0 = (int)xf;
    int y1 = min(y0 + 1, 63), x1 = min(x0 + 1, 63);
    float wy = y - yf, wx = x - xf;
    int4 p00 = E[(size_t)(base + y0 * 64 + x0) * 64 + lane];
    int4 p01 = E[(size_t)(base + y0 * 64 + x1) * 64 + lane];
    int4 p10 = E[(size_t)(base + y1 * 64 + x0) * 64 + lane];
    int4 p11 = E[(size_t)(base + y1 * 64 + x1) * 64 + lane];
    f4 k00, v00, k01, v01, k10, v10, k11, v11;
    unpack8(p00, k00, v00); unpack8(p01, k01, v01);
    unpack8(p10, k10, v10); unpack8(p11, k11, v11);
    float w00 = (1.f - wy) * (1.f - wx), w01 = (1.f - wy) * wx;
    float w10 = wy * (1.f - wx), w11 = wy * wx;
    f4 kk = w00 * k00 + w01 * k01 + w10 * k10 + w11 * k11;
    f4 vv = w00 * v00 + w01 * v01 + w10 * v10 + w11 * v11;
    kk += o0 * wk0 + o1 * wk1 + bkv;
    vv += o0 * wv0 + o1 * wv1 + bvv;
    float p = qv.x * kk.x + qv.y * kk.y + qv.z * kk.z + qv.w * kk.w;
    p += __shfl_xor(p, 1); p += __shfl_xor(p, 2);
    p += __shfl_xor(p, 4); p += __shfl_xor(p, 8);
    p *= 0.125f;   // /sqrt(64)
    float mn = fmaxf(m, p);
    float cor = __expf(m - mn);
    float wgt = __expf(p - mn);
    l = l * cor + wgt;
    acc = acc * cor + wgt * vv;
    m = mn;
  }
  float inv = 1.f / l;
  f4 o = acc * inv;
  ushort4 h;
  h.x = f2bf(o.x); h.y = f2bf(o.y); h.z = f2bf(o.z); h.w = f2bf(o.w);
  *(ushort4*)(ah + (size_t)tok * 256 + lane * 4) = h;
}

// ---------------------------------------------------------------------------
// LayerNorm(a + b) * scale + bias. One wave per token.
// INP: 0 -> a0 fp32; 1 -> a0/a1 hi/lo planes.  OUTP: 0 -> fp32; 1 -> planes.
// ---------------------------------------------------------------------------
template<int INP, int OUTP>
__global__ __launch_bounds__(256) void ln_k(const void* __restrict__ a0,
                                            const void* __restrict__ a1,
                                            const float* __restrict__ b,
                                            const float* __restrict__ sc,
                                            const float* __restrict__ bi,
                                            void* __restrict__ o0,
                                            void* __restrict__ o1){
  const int tid = threadIdx.x;
  const int wave = tid >> 6, lane = tid & 63;
  const int tok = blockIdx.x * 4 + wave;
  float x0, x1, x2, x3;
  if (INP){
    ushort4 h = ((const ushort4*)a0)[(size_t)tok * 64 + lane];
    ushort4 lo = ((const ushort4*)a1)[(size_t)tok * 64 + lane];
    x0 = bf2f(h.x) + bf2f(lo.x); x1 = bf2f(h.y) + bf2f(lo.y);
    x2 = bf2f(h.z) + bf2f(lo.z); x3 = bf2f(h.w) + bf2f(lo.w);
  } else {
    f4 av = ((const f4*)a0)[(size_t)tok * 64 + lane];
    x0 = av.x; x1 = av.y; x2 = av.z; x3 = av.w;
  }
  f4 bv = ((const f4*)b)[(size_t)tok * 64 + lane];
  x0 += bv.x; x1 += bv.y; x2 += bv.z; x3 += bv.w;
  float sm = x0 + x1 + x2 + x3;
  float sq = x0 * x0 + x1 * x1 + x2 * x2 + x3 * x3;
  #pragma unroll
  for (int mm = 1; mm < 64; mm <<= 1){ sm += __shfl_xor(sm, mm); sq += __shfl_xor(sq, mm); }
  float mean = sm * (1.f / 256.f);
  float var = sq * (1.f / 256.f) - mean * mean;
  float rs = rsqrtf(var + 1e-6f);
  f4 sv = ((const f4*)sc)[lane];
  f4 bb = ((const f4*)bi)[lane];
  float y0 = (x0 - mean) * rs * sv.x + bb.x;
  float y1 = (x1 - mean) * rs * sv.y + bb.y;
  float y2 = (x2 - mean) * rs * sv.z + bb.z;
  float y3 = (x3 - mean) * rs * sv.w + bb.w;
  if (OUTP){
    ushort4 h, lo;
    h.x = f2bf(y0); lo.x = f2bf(y0 - bf2f(h.x));
    h.y = f2bf(y1); lo.y = f2bf(y1 - bf2f(h.y));
    h.z = f2bf(y2); lo.z = f2bf(y2 - bf2f(h.z));
    h.w = f2bf(y3); lo.w = f2bf(y3 - bf2f(h.w));
    ((ushort4*)o0)[(size_t)tok * 64 + lane] = h;
    ((ushort4*)o1)[(size_t)tok * 64 + lane] = lo;
  } else {
    f4 ov = {y0, y1, y2, y3};
    ((f4*)o0)[(size_t)tok * 64 + lane] = ov;
  }
}

// ---------------------------------------------------------------------------
extern "C" void kernel_launch(void* const* d_in, const int* in_sizes, int n_in,
                              void* d_out, int out_size, void* d_ws, size_t ws_size,
                              hipStream_t stream){
  const float* hs   = (const float*)d_in[0];
  const float* emb  = (const float*)d_in[1];
  const float* Woff = (const float*)d_in[2];
  const float* boff = (const float*)d_in[3];
  const float* Wkvp = (const float*)d_in[4];
  const float* bkvp = (const float*)d_in[5];
  const float* Wq   = (const float*)d_in[6];
  const float* bq   = (const float*)d_in[7];
  const float* Wk   = (const float*)d_in[8];
  const float* bk   = (const float*)d_in[9];
  const float* Wv   = (const float*)d_in[10];
  const float* bv   = (const float*)d_in[11];
  const float* Wo   = (const float*)d_in[12];
  const float* bo   = (const float*)d_in[13];
  const float* ln1s = (const float*)d_in[14];
  const float* ln1b = (const float*)d_in[15];
  const float* ln2s = (const float*)d_in[16];
  const float* ln2b = (const float*)d_in[17];
  const float* W1   = (const float*)d_in[18];
  const float* b1   = (const float*)d_in[19];
  const float* W2   = (const float*)d_in[20];
  const float* b2   = (const float*)d_in[21];

  char* w = (char*)d_ws;
  auto alloc = [&](size_t bytes){ char* p = w; w += (bytes + 255) & ~(size_t)255; return p; };
  // weight planes: [WqT | WkT | WvT | WoT] contiguous hi and lo
  u16* qkvoTh = (u16*)alloc(4 * 65536 * 2);
  u16* qkvoTl = (u16*)alloc(4 * 65536 * 2);
  u16* WqTh = qkvoTh;              u16* WqTl = qkvoTl;
  u16* kvWh = qkvoTh + 65536;      u16* kvWl = qkvoTl + 65536;   // [512,256]
  u16* WoTh = qkvoTh + 3 * 65536;  u16* WoTl = qkvoTl + 3 * 65536;
  u16* W1Th = (u16*)alloc(262144 * 2); u16* W1Tl = (u16*)alloc(262144 * 2);
  u16* W2Th = (u16*)alloc(262144 * 2); u16* W2Tl = (u16*)alloc(262144 * 2);
  float* kvc = (float*)alloc(1536 * 4);
  // slot1 (8.4 MB): hs hi/lo planes / attn hi plane / xb planes
  char* slot1 = alloc((size_t)NT * 256 * 4);
  u16* hsph = (u16*)slot1;          u16* hspl = hsph + (size_t)NT * 256;
  u16* attnh = hsph;
  u16* xbh = hsph;                  u16* xbl = hspl;
  // slot2 (8.4 MB): emb bf16 plane / aout fp32
  char* slot2 = alloc((size_t)NT * 256 * 4);
  u16* embh = (u16*)slot2;
  float* aout = (float*)slot2;
  // slot3 (8.4 MB): off+loc / mout fp32
  char* slot3 = alloc((size_t)NT * 256 * 4);
  float* off = (float*)slot3;       float* loc = off + (size_t)NT * 32;
  float* mout = (float*)slot3;
  // slot4 (16.8 MB): qb fp32 + EKV bf16 / h1 bf16 [NT,1024] (16 MB)
  char* slot4 = alloc((size_t)NT * 256 * 8);
  float* qb = (float*)slot4;
  u16* EKV = (u16*)(slot4 + (size_t)NT * 256 * 4);   // [NT,512] packed bf16
  u16* h1 = (u16*)slot4;                             // [NT,1024] bf16 plane
  if ((size_t)(w - (char*)d_ws) > ws_size) return;

  // prep
  prep_k<<<4096, 256, 0, stream>>>(hs, emb, hsph, hspl, embh);
  transposeB_k<<<dim3(8, 8, 4), 256, 0, stream>>>(Wq, Wk, Wv, Wo, qkvoTh, qkvoTl);
  transpose3_k<<<dim3(32, 8), 256, 0, stream>>>(W1, W1Th, W1Tl, 256, 1024);
  transpose3_k<<<dim3(8, 32), 256, 0, stream>>>(W2, W2Th, W2Tl, 1024, 256);
  prepkv_k<<<2, 256, 0, stream>>>(Wkvp, bkvp, Wk, bk, Wv, bv, kvc);
  offsets_k<<<1024, 256, 0, stream>>>(hs, Woff, boff, off, loc);

  // grouped q (3-pass) + EKV (2-pass) in ONE 1536-block dispatch
  qekv_k<<<1536, 256, 0, stream>>>(hsph, hspl, WqTh, WqTl, bq,
                                   embh, kvWh, kvWl, qb, EKV);

  // gather + online-softmax attention
  attn_k<<<2048, 256, 0, stream>>>(qb, EKV, off, loc, kvc, attnh);

  // out-proj (2-pass), LN1, MLP (W1 via 128x128 tile), LN2
  gemm_k<64, 1, 0><<<dim3(128, 4), 256, 0, stream>>>(attnh, nullptr, WoTh, WoTl, bo, aout, NT, 256, 256);
  ln_k<0, 1><<<2048, 256, 0, stream>>>(hs, nullptr, aout, ln1s, ln1b, xbh, xbl);
  gemm128_k<<<dim3(64, 8), 256, 0, stream>>>(xbh, W1Th, W1Tl, b1, h1, NT, 1024, 256);
  gemm_k<64, 1, 0><<<dim3(128, 4), 256, 0, stream>>>(h1, nullptr, W2Th, W2Tl, b2, mout, NT, 256, 1024);
  ln_k<1, 0><<<2048, 256, 0, stream>>>(xbh, xbl, mout, ln2s, ln2b, d_out, nullptr);
}

// Round 12
// 263.084 us; speedup vs baseline: 1.5194x; 1.0225x over previous
//
#include <hip/hip_runtime.h>

// Problem dims
#define NT 8192      // N*H*W tokens
#define DM 256
#define HH 64
#define WW 64

typedef unsigned short u16;
typedef __attribute__((ext_vector_type(8))) short short8;  // 8 x bf16 mfma frag
typedef __attribute__((ext_vector_type(4))) float f4;

__device__ __forceinline__ float bf2f(u16 u){
  union { unsigned int i; float f; } v; v.i = ((unsigned int)u) << 16; return v.f;
}
__device__ __forceinline__ u16 f2bf(float f){
  union { float f; unsigned int i; } v; v.f = f;
  unsigned int r = (v.i + 0x7fffu + ((v.i >> 16) & 1u)) >> 16;
  return (u16)r;
}
// async global->LDS 16B (direct DMA, no VGPR round trip)
__device__ __forceinline__ void gld16(const void* g, void* l){
  __builtin_amdgcn_global_load_lds(
      (const __attribute__((address_space(1))) unsigned int*)g,
      (__attribute__((address_space(3))) unsigned int*)l, 16, 0, 0);
}

// ---------------------------------------------------------------------------
// Prolog: per block of 8 tokens — offsets GEMV + hs -> hi/lo planes +
// emb -> hi plane. hs read ONCE via LDS (replaces prep_k + offsets_k).
// Numerically identical to the split kernels.
// ---------------------------------------------------------------------------
__global__ __launch_bounds__(256) void prolog_k(const float* __restrict__ hs,
                                                const float* __restrict__ emb,
                                                const float* __restrict__ Woff,
                                                const float* __restrict__ boff,
                                                u16* __restrict__ hsph,
                                                u16* __restrict__ hspl,
                                                u16* __restrict__ embh,
                                                float* __restrict__ off,
                                                float* __restrict__ loc){
  __shared__ float hsl[2048];
  __shared__ float wl[8192];
  const int tid = threadIdx.x;
  const int t0 = blockIdx.x * 8;
  for (int i = tid; i < 8192; i += 256) wl[i] = Woff[i];
  for (int i = tid; i < 2048; i += 256) hsl[i] = hs[(size_t)t0 * 256 + i];
  __syncthreads();
  // offsets: thread = (token g = tid>>5, output o = tid&31 = s*2+k)
  {
    const int g = tid >> 5, o = tid & 31;
    float acc = 0.f;
    #pragma unroll 8
    for (int d = 0; d < 256; d++) acc += hsl[g * 256 + d] * wl[d * 32 + o];
    acc += boff[o];
    float sg = 1.f / (1.f + expf(-acc));
    float of = 60.f * sg - 30.f;
    int tok = t0 + g;
    int hh = (tok >> 6) & 63, ww = tok & 63;
    float base = (o & 1) ? (float)ww : (float)hh;
    float l = fminf(fmaxf(base + of, 0.f), 63.f);
    off[tok * 32 + o] = of;
    loc[tok * 32 + o] = l;
  }
  // hs split + emb cvt: 512 f4 chunks over 8 tokens
  for (int c = tid; c < 512; c += 256){
    f4 v = *(const f4*)&hsl[c * 4];
    ushort4 h, l;
    h.x = f2bf(v.x); l.x = f2bf(v.x - bf2f(h.x));
    h.y = f2bf(v.y); l.y = f2bf(v.y - bf2f(h.y));
    h.z = f2bf(v.z); l.z = f2bf(v.z - bf2f(h.z));
    h.w = f2bf(v.w); l.w = f2bf(v.w - bf2f(h.w));
    ((ushort4*)hsph)[(size_t)t0 * 64 + c] = h;
    ((ushort4*)hspl)[(size_t)t0 * 64 + c] = l;
    f4 e = ((const f4*)emb)[(size_t)t0 * 64 + c];
    ushort4 eh;
    eh.x = f2bf(e.x); eh.y = f2bf(e.y); eh.z = f2bf(e.z); eh.w = f2bf(e.w);
    ((ushort4*)embh)[(size_t)t0 * 64 + c] = eh;
  }
}

// ---------------------------------------------------------------------------
// All weight prep in ONE dispatch (770 blocks):
//  b<256: qkvo transposes (4 mats x 64 tiles); 256..511: W1^T; 512..767: W2^T;
//  768/769: fold W_kvp/b_kvp through Wk/Wv -> kvc. Numerically identical to
//  the split transposeB/transpose3/prepkv kernels.
// ---------------------------------------------------------------------------
__global__ __launch_bounds__(256) void weights_k(const float* __restrict__ Wq,
                                                 const float* __restrict__ Wk,
                                                 const float* __restrict__ Wv,
                                                 const float* __restrict__ Wo,
                                                 const float* __restrict__ W1,
                                                 const float* __restrict__ W2,
                                                 const float* __restrict__ Wkvp,
                                                 const float* __restrict__ bkvp,
                                                 const float* __restrict__ bk,
                                                 const float* __restrict__ bv,
                                                 u16* __restrict__ qkvoTh,
                                                 u16* __restrict__ qkvoTl,
                                                 u16* __restrict__ W1Th,
                                                 u16* __restrict__ W1Tl,
                                                 u16* __restrict__ W2Th,
                                                 u16* __restrict__ W2Tl,
                                                 float* __restrict__ kvc){
  __shared__ float t[32][33];
  const int b = blockIdx.x;
  const int tid = threadIdx.x;
  if (b >= 768){               // prepkv fold
    const float* Wx = (b == 768) ? Wk : Wv;
    const float* bx = (b == 768) ? bk : bv;
    float* o = kvc + (b - 768) * 768;
    int e = tid;
    float a0 = 0.f, a1 = 0.f, ab = 0.f;
    for (int d = 0; d < 256; d++){
      float w = Wx[d * 256 + e];
      a0 += Wkvp[d] * w;
      a1 += Wkvp[256 + d] * w;
      ab += bkvp[d] * w;
    }
    o[e] = a0; o[256 + e] = a1; o[512 + e] = ab + bx[e];
    return;
  }
  const float* src; u16 *dh, *dl; int R, C, c0, r0;
  if (b < 256){
    int mat = b >> 6, tt = b & 63;
    src = mat == 0 ? Wq : mat == 1 ? Wk : mat == 2 ? Wv : Wo;
    dh = qkvoTh + mat * 65536; dl = qkvoTl + mat * 65536;
    R = 256; C = 256; c0 = (tt & 7) * 32; r0 = (tt >> 3) * 32;
  } else if (b < 512){
    int tt = b - 256; src = W1; dh = W1Th; dl = W1Tl; R = 256; C = 1024;
    c0 = (tt & 31) * 32; r0 = (tt >> 5) * 32;
  } else {
    int tt = b - 512; src = W2; dh = W2Th; dl = W2Tl; R = 1024; C = 256;
    c0 = (tt & 7) * 32; r0 = (tt >> 3) * 32;
  }
  int tx = tid & 31, ty = tid >> 5;
  for (int i = ty; i < 32; i += 8) t[i][tx] = src[(size_t)(r0 + i) * C + c0 + tx];
  __syncthreads();
  for (int i = ty; i < 32; i += 8){
    float x = t[tx][i];
    u16 h = f2bf(x);
    size_t idx = (size_t)(c0 + i) * R + r0 + tx;
    dh[idx] = h;
    dl[idx] = f2bf(x - bf2f(h));
  }
}

// ---------------------------------------------------------------------------
// Grouped q + EKV GEMM, ONE dispatch (1536 blocks), BM=BN=64, BK=64, K=256.
//  blocks 0..511:    q   = hs(hi/lo, 3-pass) x WqT(hi/lo) + bq -> fp32 qb
//  blocks 512..1535: EKV = emb(hi, 2-pass)  x kvWT(hi/lo)      -> packed bf16
// ---------------------------------------------------------------------------
__global__ __launch_bounds__(256) void qekv_k(const u16* __restrict__ hsph,
                                              const u16* __restrict__ hspl,
                                              const u16* __restrict__ WqTh,
                                              const u16* __restrict__ WqTl,
                                              const float* __restrict__ bq,
                                              const u16* __restrict__ embh,
                                              const u16* __restrict__ kvWh,
                                              const u16* __restrict__ kvWl,
                                              float* __restrict__ qb,
                                              u16* __restrict__ EKV){
  __shared__ __align__(16) u16 Ah[8][64][8];
  __shared__ __align__(16) u16 Al[8][64][8];
  __shared__ __align__(16) u16 Bh[8][64][8];
  __shared__ __align__(16) u16 Bl[8][64][8];
  const int bid = blockIdx.x;
  const bool isQ = bid < 512;
  const int b2 = isQ ? bid : bid - 512;
  const int m0 = (b2 & 127) << 6;
  const int n0 = (b2 >> 7) << 6;
  const int K = 256;
  const u16* Agh = isQ ? hsph : embh;
  const u16* Bgh = isQ ? WqTh : kvWh;
  const u16* Bgl = isQ ? WqTl : kvWl;
  const int tid = threadIdx.x;
  const int lane = tid & 63, wave = tid >> 6;
  const int quad = lane >> 4, l15 = lane & 15;
  const int wm = (wave >> 1) << 5, wn = (wave & 1) << 5;
  const int ar = tid & 63, aq = tid >> 6;
  const u16* gAh = Agh + (size_t)(m0 + ar) * K + aq * 8;
  const u16* gAl = hspl + (size_t)(m0 + ar) * K + aq * 8;   // only read if isQ
  const u16* gBh = Bgh + (size_t)(n0 + ar) * K + aq * 8;
  const u16* gBl = Bgl + (size_t)(n0 + ar) * K + aq * 8;
  f4 acc[2][2] = {};
  for (int k0 = 0; k0 < K; k0 += 64){
    __syncthreads();
    gld16(gAh + k0,      &Ah[aq][ar][0]);
    gld16(gAh + k0 + 32, &Ah[aq + 4][ar][0]);
    if (isQ){
      gld16(gAl + k0,      &Al[aq][ar][0]);
      gld16(gAl + k0 + 32, &Al[aq + 4][ar][0]);
    }
    gld16(gBh + k0,      &Bh[aq][ar][0]);
    gld16(gBh + k0 + 32, &Bh[aq + 4][ar][0]);
    gld16(gBl + k0,      &Bl[aq][ar][0]);
    gld16(gBl + k0 + 32, &Bl[aq + 4][ar][0]);
    asm volatile("s_waitcnt vmcnt(0)" ::: "memory");
    __syncthreads();
    #pragma unroll
    for (int kh = 0; kh < 2; kh++){
      const int q = kh * 4 + quad;
      short8 ahf[2], alf[2], bhf[2], blf[2];
      #pragma unroll
      for (int i = 0; i < 2; i++){
        ahf[i] = *(const short8*)(&Ah[q][wm + i * 16 + l15][0]);
        bhf[i] = *(const short8*)(&Bh[q][wn + i * 16 + l15][0]);
        blf[i] = *(const short8*)(&Bl[q][wn + i * 16 + l15][0]);
      }
      if (isQ){
        #pragma unroll
        for (int i = 0; i < 2; i++)
          alf[i] = *(const short8*)(&Al[q][wm + i * 16 + l15][0]);
      }
      #pragma unroll
      for (int mi = 0; mi < 2; mi++)
      #pragma unroll
      for (int ni = 0; ni < 2; ni++){
        if (isQ)
          acc[mi][ni] = __builtin_amdgcn_mfma_f32_16x16x32_bf16(alf[mi], bhf[ni], acc[mi][ni], 0, 0, 0);
        acc[mi][ni] = __builtin_amdgcn_mfma_f32_16x16x32_bf16(ahf[mi], blf[ni], acc[mi][ni], 0, 0, 0);
        acc[mi][ni] = __builtin_amdgcn_mfma_f32_16x16x32_bf16(ahf[mi], bhf[ni], acc[mi][ni], 0, 0, 0);
      }
    }
  }
  #pragma unroll
  for (int mi = 0; mi < 2; mi++)
  #pragma unroll
  for (int ni = 0; ni < 2; ni++){
    int col = n0 + wn + ni * 16 + l15;
    int rowb = m0 + wm + mi * 16 + quad * 4;
    if (isQ){
      float bval = bq[col];
      #pragma unroll
      for (int rg = 0; rg < 4; rg++)
        qb[(size_t)(rowb + rg) * 256 + col] = acc[mi][ni][rg] + bval;
    } else {
      int part = col >> 8, d = col & 255;
      int pc = ((d >> 2) << 3) + (part << 2) + (d & 3);
      #pragma unroll
      for (int rg = 0; rg < 4; rg++)
        EKV[(size_t)(rowb + rg) * 512 + pc] = f2bf(acc[mi][ni][rg]);
    }
  }
}

// ---------------------------------------------------------------------------
// Split-precision MFMA GEMM (r7-proven). BM=64, BK=64, BN=64 used here.
// APREC 1: A single bf16 plane -> Ah*Bl + Ah*Bh.  EPI 0: fp32 +bias.
// ---------------------------------------------------------------------------
template<int BN, int APREC, int EPI>
__global__ __launch_bounds__(256) void gemm_k(const u16* __restrict__ Agh,
                                              const u16* __restrict__ Agl,
                                              const u16* __restrict__ Bgh,
                                              const u16* __restrict__ Bgl,
                                              const float* __restrict__ bias,
                                              void* __restrict__ C0,
                                              int M, int N, int K){
  constexpr int NF = BN / 32;
  __shared__ __align__(16) u16 Ah[8][64][8];
  __shared__ __align__(16) u16 Al[APREC == 2 ? 8 : 1][64][8];
  __shared__ __align__(16) u16 Bh[8][BN][8];
  __shared__ __align__(16) u16 Bl[8][BN][8];
  const int m0 = blockIdx.x << 6, n0 = blockIdx.y * BN;
  const int tid = threadIdx.x;
  const int lane = tid & 63, wave = tid >> 6;
  const int quad = lane >> 4, l15 = lane & 15;
  const int wm = (wave >> 1) << 5;
  const int wn = (wave & 1) * (BN >> 1);
  const int ar = tid & 63, aq = tid >> 6;
  const u16* gAh = Agh + (size_t)(m0 + ar) * K + aq * 8;
  const u16* gAl = (APREC == 2) ? (Agl + (size_t)(m0 + ar) * K + aq * 8) : nullptr;
  const int br = (BN == 128) ? (tid & 127) : (tid & 63);
  const int bq = (BN == 128) ? (tid >> 7) : (tid >> 6);
  const u16* gBh = Bgh + (size_t)(n0 + br) * K + bq * 8;
  const u16* gBl = Bgl + (size_t)(n0 + br) * K + bq * 8;
  f4 acc[2][NF] = {};
  for (int k0 = 0; k0 < K; k0 += 64){
    __syncthreads();
    gld16(gAh + k0,      &Ah[aq][ar][0]);
    gld16(gAh + k0 + 32, &Ah[aq + 4][ar][0]);
    if (APREC == 2){
      gld16(gAl + k0,      &Al[aq][ar][0]);
      gld16(gAl + k0 + 32, &Al[aq + 4][ar][0]);
    }
    if (BN == 128){
      gld16(gBh + k0,      &Bh[bq][br][0]);
      gld16(gBh + k0 + 16, &Bh[bq + 2][br][0]);
      gld16(gBh + k0 + 32, &Bh[bq + 4][br][0]);
      gld16(gBh + k0 + 48, &Bh[bq + 6][br][0]);
      gld16(gBl + k0,      &Bl[bq][br][0]);
      gld16(gBl + k0 + 16, &Bl[bq + 2][br][0]);
      gld16(gBl + k0 + 32, &Bl[bq + 4][br][0]);
      gld16(gBl + k0 + 48, &Bl[bq + 6][br][0]);
    } else {
      gld16(gBh + k0,      &Bh[bq][br][0]);
      gld16(gBh + k0 + 32, &Bh[bq + 4][br][0]);
      gld16(gBl + k0,      &Bl[bq][br][0]);
      gld16(gBl + k0 + 32, &Bl[bq + 4][br][0]);
    }
    asm volatile("s_waitcnt vmcnt(0)" ::: "memory");
    __syncthreads();
    #pragma unroll
    for (int kh = 0; kh < 2; kh++){
      const int q = kh * 4 + quad;
      short8 ahf[2], alf[2], bhf[NF], blf[NF];
      #pragma unroll
      for (int i = 0; i < 2; i++){
        ahf[i] = *(const short8*)(&Ah[q][wm + i * 16 + l15][0]);
        if (APREC == 2) alf[i] = *(const short8*)(&Al[q][wm + i * 16 + l15][0]);
      }
      #pragma unroll
      for (int i = 0; i < NF; i++){
        bhf[i] = *(const short8*)(&Bh[q][wn + i * 16 + l15][0]);
        blf[i] = *(const short8*)(&Bl[q][wn + i * 16 + l15][0]);
      }
      #pragma unroll
      for (int mi = 0; mi < 2; mi++)
      #pragma unroll
      for (int ni = 0; ni < NF; ni++){
        if (APREC == 2)
          acc[mi][ni] = __builtin_amdgcn_mfma_f32_16x16x32_bf16(alf[mi], bhf[ni], acc[mi][ni], 0, 0, 0);
        acc[mi][ni] = __builtin_amdgcn_mfma_f32_16x16x32_bf16(ahf[mi], blf[ni], acc[mi][ni], 0, 0, 0);
        acc[mi][ni] = __builtin_amdgcn_mfma_f32_16x16x32_bf16(ahf[mi], bhf[ni], acc[mi][ni], 0, 0, 0);
      }
    }
  }
  #pragma unroll
  for (int mi = 0; mi < 2; mi++)
  #pragma unroll
  for (int ni = 0; ni < NF; ni++){
    int col = n0 + wn + ni * 16 + l15;
    float bval = bias ? bias[col] : 0.f;
    int rowb = m0 + wm + mi * 16 + quad * 4;
    #pragma unroll
    for (int rg = 0; rg < 4; rg++){
      float v = acc[mi][ni][rg] + bval;
      int row = rowb + rg;
      if (EPI == 0){
        ((float*)C0)[(size_t)row * N + col] = v;
      } else if (EPI == 1){
        float t = v + 0.044715f * v * v * v;
        float g = 0.5f * v * (1.f + tanhf(0.7978845608f * t));
        ((u16*)C0)[(size_t)row * N + col] = f2bf(g);
      } else {
        int part = col >> 8, d = col & 255;
        int pc = ((d >> 2) << 3) + (part << 2) + (d & 3);
        ((u16*)C0)[(size_t)row * 512 + pc] = f2bf(v);
      }
    }
  }
}

// ---------------------------------------------------------------------------
// Dedicated W1 GEMM: 128x128 tile, BK=64, A single bf16 plane (2-pass),
// gelu -> bf16. Proven clean under replay tripwire (r10).
// ---------------------------------------------------------------------------
__global__ __launch_bounds__(256) void gemm128_k(const u16* __restrict__ Agh,
                                                 const u16* __restrict__ Bgh,
                                                 const u16* __restrict__ Bgl,
                                                 const float* __restrict__ bias,
                                                 u16* __restrict__ C0,
                                                 int M, int N, int K){
  __shared__ __align__(16) u16 Ah[8][128][8];
  __shared__ __align__(16) u16 Bh[8][128][8];
  __shared__ __align__(16) u16 Bl[8][128][8];
  const int m0 = blockIdx.x << 7, n0 = blockIdx.y << 7;
  const int tid = threadIdx.x;
  const int lane = tid & 63, wave = tid >> 6;
  const int quad = lane >> 4, l15 = lane & 15;
  const int wm = (wave >> 1) << 6, wn = (wave & 1) << 6;
  const int ar = tid & 127, q0 = tid >> 7;
  const u16* gA  = Agh + (size_t)(m0 + ar) * K + q0 * 8;
  const u16* gBhp = Bgh + (size_t)(n0 + ar) * K + q0 * 8;
  const u16* gBlp = Bgl + (size_t)(n0 + ar) * K + q0 * 8;
  f4 acc[4][4] = {};
  for (int k0 = 0; k0 < K; k0 += 64){
    __syncthreads();
    #pragma unroll
    for (int j = 0; j < 4; j++){
      gld16(gA   + k0 + j * 16, &Ah[q0 + 2 * j][ar][0]);
      gld16(gBhp + k0 + j * 16, &Bh[q0 + 2 * j][ar][0]);
      gld16(gBlp + k0 + j * 16, &Bl[q0 + 2 * j][ar][0]);
    }
    asm volatile("s_waitcnt vmcnt(0)" ::: "memory");
    __syncthreads();
    #pragma unroll
    for (int kh = 0; kh < 2; kh++){
      const int q = kh * 4 + quad;
      short8 af[4], bh8[4], bl8[4];
      #pragma unroll
      for (int i = 0; i < 4; i++){
        af[i]  = *(const short8*)(&Ah[q][wm + i * 16 + l15][0]);
        bh8[i] = *(const short8*)(&Bh[q][wn + i * 16 + l15][0]);
        bl8[i] = *(const short8*)(&Bl[q][wn + i * 16 + l15][0]);
      }
      #pragma unroll
      for (int mi = 0; mi < 4; mi++)
      #pragma unroll
      for (int ni = 0; ni < 4; ni++){
        acc[mi][ni] = __builtin_amdgcn_mfma_f32_16x16x32_bf16(af[mi], bl8[ni], acc[mi][ni], 0, 0, 0);
        acc[mi][ni] = __builtin_amdgcn_mfma_f32_16x16x32_bf16(af[mi], bh8[ni], acc[mi][ni], 0, 0, 0);
      }
    }
  }
  #pragma unroll
  for (int mi = 0; mi < 4; mi++)
  #pragma unroll
  for (int ni = 0; ni < 4; ni++){
    int col = n0 + wn + ni * 16 + l15;
    float bval = bias[col];
    int rowb = m0 + wm + mi * 16 + quad * 4;
    #pragma unroll
    for (int rg = 0; rg < 4; rg++){
      float v = acc[mi][ni][rg] + bval;
      float t = v + 0.044715f * v * v * v;
      float g = 0.5f * v * (1.f + tanhf(0.7978845608f * t));
      C0[(size_t)(rowb + rg) * N + col] = f2bf(g);
    }
  }
}

// ---------------------------------------------------------------------------
// Attention, single pass (online softmax). One wave per token; lane owns dims
// [4*lane,4*lane+4). EKV packed bf16: one 16B load per corner = k4|v4.
// Output: bf16 hi plane only (O-proj runs 2-pass on it). Linear token map.
// ---------------------------------------------------------------------------
__device__ __forceinline__ void unpack8(int4 p, f4& k4, f4& v4){
  k4.x = bf2f((u16)(p.x & 0xffff)); k4.y = bf2f((u16)((unsigned)p.x >> 16));
  k4.z = bf2f((u16)(p.y & 0xffff)); k4.w = bf2f((u16)((unsigned)p.y >> 16));
  v4.x = bf2f((u16)(p.z & 0xffff)); v4.y = bf2f((u16)((unsigned)p.z >> 16));
  v4.z = bf2f((u16)(p.w & 0xffff)); v4.w = bf2f((u16)((unsigned)p.w >> 16));
}

__global__ __launch_bounds__(256) void attn_k(const float* __restrict__ q,
                                              const u16* __restrict__ EKV,
                                              const float* __restrict__ offb,
                                              const float* __restrict__ locb,
                                              const float* __restrict__ kvc,
                                              u16* __restrict__ ah){
  const int tid = threadIdx.x;
  const int wave = tid >> 6, lane = tid & 63;
  const int tok = blockIdx.x * 4 + wave;
  const int base = (tok >> 12) << 12;   // n*4096
  const int4* E = (const int4*)EKV;     // 16B per (row,lane)
  const f4* kvc4 = (const f4*)kvc;
  f4 qv  = *((const f4*)q + (size_t)tok * 64 + lane);
  f4 wk0 = kvc4[lane], wk1 = kvc4[64 + lane], bkv = kvc4[128 + lane];
  f4 wv0 = kvc4[192 + lane], wv1 = kvc4[256 + lane], bvv = kvc4[320 + lane];
  float m = -1e30f, l = 0.f;
  f4 acc = {0.f, 0.f, 0.f, 0.f};
  #pragma unroll
  for (int s = 0; s < 16; s++){
    float y = locb[tok * 32 + s * 2], x = locb[tok * 32 + s * 2 + 1];
    float o0 = offb[tok * 32 + s * 2], o1 = offb[tok * 32 + s * 2 + 1];
    float yf = floorf(y), xf = floorf(x);
    int y0 = (int)yf, x0 = (int)xf;
    int y1 = min(y0 + 1, 63), x1 = min(x0 + 1, 63);
    float wy = y - yf, wx = x - xf;
    int4 p00 = E[(size_t)(base + y0 * 64 + x0) * 64 + lane];
    int4 p01 = E[(size_t)(base + y0 * 64 + x1) * 64 + lane];
    int4 p10 = E[(size_t)(base + y1 * 64 + x0) * 64 + lane];
    int4 p11 = E[(size_t)(base + y1 * 64 + x1) * 64 + lane];
    f4 k00, v00, k01, v01, k10, v10, k11, v11;
    unpack8(p00, k00, v00); unpack8(p01, k01, v01);
    unpack8(p10, k10, v10); unpack8(p11, k11, v11);
    float w00 = (1.f - wy) * (1.f - wx), w01 = (1.f - wy) * wx;
    float w10 = wy * (1.f - wx), w11 = wy * wx;
    f4 kk = w00 * k00 + w01 * k01 + w10 * k10 + w11 * k11;
    f4 vv = w00 * v00 + w01 * v01 + w10 * v10 + w11 * v11;
    kk += o0 * wk0 + o1 * wk1 + bkv;
    vv += o0 * wv0 + o1 * wv1 + bvv;
    float p = qv.x * kk.x + qv.y * kk.y + qv.z * kk.z + qv.w * kk.w;
    p += __shfl_xor(p, 1); p += __shfl_xor(p, 2);
    p += __shfl_xor(p, 4); p += __shfl_xor(p, 8);
    p *= 0.125f;   // /sqrt(64)
    float mn = fmaxf(m, p);
    float cor = __expf(m - mn);
    float wgt = __expf(p - mn);
    l = l * cor + wgt;
    acc = acc * cor + wgt * vv;
    m = mn;
  }
  float inv = 1.f / l;
  f4 o = acc * inv;
  ushort4 h;
  h.x = f2bf(o.x); h.y = f2bf(o.y); h.z = f2bf(o.z); h.w = f2bf(o.w);
  *(ushort4*)(ah + (size_t)tok * 256 + lane * 4) = h;
}

// ---------------------------------------------------------------------------
// LayerNorm(a + b) * scale + bias. One wave per token.
// INP: 0 -> a0 fp32; 1 -> a0/a1 hi/lo planes.  OUTP: 0 -> fp32; 1 -> planes.
// ---------------------------------------------------------------------------
template<int INP, int OUTP>
__global__ __launch_bounds__(256) void ln_k(const void* __restrict__ a0,
                                            const void* __restrict__ a1,
                                            const float* __restrict__ b,
                                            const float* __restrict__ sc,
                                            const float* __restrict__ bi,
                                            void* __restrict__ o0,
                                            void* __restrict__ o1){
  const int tid = threadIdx.x;
  const int wave = tid >> 6, lane = tid & 63;
  const int tok = blockIdx.x * 4 + wave;
  float x0, x1, x2, x3;
  if (INP){
    ushort4 h = ((const ushort4*)a0)[(size_t)tok * 64 + lane];
    ushort4 lo = ((const ushort4*)a1)[(size_t)tok * 64 + lane];
    x0 = bf2f(h.x) + bf2f(lo.x); x1 = bf2f(h.y) + bf2f(lo.y);
    x2 = bf2f(h.z) + bf2f(lo.z); x3 = bf2f(h.w) + bf2f(lo.w);
  } else {
    f4 av = ((const f4*)a0)[(size_t)tok * 64 + lane];
    x0 = av.x; x1 = av.y; x2 = av.z; x3 = av.w;
  }
  f4 bv = ((const f4*)b)[(size_t)tok * 64 + lane];
  x0 += bv.x; x1 += bv.y; x2 += bv.z; x3 += bv.w;
  float sm = x0 + x1 + x2 + x3;
  float sq = x0 * x0 + x1 * x1 + x2 * x2 + x3 * x3;
  #pragma unroll
  for (int mm = 1; mm < 64; mm <<= 1){ sm += __shfl_xor(sm, mm); sq += __shfl_xor(sq, mm); }
  float mean = sm * (1.f / 256.f);
  float var = sq * (1.f / 256.f) - mean * mean;
  float rs = rsqrtf(var + 1e-6f);
  f4 sv = ((const f4*)sc)[lane];
  f4 bb = ((const f4*)bi)[lane];
  float y0 = (x0 - mean) * rs * sv.x + bb.x;
  float y1 = (x1 - mean) * rs * sv.y + bb.y;
  float y2 = (x2 - mean) * rs * sv.z + bb.z;
  float y3 = (x3 - mean) * rs * sv.w + bb.w;
  if (OUTP){
    ushort4 h, lo;
    h.x = f2bf(y0); lo.x = f2bf(y0 - bf2f(h.x));
    h.y = f2bf(y1); lo.y = f2bf(y1 - bf2f(h.y));
    h.z = f2bf(y2); lo.z = f2bf(y2 - bf2f(h.z));
    h.w = f2bf(y3); lo.w = f2bf(y3 - bf2f(h.w));
    ((ushort4*)o0)[(size_t)tok * 64 + lane] = h;
    ((ushort4*)o1)[(size_t)tok * 64 + lane] = lo;
  } else {
    f4 ov = {y0, y1, y2, y3};
    ((f4*)o0)[(size_t)tok * 64 + lane] = ov;
  }
}

// ---------------------------------------------------------------------------
extern "C" void kernel_launch(void* const* d_in, const int* in_sizes, int n_in,
                              void* d_out, int out_size, void* d_ws, size_t ws_size,
                              hipStream_t stream){
  const float* hs   = (const float*)d_in[0];
  const float* emb  = (const float*)d_in[1];
  const float* Woff = (const float*)d_in[2];
  const float* boff = (const float*)d_in[3];
  const float* Wkvp = (const float*)d_in[4];
  const float* bkvp = (const float*)d_in[5];
  const float* Wq   = (const float*)d_in[6];
  const float* bq   = (const float*)d_in[7];
  const float* Wk   = (const float*)d_in[8];
  const float* bk   = (const float*)d_in[9];
  const float* Wv   = (const float*)d_in[10];
  const float* bv   = (const float*)d_in[11];
  const float* Wo   = (const float*)d_in[12];
  const float* bo   = (const float*)d_in[13];
  const float* ln1s = (const float*)d_in[14];
  const float* ln1b = (const float*)d_in[15];
  const float* ln2s = (const float*)d_in[16];
  const float* ln2b = (const float*)d_in[17];
  const float* W1   = (const float*)d_in[18];
  const float* b1   = (const float*)d_in[19];
  const float* W2   = (const float*)d_in[20];
  const float* b2   = (const float*)d_in[21];

  char* w = (char*)d_ws;
  auto alloc = [&](size_t bytes){ char* p = w; w += (bytes + 255) & ~(size_t)255; return p; };
  // weight planes: [WqT | WkT | WvT | WoT] contiguous hi and lo
  u16* qkvoTh = (u16*)alloc(4 * 65536 * 2);
  u16* qkvoTl = (u16*)alloc(4 * 65536 * 2);
  u16* WqTh = qkvoTh;              u16* WqTl = qkvoTl;
  u16* kvWh = qkvoTh + 65536;      u16* kvWl = qkvoTl + 65536;   // [512,256]
  u16* WoTh = qkvoTh + 3 * 65536;  u16* WoTl = qkvoTl + 3 * 65536;
  u16* W1Th = (u16*)alloc(262144 * 2); u16* W1Tl = (u16*)alloc(262144 * 2);
  u16* W2Th = (u16*)alloc(262144 * 2); u16* W2Tl = (u16*)alloc(262144 * 2);
  float* kvc = (float*)alloc(1536 * 4);
  // slot1 (8.4 MB): hs hi/lo planes / attn hi plane / xb planes
  char* slot1 = alloc((size_t)NT * 256 * 4);
  u16* hsph = (u16*)slot1;          u16* hspl = hsph + (size_t)NT * 256;
  u16* attnh = hsph;
  u16* xbh = hsph;                  u16* xbl = hspl;
  // slot2 (8.4 MB): emb bf16 plane / aout fp32
  char* slot2 = alloc((size_t)NT * 256 * 4);
  u16* embh = (u16*)slot2;
  float* aout = (float*)slot2;
  // slot3 (8.4 MB): off+loc / mout fp32
  char* slot3 = alloc((size_t)NT * 256 * 4);
  float* off = (float*)slot3;       float* loc = off + (size_t)NT * 32;
  float* mout = (float*)slot3;
  // slot4 (16.8 MB): qb fp32 + EKV bf16 / h1 bf16 [NT,1024] (16 MB)
  char* slot4 = alloc((size_t)NT * 256 * 8);
  float* qb = (float*)slot4;
  u16* EKV = (u16*)(slot4 + (size_t)NT * 256 * 4);   // [NT,512] packed bf16
  u16* h1 = (u16*)slot4;                             // [NT,1024] bf16 plane
  if ((size_t)(w - (char*)d_ws) > ws_size) return;

  // prep: 2 dispatches (hs read once; all weight prep batched)
  prolog_k<<<1024, 256, 0, stream>>>(hs, emb, Woff, boff, hsph, hspl, embh, off, loc);
  weights_k<<<770, 256, 0, stream>>>(Wq, Wk, Wv, Wo, W1, W2, Wkvp, bkvp, bk, bv,
                                     qkvoTh, qkvoTl, W1Th, W1Tl, W2Th, W2Tl, kvc);

  // grouped q (3-pass) + EKV (2-pass) in ONE 1536-block dispatch
  qekv_k<<<1536, 256, 0, stream>>>(hsph, hspl, WqTh, WqTl, bq,
                                   embh, kvWh, kvWl, qb, EKV);

  // gather + online-softmax attention
  attn_k<<<2048, 256, 0, stream>>>(qb, EKV, off, loc, kvc, attnh);

  // out-proj (2-pass), LN1, MLP (W1 via 128x128 tile), LN2
  gemm_k<64, 1, 0><<<dim3(128, 4), 256, 0, stream>>>(attnh, nullptr, WoTh, WoTl, bo, aout, NT, 256, 256);
  ln_k<0, 1><<<2048, 256, 0, stream>>>(hs, nullptr, aout, ln1s, ln1b, xbh, xbl);
  gemm128_k<<<dim3(64, 8), 256, 0, stream>>>(xbh, W1Th, W1Tl, b1, h1, NT, 1024, 256);
  gemm_k<64, 1, 0><<<dim3(128, 4), 256, 0, stream>>>(h1, nullptr, W2Th, W2Tl, b2, mout, NT, 256, 1024);
  ln_k<1, 0><<<2048, 256, 0, stream>>>(xbh, xbl, mout, ln2s, ln2b, d_out, nullptr);
}

// Round 13
// 238.502 us; speedup vs baseline: 1.6760x; 1.1031x over previous
//
#include <hip/hip_runtime.h>

// Problem dims
#define NT 8192      // N*H*W tokens
#define DM 256
#define HH 64
#define WW 64

typedef unsigned short u16;
typedef __attribute__((ext_vector_type(8))) short short8;  // 8 x bf16 mfma frag
typedef __attribute__((ext_vector_type(4))) float f4;

__device__ __forceinline__ float bf2f(u16 u){
  union { unsigned int i; float f; } v; v.i = ((unsigned int)u) << 16; return v.f;
}
__device__ __forceinline__ u16 f2bf(float f){
  union { float f; unsigned int i; } v; v.f = f;
  unsigned int r = (v.i + 0x7fffu + ((v.i >> 16) & 1u)) >> 16;
  return (u16)r;
}
// async global->LDS 16B (direct DMA, no VGPR round trip)
__device__ __forceinline__ void gld16(const void* g, void* l){
  __builtin_amdgcn_global_load_lds(
      (const __attribute__((address_space(1))) unsigned int*)g,
      (__attribute__((address_space(3))) unsigned int*)l, 16, 0, 0);
}

// ---------------------------------------------------------------------------
// ALL prep in ONE dispatch (1794 blocks):
//  b < 1024: prolog path — per 8 tokens: offsets GEMV + hs->hi/lo + emb->hi
//  1024..1279: qkvo transposes; 1280..1535: W1^T; 1536..1791: W2^T;
//  1792/1793: fold W_kvp/b_kvp through Wk/Wv -> kvc.
// Both paths numerically identical to the r12 (proven-clean) kernels.
// ---------------------------------------------------------------------------
__global__ __launch_bounds__(256) void prepall_k(const float* __restrict__ hs,
                                                 const float* __restrict__ emb,
                                                 const float* __restrict__ Woff,
                                                 const float* __restrict__ boff,
                                                 const float* __restrict__ Wq,
                                                 const float* __restrict__ Wk,
                                                 const float* __restrict__ Wv,
                                                 const float* __restrict__ Wo,
                                                 const float* __restrict__ W1,
                                                 const float* __restrict__ W2,
                                                 const float* __restrict__ Wkvp,
                                                 const float* __restrict__ bkvp,
                                                 const float* __restrict__ bk,
                                                 const float* __restrict__ bv,
                                                 u16* __restrict__ hsph,
                                                 u16* __restrict__ hspl,
                                                 u16* __restrict__ embh,
                                                 float* __restrict__ off,
                                                 float* __restrict__ loc,
                                                 u16* __restrict__ qkvoTh,
                                                 u16* __restrict__ qkvoTl,
                                                 u16* __restrict__ W1Th,
                                                 u16* __restrict__ W1Tl,
                                                 u16* __restrict__ W2Th,
                                                 u16* __restrict__ W2Tl,
                                                 float* __restrict__ kvc){
  __shared__ float smem[10240];
  const int blk = blockIdx.x;
  const int tid = threadIdx.x;
  if (blk < 1024){
    // ---- prolog path ----
    float* hsl = smem;          // [2048]
    float* wl  = smem + 2048;   // [8192]
    const int t0 = blk * 8;
    for (int i = tid; i < 8192; i += 256) wl[i] = Woff[i];
    for (int i = tid; i < 2048; i += 256) hsl[i] = hs[(size_t)t0 * 256 + i];
    __syncthreads();
    {
      const int g = tid >> 5, o = tid & 31;
      float acc = 0.f;
      #pragma unroll 8
      for (int d = 0; d < 256; d++) acc += hsl[g * 256 + d] * wl[d * 32 + o];
      acc += boff[o];
      float sg = 1.f / (1.f + expf(-acc));
      float of = 60.f * sg - 30.f;
      int tok = t0 + g;
      int hh = (tok >> 6) & 63, ww = tok & 63;
      float base = (o & 1) ? (float)ww : (float)hh;
      float l = fminf(fmaxf(base + of, 0.f), 63.f);
      off[tok * 32 + o] = of;
      loc[tok * 32 + o] = l;
    }
    for (int c = tid; c < 512; c += 256){
      f4 v = *(const f4*)&hsl[c * 4];
      ushort4 h, l;
      h.x = f2bf(v.x); l.x = f2bf(v.x - bf2f(h.x));
      h.y = f2bf(v.y); l.y = f2bf(v.y - bf2f(h.y));
      h.z = f2bf(v.z); l.z = f2bf(v.z - bf2f(h.z));
      h.w = f2bf(v.w); l.w = f2bf(v.w - bf2f(h.w));
      ((ushort4*)hsph)[(size_t)t0 * 64 + c] = h;
      ((ushort4*)hspl)[(size_t)t0 * 64 + c] = l;
      f4 e = ((const f4*)emb)[(size_t)t0 * 64 + c];
      ushort4 eh;
      eh.x = f2bf(e.x); eh.y = f2bf(e.y); eh.z = f2bf(e.z); eh.w = f2bf(e.w);
      ((ushort4*)embh)[(size_t)t0 * 64 + c] = eh;
    }
    return;
  }
  const int b = blk - 1024;
  if (b >= 768){               // prepkv fold
    const float* Wx = (b == 768) ? Wk : Wv;
    const float* bx = (b == 768) ? bk : bv;
    float* o = kvc + (b - 768) * 768;
    int e = tid;
    float a0 = 0.f, a1 = 0.f, ab = 0.f;
    for (int d = 0; d < 256; d++){
      float w = Wx[d * 256 + e];
      a0 += Wkvp[d] * w;
      a1 += Wkvp[256 + d] * w;
      ab += bkvp[d] * w;
    }
    o[e] = a0; o[256 + e] = a1; o[512 + e] = ab + bx[e];
    return;
  }
  // ---- weight transpose path ----
  float (*t)[33] = (float(*)[33])smem;
  const float* src; u16 *dh, *dl; int R, C, c0, r0;
  if (b < 256){
    int mat = b >> 6, tt = b & 63;
    src = mat == 0 ? Wq : mat == 1 ? Wk : mat == 2 ? Wv : Wo;
    dh = qkvoTh + mat * 65536; dl = qkvoTl + mat * 65536;
    R = 256; C = 256; c0 = (tt & 7) * 32; r0 = (tt >> 3) * 32;
  } else if (b < 512){
    int tt = b - 256; src = W1; dh = W1Th; dl = W1Tl; R = 256; C = 1024;
    c0 = (tt & 31) * 32; r0 = (tt >> 5) * 32;
  } else {
    int tt = b - 512; src = W2; dh = W2Th; dl = W2Tl; R = 1024; C = 256;
    c0 = (tt & 7) * 32; r0 = (tt >> 3) * 32;
  }
  int tx = tid & 31, ty = tid >> 5;
  for (int i = ty; i < 32; i += 8) t[i][tx] = src[(size_t)(r0 + i) * C + c0 + tx];
  __syncthreads();
  for (int i = ty; i < 32; i += 8){
    float x = t[tx][i];
    u16 h = f2bf(x);
    size_t idx = (size_t)(c0 + i) * R + r0 + tx;
    dh[idx] = h;
    dl[idx] = f2bf(x - bf2f(h));
  }
}

// ---------------------------------------------------------------------------
// Grouped q + EKV GEMM, ONE dispatch (1536 blocks), BM=BN=64, BK=64, K=256.
//  blocks 0..511:    q   = hs(hi/lo, 3-pass) x WqT(hi/lo) + bq -> fp32 qb
//  blocks 512..1535: EKV = emb(hi, 2-pass)  x kvWT(hi/lo)      -> packed bf16
// Score-path precision preserved (r10 showed q/K sensitivity).
// ---------------------------------------------------------------------------
__global__ __launch_bounds__(256) void qekv_k(const u16* __restrict__ hsph,
                                              const u16* __restrict__ hspl,
                                              const u16* __restrict__ WqTh,
                                              const u16* __restrict__ WqTl,
                                              const float* __restrict__ bq,
                                              const u16* __restrict__ embh,
                                              const u16* __restrict__ kvWh,
                                              const u16* __restrict__ kvWl,
                                              float* __restrict__ qb,
                                              u16* __restrict__ EKV){
  __shared__ __align__(16) u16 Ah[8][64][8];
  __shared__ __align__(16) u16 Al[8][64][8];
  __shared__ __align__(16) u16 Bh[8][64][8];
  __shared__ __align__(16) u16 Bl[8][64][8];
  const int bid = blockIdx.x;
  const bool isQ = bid < 512;
  const int b2 = isQ ? bid : bid - 512;
  const int m0 = (b2 & 127) << 6;
  const int n0 = (b2 >> 7) << 6;
  const int K = 256;
  const u16* Agh = isQ ? hsph : embh;
  const u16* Bgh = isQ ? WqTh : kvWh;
  const u16* Bgl = isQ ? WqTl : kvWl;
  const int tid = threadIdx.x;
  const int lane = tid & 63, wave = tid >> 6;
  const int quad = lane >> 4, l15 = lane & 15;
  const int wm = (wave >> 1) << 5, wn = (wave & 1) << 5;
  const int ar = tid & 63, aq = tid >> 6;
  const u16* gAh = Agh + (size_t)(m0 + ar) * K + aq * 8;
  const u16* gAl = hspl + (size_t)(m0 + ar) * K + aq * 8;   // only read if isQ
  const u16* gBh = Bgh + (size_t)(n0 + ar) * K + aq * 8;
  const u16* gBl = Bgl + (size_t)(n0 + ar) * K + aq * 8;
  f4 acc[2][2] = {};
  for (int k0 = 0; k0 < K; k0 += 64){
    __syncthreads();
    gld16(gAh + k0,      &Ah[aq][ar][0]);
    gld16(gAh + k0 + 32, &Ah[aq + 4][ar][0]);
    if (isQ){
      gld16(gAl + k0,      &Al[aq][ar][0]);
      gld16(gAl + k0 + 32, &Al[aq + 4][ar][0]);
    }
    gld16(gBh + k0,      &Bh[aq][ar][0]);
    gld16(gBh + k0 + 32, &Bh[aq + 4][ar][0]);
    gld16(gBl + k0,      &Bl[aq][ar][0]);
    gld16(gBl + k0 + 32, &Bl[aq + 4][ar][0]);
    asm volatile("s_waitcnt vmcnt(0)" ::: "memory");
    __syncthreads();
    #pragma unroll
    for (int kh = 0; kh < 2; kh++){
      const int q = kh * 4 + quad;
      short8 ahf[2], alf[2], bhf[2], blf[2];
      #pragma unroll
      for (int i = 0; i < 2; i++){
        ahf[i] = *(const short8*)(&Ah[q][wm + i * 16 + l15][0]);
        bhf[i] = *(const short8*)(&Bh[q][wn + i * 16 + l15][0]);
        blf[i] = *(const short8*)(&Bl[q][wn + i * 16 + l15][0]);
      }
      if (isQ){
        #pragma unroll
        for (int i = 0; i < 2; i++)
          alf[i] = *(const short8*)(&Al[q][wm + i * 16 + l15][0]);
      }
      #pragma unroll
      for (int mi = 0; mi < 2; mi++)
      #pragma unroll
      for (int ni = 0; ni < 2; ni++){
        if (isQ)
          acc[mi][ni] = __builtin_amdgcn_mfma_f32_16x16x32_bf16(alf[mi], bhf[ni], acc[mi][ni], 0, 0, 0);
        acc[mi][ni] = __builtin_amdgcn_mfma_f32_16x16x32_bf16(ahf[mi], blf[ni], acc[mi][ni], 0, 0, 0);
        acc[mi][ni] = __builtin_amdgcn_mfma_f32_16x16x32_bf16(ahf[mi], bhf[ni], acc[mi][ni], 0, 0, 0);
      }
    }
  }
  #pragma unroll
  for (int mi = 0; mi < 2; mi++)
  #pragma unroll
  for (int ni = 0; ni < 2; ni++){
    int col = n0 + wn + ni * 16 + l15;
    int rowb = m0 + wm + mi * 16 + quad * 4;
    if (isQ){
      float bval = bq[col];
      #pragma unroll
      for (int rg = 0; rg < 4; rg++)
        qb[(size_t)(rowb + rg) * 256 + col] = acc[mi][ni][rg] + bval;
    } else {
      int part = col >> 8, d = col & 255;
      int pc = ((d >> 2) << 3) + (part << 2) + (d & 3);
      #pragma unroll
      for (int rg = 0; rg < 4; rg++)
        EKV[(size_t)(rowb + rg) * 512 + pc] = f2bf(acc[mi][ni][rg]);
    }
  }
}

// ---------------------------------------------------------------------------
// Split-precision MFMA GEMM. BM=64, BK=64, BN=64.
// APREC: 2 = A hi/lo planes (adds Al*Bh pass), 1 = A hi only.
// BPREC: 2 = B hi/lo planes (adds Ah*Bl pass), 1 = B hi only.
// EPI 0: fp32 +bias -> C0.   EPI 1: gelu(tanh) -> bf16 plane C0.
// ---------------------------------------------------------------------------
template<int BN, int APREC, int BPREC, int EPI>
__global__ __launch_bounds__(256) void gemm_k(const u16* __restrict__ Agh,
                                              const u16* __restrict__ Agl,
                                              const u16* __restrict__ Bgh,
                                              const u16* __restrict__ Bgl,
                                              const float* __restrict__ bias,
                                              void* __restrict__ C0,
                                              int M, int N, int K){
  constexpr int NF = BN / 32;
  __shared__ __align__(16) u16 Ah[8][64][8];
  __shared__ __align__(16) u16 Al[APREC == 2 ? 8 : 1][64][8];
  __shared__ __align__(16) u16 Bh[8][BN][8];
  __shared__ __align__(16) u16 Bl[BPREC == 2 ? 8 : 1][BN][8];
  const int m0 = blockIdx.x << 6, n0 = blockIdx.y * BN;
  const int tid = threadIdx.x;
  const int lane = tid & 63, wave = tid >> 6;
  const int quad = lane >> 4, l15 = lane & 15;
  const int wm = (wave >> 1) << 5;
  const int wn = (wave & 1) * (BN >> 1);
  const int ar = tid & 63, aq = tid >> 6;
  const u16* gAh = Agh + (size_t)(m0 + ar) * K + aq * 8;
  const u16* gAl = (APREC == 2) ? (Agl + (size_t)(m0 + ar) * K + aq * 8) : nullptr;
  const int br = (BN == 128) ? (tid & 127) : (tid & 63);
  const int bq = (BN == 128) ? (tid >> 7) : (tid >> 6);
  const u16* gBh = Bgh + (size_t)(n0 + br) * K + bq * 8;
  const u16* gBl = (BPREC == 2) ? (Bgl + (size_t)(n0 + br) * K + bq * 8) : nullptr;
  f4 acc[2][NF] = {};
  for (int k0 = 0; k0 < K; k0 += 64){
    __syncthreads();
    gld16(gAh + k0,      &Ah[aq][ar][0]);
    gld16(gAh + k0 + 32, &Ah[aq + 4][ar][0]);
    if (APREC == 2){
      gld16(gAl + k0,      &Al[aq][ar][0]);
      gld16(gAl + k0 + 32, &Al[aq + 4][ar][0]);
    }
    gld16(gBh + k0,      &Bh[bq][br][0]);
    gld16(gBh + k0 + 32, &Bh[bq + 4][br][0]);
    if (BPREC == 2){
      gld16(gBl + k0,      &Bl[bq][br][0]);
      gld16(gBl + k0 + 32, &Bl[bq + 4][br][0]);
    }
    asm volatile("s_waitcnt vmcnt(0)" ::: "memory");
    __syncthreads();
    #pragma unroll
    for (int kh = 0; kh < 2; kh++){
      const int q = kh * 4 + quad;
      short8 ahf[2], alf[2], bhf[NF], blf[NF];
      #pragma unroll
      for (int i = 0; i < 2; i++){
        ahf[i] = *(const short8*)(&Ah[q][wm + i * 16 + l15][0]);
        if (APREC == 2) alf[i] = *(const short8*)(&Al[q][wm + i * 16 + l15][0]);
      }
      #pragma unroll
      for (int i = 0; i < NF; i++){
        bhf[i] = *(const short8*)(&Bh[q][wn + i * 16 + l15][0]);
        if (BPREC == 2) blf[i] = *(const short8*)(&Bl[q][wn + i * 16 + l15][0]);
      }
      #pragma unroll
      for (int mi = 0; mi < 2; mi++)
      #pragma unroll
      for (int ni = 0; ni < NF; ni++){
        if (APREC == 2)
          acc[mi][ni] = __builtin_amdgcn_mfma_f32_16x16x32_bf16(alf[mi], bhf[ni], acc[mi][ni], 0, 0, 0);
        if (BPREC == 2)
          acc[mi][ni] = __builtin_amdgcn_mfma_f32_16x16x32_bf16(ahf[mi], blf[ni], acc[mi][ni], 0, 0, 0);
        acc[mi][ni] = __builtin_amdgcn_mfma_f32_16x16x32_bf16(ahf[mi], bhf[ni], acc[mi][ni], 0, 0, 0);
      }
    }
  }
  #pragma unroll
  for (int mi = 0; mi < 2; mi++)
  #pragma unroll
  for (int ni = 0; ni < NF; ni++){
    int col = n0 + wn + ni * 16 + l15;
    float bval = bias ? bias[col] : 0.f;
    int rowb = m0 + wm + mi * 16 + quad * 4;
    #pragma unroll
    for (int rg = 0; rg < 4; rg++){
      float v = acc[mi][ni][rg] + bval;
      int row = rowb + rg;
      if (EPI == 0){
        ((float*)C0)[(size_t)row * N + col] = v;
      } else {
        float t = v + 0.044715f * v * v * v;
        float g = 0.5f * v * (1.f + tanhf(0.7978845608f * t));
        ((u16*)C0)[(size_t)row * N + col] = f2bf(g);
      }
    }
  }
}

// ---------------------------------------------------------------------------
// Dedicated W1 GEMM: 128x128 tile, BK=64, A bf16 plane, B hi plane (1-pass),
// gelu -> bf16. 32 MFMA : 16 ds_read per K-iter. Proven clean (r10).
// ---------------------------------------------------------------------------
__global__ __launch_bounds__(256) void gemm128_k(const u16* __restrict__ Agh,
                                                 const u16* __restrict__ Bgh,
                                                 const float* __restrict__ bias,
                                                 u16* __restrict__ C0,
                                                 int M, int N, int K){
  __shared__ __align__(16) u16 Ah[8][128][8];
  __shared__ __align__(16) u16 Bh[8][128][8];
  const int m0 = blockIdx.x << 7, n0 = blockIdx.y << 7;
  const int tid = threadIdx.x;
  const int lane = tid & 63, wave = tid >> 6;
  const int quad = lane >> 4, l15 = lane & 15;
  const int wm = (wave >> 1) << 6, wn = (wave & 1) << 6;
  const int ar = tid & 127, q0 = tid >> 7;
  const u16* gA  = Agh + (size_t)(m0 + ar) * K + q0 * 8;
  const u16* gBhp = Bgh + (size_t)(n0 + ar) * K + q0 * 8;
  f4 acc[4][4] = {};
  for (int k0 = 0; k0 < K; k0 += 64){
    __syncthreads();
    #pragma unroll
    for (int j = 0; j < 4; j++){
      gld16(gA   + k0 + j * 16, &Ah[q0 + 2 * j][ar][0]);
      gld16(gBhp + k0 + j * 16, &Bh[q0 + 2 * j][ar][0]);
    }
    asm volatile("s_waitcnt vmcnt(0)" ::: "memory");
    __syncthreads();
    #pragma unroll
    for (int kh = 0; kh < 2; kh++){
      const int q = kh * 4 + quad;
      short8 af[4], bh8[4];
      #pragma unroll
      for (int i = 0; i < 4; i++){
        af[i]  = *(const short8*)(&Ah[q][wm + i * 16 + l15][0]);
        bh8[i] = *(const short8*)(&Bh[q][wn + i * 16 + l15][0]);
      }
      #pragma unroll
      for (int mi = 0; mi < 4; mi++)
      #pragma unroll
      for (int ni = 0; ni < 4; ni++)
        acc[mi][ni] = __builtin_amdgcn_mfma_f32_16x16x32_bf16(af[mi], bh8[ni], acc[mi][ni], 0, 0, 0);
    }
  }
  #pragma unroll
  for (int mi = 0; mi < 4; mi++)
  #pragma unroll
  for (int ni = 0; ni < 4; ni++){
    int col = n0 + wn + ni * 16 + l15;
    float bval = bias[col];
    int rowb = m0 + wm + mi * 16 + quad * 4;
    #pragma unroll
    for (int rg = 0; rg < 4; rg++){
      float v = acc[mi][ni][rg] + bval;
      float t = v + 0.044715f * v * v * v;
      float g = 0.5f * v * (1.f + tanhf(0.7978845608f * t));
      C0[(size_t)(rowb + rg) * N + col] = f2bf(g);
    }
  }
}

// ---------------------------------------------------------------------------
// Attention, single pass (online softmax). One wave per token; lane owns dims
// [4*lane,4*lane+4). EKV packed bf16: one 16B load per corner = k4|v4.
// Output: bf16 hi plane only. Linear token map (XCD swizzle = r8 divergence).
// ---------------------------------------------------------------------------
__device__ __forceinline__ void unpack8(int4 p, f4& k4, f4& v4){
  k4.x = bf2f((u16)(p.x & 0xffff)); k4.y = bf2f((u16)((unsigned)p.x >> 16));
  k4.z = bf2f((u16)(p.y & 0xffff)); k4.w = bf2f((u16)((unsigned)p.y >> 16));
  v4.x = bf2f((u16)(p.z & 0xffff)); v4.y = bf2f((u16)((unsigned)p.z >> 16));
  v4.z = bf2f((u16)(p.w & 0xffff)); v4.w = bf2f((u16)((unsigned)p.w >> 16));
}

__global__ __launch_bounds__(256) void attn_k(const float* __restrict__ q,
                                              const u16* __restrict__ EKV,
                                              const float* __restrict__ offb,
                                              const float* __restrict__ locb,
                                              const float* __restrict__ kvc,
                                              u16* __restrict__ ah){
  const int tid = threadIdx.x;
  const int wave = tid >> 6, lane = tid & 63;
  const int tok = blockIdx.x * 4 + wave;
  const int base = (tok >> 12) << 12;   // n*4096
  const int4* E = (const int4*)EKV;     // 16B per (row,lane)
  const f4* kvc4 = (const f4*)kvc;
  f4 qv  = *((const f4*)q + (size_t)tok * 64 + lane);
  f4 wk0 = kvc4[lane], wk1 = kvc4[64 + lane], bkv = kvc4[128 + lane];
  f4 wv0 = kvc4[192 + lane], wv1 = kvc4[256 + lane], bvv = kvc4[320 + lane];
  float m = -1e30f, l = 0.f;
  f4 acc = {0.f, 0.f, 0.f, 0.f};
  #pragma unroll
  for (int s = 0; s < 16; s++){
    float y = locb[tok * 32 + s * 2], x = locb[tok * 32 + s * 2 + 1];
    float o0 = offb[tok * 32 + s * 2], o1 = offb[tok * 32 + s * 2 + 1];
    float yf = floorf(y), xf = floorf(x);
    int y0 = (int)yf, x0 = (int)xf;
    int y1 = min(y0 + 1, 63), x1 = min(x0 + 1, 63);
    float wy = y - yf, wx = x - xf;
    int4 p00 = E[(size_t)(base + y0 * 64 + x0) * 64 + lane];
    int4 p01 = E[(size_t)(base + y0 * 64 + x1) * 64 + lane];
    int4 p10 = E[(size_t)(base + y1 * 64 + x0) * 64 + lane];
    int4 p11 = E[(size_t)(base + y1 * 64 + x1) * 64 + lane];
    f4 k00, v00, k01, v01, k10, v10, k11, v11;
    unpack8(p00, k00, v00); unpack8(p01, k01, v01);
    unpack8(p10, k10, v10); unpack8(p11, k11, v11);
    float w00 = (1.f - wy) * (1.f - wx), w01 = (1.f - wy) * wx;
    float w10 = wy * (1.f - wx), w11 = wy * wx;
    f4 kk = w00 * k00 + w01 * k01 + w10 * k10 + w11 * k11;
    f4 vv = w00 * v00 + w01 * v01 + w10 * v10 + w11 * v11;
    kk += o0 * wk0 + o1 * wk1 + bkv;
    vv += o0 * wv0 + o1 * wv1 + bvv;
    float p = qv.x * kk.x + qv.y * kk.y + qv.z * kk.z + qv.w * kk.w;
    p += __shfl_xor(p, 1); p += __shfl_xor(p, 2);
    p += __shfl_xor(p, 4); p += __shfl_xor(p, 8);
    p *= 0.125f;   // /sqrt(64)
    float mn = fmaxf(m, p);
    float cor = __expf(m - mn);
    float wgt = __expf(p - mn);
    l = l * cor + wgt;
    acc = acc * cor + wgt * vv;
    m = mn;
  }
  float inv = 1.f / l;
  f4 o = acc * inv;
  ushort4 h;
  h.x = f2bf(o.x); h.y = f2bf(o.y); h.z = f2bf(o.z); h.w = f2bf(o.w);
  *(ushort4*)(ah + (size_t)tok * 256 + lane * 4) = h;
}

// ---------------------------------------------------------------------------
// LayerNorm(a + b) * scale + bias. One wave per token.
// INP: 0 -> a0 fp32; 1 -> a0/a1 hi/lo planes.  OUTP: 0 -> fp32; 1 -> planes.
// ---------------------------------------------------------------------------
template<int INP, int OUTP>
__global__ __launch_bounds__(256) void ln_k(const void* __restrict__ a0,
                                            const void* __restrict__ a1,
                                            const float* __restrict__ b,
                                            const float* __restrict__ sc,
                                            const float* __restrict__ bi,
                                            void* __restrict__ o0,
                                            void* __restrict__ o1){
  const int tid = threadIdx.x;
  const int wave = tid >> 6, lane = tid & 63;
  const int tok = blockIdx.x * 4 + wave;
  float x0, x1, x2, x3;
  if (INP){
    ushort4 h = ((const ushort4*)a0)[(size_t)tok * 64 + lane];
    ushort4 lo = ((const ushort4*)a1)[(size_t)tok * 64 + lane];
    x0 = bf2f(h.x) + bf2f(lo.x); x1 = bf2f(h.y) + bf2f(lo.y);
    x2 = bf2f(h.z) + bf2f(lo.z); x3 = bf2f(h.w) + bf2f(lo.w);
  } else {
    f4 av = ((const f4*)a0)[(size_t)tok * 64 + lane];
    x0 = av.x; x1 = av.y; x2 = av.z; x3 = av.w;
  }
  f4 bv = ((const f4*)b)[(size_t)tok * 64 + lane];
  x0 += bv.x; x1 += bv.y; x2 += bv.z; x3 += bv.w;
  float sm = x0 + x1 + x2 + x3;
  float sq = x0 * x0 + x1 * x1 + x2 * x2 + x3 * x3;
  #pragma unroll
  for (int mm = 1; mm < 64; mm <<= 1){ sm += __shfl_xor(sm, mm); sq += __shfl_xor(sq, mm); }
  float mean = sm * (1.f / 256.f);
  float var = sq * (1.f / 256.f) - mean * mean;
  float rs = rsqrtf(var + 1e-6f);
  f4 sv = ((const f4*)sc)[lane];
  f4 bb = ((const f4*)bi)[lane];
  float y0 = (x0 - mean) * rs * sv.x + bb.x;
  float y1 = (x1 - mean) * rs * sv.y + bb.y;
  float y2 = (x2 - mean) * rs * sv.z + bb.z;
  float y3 = (x3 - mean) * rs * sv.w + bb.w;
  if (OUTP){
    ushort4 h, lo;
    h.x = f2bf(y0); lo.x = f2bf(y0 - bf2f(h.x));
    h.y = f2bf(y1); lo.y = f2bf(y1 - bf2f(h.y));
    h.z = f2bf(y2); lo.z = f2bf(y2 - bf2f(h.z));
    h.w = f2bf(y3); lo.w = f2bf(y3 - bf2f(h.w));
    ((ushort4*)o0)[(size_t)tok * 64 + lane] = h;
    ((ushort4*)o1)[(size_t)tok * 64 + lane] = lo;
  } else {
    f4 ov = {y0, y1, y2, y3};
    ((f4*)o0)[(size_t)tok * 64 + lane] = ov;
  }
}

// ---------------------------------------------------------------------------
extern "C" void kernel_launch(void* const* d_in, const int* in_sizes, int n_in,
                              void* d_out, int out_size, void* d_ws, size_t ws_size,
                              hipStream_t stream){
  const float* hs   = (const float*)d_in[0];
  const float* emb  = (const float*)d_in[1];
  const float* Woff = (const float*)d_in[2];
  const float* boff = (const float*)d_in[3];
  const float* Wkvp = (const float*)d_in[4];
  const float* bkvp = (const float*)d_in[5];
  const float* Wq   = (const float*)d_in[6];
  const float* bq   = (const float*)d_in[7];
  const float* Wk   = (const float*)d_in[8];
  const float* bk   = (const float*)d_in[9];
  const float* Wv   = (const float*)d_in[10];
  const float* bv   = (const float*)d_in[11];
  const float* Wo   = (const float*)d_in[12];
  const float* bo   = (const float*)d_in[13];
  const float* ln1s = (const float*)d_in[14];
  const float* ln1b = (const float*)d_in[15];
  const float* ln2s = (const float*)d_in[16];
  const float* ln2b = (const float*)d_in[17];
  const float* W1   = (const float*)d_in[18];
  const float* b1   = (const float*)d_in[19];
  const float* W2   = (const float*)d_in[20];
  const float* b2   = (const float*)d_in[21];

  char* w = (char*)d_ws;
  auto alloc = [&](size_t bytes){ char* p = w; w += (bytes + 255) & ~(size_t)255; return p; };
  // weight planes: [WqT | WkT | WvT | WoT] contiguous hi and lo
  u16* qkvoTh = (u16*)alloc(4 * 65536 * 2);
  u16* qkvoTl = (u16*)alloc(4 * 65536 * 2);
  u16* WqTh = qkvoTh;              u16* WqTl = qkvoTl;
  u16* kvWh = qkvoTh + 65536;      u16* kvWl = qkvoTl + 65536;   // [512,256]
  u16* WoTh = qkvoTh + 3 * 65536;
  u16* W1Th = (u16*)alloc(262144 * 2); u16* W1Tl = (u16*)alloc(262144 * 2);
  u16* W2Th = (u16*)alloc(262144 * 2); u16* W2Tl = (u16*)alloc(262144 * 2);
  float* kvc = (float*)alloc(1536 * 4);
  // slot1 (8.4 MB): hs hi/lo planes / attn hi plane / xb planes
  char* slot1 = alloc((size_t)NT * 256 * 4);
  u16* hsph = (u16*)slot1;          u16* hspl = hsph + (size_t)NT * 256;
  u16* attnh = hsph;
  u16* xbh = hsph;                  u16* xbl = hspl;
  // slot2 (8.4 MB): emb bf16 plane / aout fp32
  char* slot2 = alloc((size_t)NT * 256 * 4);
  u16* embh = (u16*)slot2;
  float* aout = (float*)slot2;
  // slot3 (8.4 MB): off+loc / mout fp32
  char* slot3 = alloc((size_t)NT * 256 * 4);
  float* off = (float*)slot3;       float* loc = off + (size_t)NT * 32;
  float* mout = (float*)slot3;
  // slot4 (16.8 MB): qb fp32 + EKV bf16 / h1 bf16 [NT,1024] (16 MB)
  char* slot4 = alloc((size_t)NT * 256 * 8);
  float* qb = (float*)slot4;
  u16* EKV = (u16*)(slot4 + (size_t)NT * 256 * 4);   // [NT,512] packed bf16
  u16* h1 = (u16*)slot4;                             // [NT,1024] bf16 plane
  if ((size_t)(w - (char*)d_ws) > ws_size) return;

  // ALL prep in one dispatch
  prepall_k<<<1794, 256, 0, stream>>>(hs, emb, Woff, boff, Wq, Wk, Wv, Wo, W1, W2,
                                      Wkvp, bkvp, bk, bv,
                                      hsph, hspl, embh, off, loc,
                                      qkvoTh, qkvoTl, W1Th, W1Tl, W2Th, W2Tl, kvc);

  // grouped q (3-pass) + EKV (2-pass) in ONE 1536-block dispatch
  qekv_k<<<1536, 256, 0, stream>>>(hsph, hspl, WqTh, WqTl, bq,
                                   embh, kvWh, kvWl, qb, EKV);

  // gather + online-softmax attention
  attn_k<<<2048, 256, 0, stream>>>(qb, EKV, off, loc, kvc, attnh);

  // out-proj (1-pass: B-rounding ~6e-4, subdominant), LN1, MLP (both 1-pass), LN2
  gemm_k<64, 1, 1, 0><<<dim3(128, 4), 256, 0, stream>>>(attnh, nullptr, WoTh, nullptr, bo, aout, NT, 256, 256);
  ln_k<0, 1><<<2048, 256, 0, stream>>>(hs, nullptr, aout, ln1s, ln1b, xbh, xbl);
  gemm128_k<<<dim3(64, 8), 256, 0, stream>>>(xbh, W1Th, b1, h1, NT, 1024, 256);
  gemm_k<64, 1, 1, 0><<<dim3(128, 4), 256, 0, stream>>>(h1, nullptr, W2Th, nullptr, b2, mout, NT, 256, 1024);
  ln_k<1, 0><<<2048, 256, 0, stream>>>(xbh, xbl, mout, ln2s, ln2b, d_out, nullptr);
}